// Round 8
// baseline (1598.543 us; speedup 1.0000x reference)
//
#include <hip/hip_runtime.h>
#include <math.h>

#define TB 256

// ---------------- maxpool 3x3 stride2 pad1 ----------------
__global__ __launch_bounds__(256) void maxpool3s2_k(
    const float* __restrict__ in, float* __restrict__ out,
    int NC, int H, int W, int Ho, int Wo) {
  int idx = blockIdx.x * TB + threadIdx.x;
  int total = NC * Ho * Wo;
  if (idx >= total) return;
  int wo = idx % Wo;
  int t = idx / Wo;
  int ho = t % Ho;
  int nc = t / Ho;
  const float* src = in + (size_t)nc * H * W;
  int y0 = 2 * ho - 1, x0 = 2 * wo - 1;
  float m = -INFINITY;
  for (int dy = 0; dy < 3; ++dy) {
    int y = y0 + dy;
    if (y < 0 || y >= H) continue;
    for (int dx = 0; dx < 3; ++dx) {
      int x = x0 + dx;
      if (x < 0 || x >= W) continue;
      m = fmaxf(m, src[(size_t)y * W + x]);
    }
  }
  out[idx] = m;
}

// ---------------- bilinear x2 upsample (jax.image.resize, half-pixel) ----------------
__global__ __launch_bounds__(256) void up2_k(
    const float* __restrict__ in, float* __restrict__ out,
    int N, int C, int H, int W, int ocoff, int ocstride) {
  int Ho = 2 * H, Wo = 2 * W;
  int total = N * C * Ho * Wo;
  int idx = blockIdx.x * TB + threadIdx.x;
  if (idx >= total) return;
  int xo = idx % Wo;
  int t = idx / Wo;
  int yo = t % Ho;
  t /= Ho;
  int c = t % C;
  int n = t / C;
  float sy = 0.5f * yo - 0.25f;
  float sx = 0.5f * xo - 0.25f;
  float y0f = floorf(sy), x0f = floorf(sx);
  float wy = sy - y0f, wx = sx - x0f;
  int y0 = (int)y0f, x0 = (int)x0f;
  int y0c = min(max(y0, 0), H - 1), y1c = min(max(y0 + 1, 0), H - 1);
  int x0c = min(max(x0, 0), W - 1), x1c = min(max(x0 + 1, 0), W - 1);
  const float* s = in + ((size_t)n * C + c) * H * W;
  float v = (1.f - wy) * ((1.f - wx) * s[(size_t)y0c * W + x0c] + wx * s[(size_t)y0c * W + x1c]) +
            wy * ((1.f - wx) * s[(size_t)y1c * W + x0c] + wx * s[(size_t)y1c * W + x1c]);
  out[(((size_t)n * ocstride + ocoff + c) * Ho + yo) * Wo + xo] = v;
}

// ---------------- CHW -> HWC transpose (C=16), LDS tiled ----------------
__global__ __launch_bounds__(256) void chw2hwc16_k(
    const float* __restrict__ src, float* __restrict__ dst, int HW) {
  __shared__ float t[16 * 65];
  int n = blockIdx.y;
  int p0 = blockIdx.x * 64;
  int tid = threadIdx.x;
  for (int e = tid; e < 1024; e += 256) {
    int c = e >> 6, j = e & 63;
    t[c * 65 + j] = src[((size_t)n * 16 + c) * HW + p0 + j];
  }
  __syncthreads();
  for (int e = tid; e < 1024; e += 256) {
    int j = e >> 4, c = e & 15;
    dst[((size_t)n * HW + p0 + j) * 16 + c] = t[c * 65 + j];
  }
}

// ---------------- deform weight reorder: (O,16,9) -> (9,16,O) ----------------
__global__ __launch_bounds__(256) void wreorder_k(
    const float* __restrict__ a, const float* __restrict__ b,
    const float* __restrict__ c, const float* __restrict__ d,
    float* __restrict__ out) {
  int t = blockIdx.x * 256 + threadIdx.x;
  if (t < 6912) {
    int which = t / 2304, r = t % 2304;
    int o = r % 16, kc = r / 16;
    int ci = kc % 16, k = kc / 16;
    const float* w = which == 0 ? a : (which == 1 ? b : c);
    out[t] = w[(o * 16 + ci) * 9 + k];
  } else if (t < 7200) {
    int r = t - 6912;
    int o = r % 2, kc = r / 2;
    int ci = kc % 16, k = kc / 16;
    out[t] = d[(o * 16 + ci) * 9 + k];
  }
}

// ---------------- conv weight reorder: (O,C,9) -> (C,9,O) ----------------
struct WEntry { const float* src; int cin; int cout; int dstoff; };
struct WTable { WEntry e[20]; };  // 18 used
__global__ __launch_bounds__(256) void wreorder_conv_k(WTable t, float* __restrict__ out) {
  WEntry en = t.e[blockIdx.y];
  int total = en.cin * en.cout * 9;
  int i = blockIdx.x * 256 + threadIdx.x;
  if (i >= total) return;
  int o = i % en.cout;
  int ck = i / en.cout;
  int k = ck % 9;
  int c = ck / 9;
  out[en.dstoff + i] = en.src[((size_t)o * en.cin + c) * 9 + k];
}

// ---------------- 3x3 conv v5: 16x16 tile, single-shot staging ----------------
// Stage ALL CIN channels (CIN*18*24 floats, <=58.8KB) in one phase -> ONE barrier
// per block (was 2*NPASS). LDS pitch 24: wave rows hit each bank exactly 2x = free.
template <int CIN0, int CIN1, int COUT>
__global__ __launch_bounds__(256) void conv3x3_v5(
    const float* __restrict__ in0, const float* __restrict__ in1,
    const float* __restrict__ wro, const float* __restrict__ bias,
    float* __restrict__ out, int H, int W, int relu, int ocoff, int ocstride) {
  constexpr int CIN = CIN0 + CIN1;
  __shared__ float lds[CIN * 18 * 24];
  const int n = blockIdx.z;
  const int bx = blockIdx.x * 16, by = blockIdx.y * 16;
  const int tx = threadIdx.x, ty = threadIdx.y;
  const int tid = ty * 16 + tx;
  const float* i0 = in0 + (size_t)n * CIN0 * H * W;
  const float* i1 = in1 + (size_t)n * CIN1 * H * W;

  // ---- stage everything ----
#pragma unroll 4
  for (int idx = tid; idx < CIN * 324; idx += 256) {
    int c = idx / 324;
    int r = idx - c * 324;
    int ly = r / 18, lx = r - ly * 18;
    int gy = by + ly - 1, gx = bx + lx - 1;
    float v = 0.f;
    if (gy >= 0 && gy < H && gx >= 0 && gx < W)
      v = (c < CIN0) ? i0[((size_t)c * H + gy) * W + gx]
                     : i1[((size_t)(c - CIN0) * H + gy) * W + gx];
    lds[c * (18 * 24) + ly * 24 + lx] = v;
  }
  __syncthreads();

  float acc[COUT];
#pragma unroll
  for (int o = 0; o < COUT; ++o) acc[o] = bias ? bias[o] : 0.f;

#pragma unroll 2
  for (int c = 0; c < CIN; ++c) {
    const float* ld = lds + c * (18 * 24) + ty * 24 + tx;
    float v[3][3];
#pragma unroll
    for (int dy = 0; dy < 3; ++dy)
#pragma unroll
      for (int dx = 0; dx < 3; ++dx) v[dy][dx] = ld[dy * 24 + dx];
    const float* wc = wro + (size_t)c * 9 * COUT;
#pragma unroll
    for (int k = 0; k < 9; ++k) {
#pragma unroll
      for (int o = 0; o < COUT; ++o)
        acc[o] = fmaf(v[k / 3][k % 3], wc[k * COUT + o], acc[o]);
    }
  }

  const int h = by + ty, x = bx + tx;
#pragma unroll
  for (int o = 0; o < COUT; ++o) {
    float r = acc[o];
    if (relu) r = fmaxf(r, 0.f);
    out[(((size_t)n * ocstride + ocoff + o) * H + h) * W + x] = r;
  }
}

// ---------------- deformable 3x3 conv: HWC input, (k,c,o) weights ----------------
// XCD swizzle: contiguous row-bands per XCD for L2 gather locality (requires gridDim.x % 8 == 0).
template <int COUT, int DG>
__global__ __launch_bounds__(256) void deform_v3(
    const float* __restrict__ inHWC, const float* __restrict__ off,
    const float* __restrict__ wt, float* __restrict__ out,
    int H, int W, int relu, int ocoff, int ocstride) {
  constexpr int CIN = 16;
  constexpr int CG = CIN / DG;
  const int n = blockIdx.y;
  const int HWt = H * W;
  const int nbx = gridDim.x;
  int bxs = blockIdx.x;
  bxs = (bxs & 7) * (nbx >> 3) + (bxs >> 3);  // XCD-contiguous band mapping
  const int hw = bxs * 256 + threadIdx.x;
  const int h = hw / W, w = hw - h * W;
  const float* inN = inHWC + (size_t)n * HWt * CIN;
  const float* offN = off + (size_t)n * (DG * 18) * HWt + hw;
  float acc[COUT];
#pragma unroll
  for (int o = 0; o < COUT; ++o) acc[o] = 0.f;
#pragma unroll
  for (int g = 0; g < DG; ++g) {
#pragma unroll
    for (int k = 0; k < 9; ++k) {
      const int ky = k / 3 - 1, kx = k % 3 - 1;
      float oy = offN[(size_t)((g * 9 + k) * 2 + 0) * HWt];
      float ox = offN[(size_t)((g * 9 + k) * 2 + 1) * HWt];
      float py = (float)(h + ky) + oy;
      float px = (float)(w + kx) + ox;
      float y0f = floorf(py), x0f = floorf(px);
      float fy = py - y0f, fx = px - x0f;
      int y0 = (int)y0f, x0 = (int)x0f;
      bool vy0 = ((unsigned)y0 < (unsigned)H);
      bool vy1 = ((unsigned)(y0 + 1) < (unsigned)H);
      bool vx0 = ((unsigned)x0 < (unsigned)W);
      bool vx1 = ((unsigned)(x0 + 1) < (unsigned)W);
      int y0c = min(max(y0, 0), H - 1), y1c = min(max(y0 + 1, 0), H - 1);
      int x0c = min(max(x0, 0), W - 1), x1c = min(max(x0 + 1, 0), W - 1);
      float w00 = (vy0 && vx0) ? (1.f - fy) * (1.f - fx) : 0.f;
      float w01 = (vy0 && vx1) ? (1.f - fy) * fx : 0.f;
      float w10 = (vy1 && vx0) ? fy * (1.f - fx) : 0.f;
      float w11 = (vy1 && vx1) ? fy * fx : 0.f;
      const float* p00 = inN + ((size_t)y0c * W + x0c) * CIN + g * CG;
      const float* p01 = inN + ((size_t)y0c * W + x1c) * CIN + g * CG;
      const float* p10 = inN + ((size_t)y1c * W + x0c) * CIN + g * CG;
      const float* p11 = inN + ((size_t)y1c * W + x1c) * CIN + g * CG;
      const float* wk = wt + (k * CIN + g * CG) * COUT;
#pragma unroll
      for (int c4 = 0; c4 < CG / 4; ++c4) {
        float4 a00 = *(const float4*)(p00 + c4 * 4);
        float4 a01 = *(const float4*)(p01 + c4 * 4);
        float4 a10 = *(const float4*)(p10 + c4 * 4);
        float4 a11 = *(const float4*)(p11 + c4 * 4);
        float v0 = w00 * a00.x + w01 * a01.x + w10 * a10.x + w11 * a11.x;
        float v1 = w00 * a00.y + w01 * a01.y + w10 * a10.y + w11 * a11.y;
        float v2 = w00 * a00.z + w01 * a01.z + w10 * a10.z + w11 * a11.z;
        float v3 = w00 * a00.w + w01 * a01.w + w10 * a10.w + w11 * a11.w;
#pragma unroll
        for (int o = 0; o < COUT; ++o) {
          float t0 = fmaf(v0, wk[(c4 * 4 + 0) * COUT + o], acc[o]);
          t0 = fmaf(v1, wk[(c4 * 4 + 1) * COUT + o], t0);
          t0 = fmaf(v2, wk[(c4 * 4 + 2) * COUT + o], t0);
          acc[o] = fmaf(v3, wk[(c4 * 4 + 3) * COUT + o], t0);
        }
      }
    }
  }
  float* outN = out + ((size_t)n * ocstride + ocoff) * HWt + hw;
#pragma unroll
  for (int o = 0; o < COUT; ++o) {
    float r = acc[o];
    if (relu) r = fmaxf(r, 0.f);
    outN[(size_t)o * HWt] = r;
  }
}

// ---------------- host-side launch helpers ----------------
template <int C0, int C1, int CO>
static void LC(hipStream_t s, const float* a, const float* b, const float* w,
               const float* bi, float* o, int N, int H, int W, bool relu,
               int ocoff, int ocstride) {
  conv3x3_v5<C0, C1, CO><<<dim3(W / 16, H / 16, N), dim3(16, 16), 0, s>>>(
      a, b, w, bi, o, H, W, relu ? 1 : 0, ocoff, ocstride);
}

static void L_deform3(hipStream_t s, const float* inHWC, const float* off, const float* wt,
                      float* out, int N, int H, int W, int dg, int Cout, bool relu,
                      int ocoff, int ocstride) {
  dim3 grd(H * W / 256, N);
  int r = relu ? 1 : 0;
  if (Cout == 16 && dg == 1)
    deform_v3<16, 1><<<grd, 256, 0, s>>>(inHWC, off, wt, out, H, W, r, ocoff, ocstride);
  else if (Cout == 2 && dg == 2)
    deform_v3<2, 2><<<grd, 256, 0, s>>>(inHWC, off, wt, out, H, W, r, ocoff, ocstride);
}

static void L_hwc(hipStream_t s, const float* src, float* dst, int N, int HW) {
  dim3 grd(HW / 64, N);
  chw2hwc16_k<<<grd, 256, 0, s>>>(src, dst, HW);
}

static void L_pool(hipStream_t s, const float* in, float* out, int NC, int H, int W) {
  int Ho = H / 2, Wo = W / 2;
  int total = NC * Ho * Wo;
  maxpool3s2_k<<<(total + TB - 1) / TB, TB, 0, s>>>(in, out, NC, H, W, Ho, Wo);
}

static void L_up2(hipStream_t s, const float* in, float* out, int N, int C, int H, int W,
                  int ocoff, int ocstride) {
  int total = N * C * 4 * H * W;
  up2_k<<<(total + TB - 1) / TB, TB, 0, s>>>(in, out, N, C, H, W, ocoff, ocstride);
}

extern "C" void kernel_launch(void* const* d_in, const int* in_sizes, int n_in,
                              void* d_out, int out_size, void* d_ws, size_t ws_size,
                              hipStream_t stream) {
  auto F = [&](int i) { return (const float*)d_in[i]; };
  const float* ref = F(0);
  const float* unr = F(1);
  const float* few1[3] = {F(2), F(6), F(10)};
  const float* feb1[3] = {F(3), F(7), F(11)};
  const float* few2[3] = {F(4), F(8), F(12)};
  const float* feb2[3] = {F(5), F(9), F(13)};
  const float* obw[3] = {F(14), F(16), F(18)};
  const float* obb[3] = {F(15), F(17), F(19)};
  const float* ogw[3] = {F(20), F(22), F(24)};
  const float* ogb[3] = {F(21), F(23), F(25)};
  const float* dcw[3] = {F(26), F(27), F(28)};
  const float* fcw[3] = {F(29), F(31), F(33)};
  const float* fcb[3] = {F(30), F(32), F(34)};
  const float* dobw = F(35);
  const float* dobb = F(36);
  const float* dogw = F(37);
  const float* dogb = F(38);
  const float* ddcw = F(39);

  // ---- workspace layout (floats) ----
  float* ws = (float*)d_ws;
  size_t p = 0;
  auto alloc = [&](size_t nf) { float* r = ws + p; p += nf; return r; };
  const size_t SC = 9437184;  // fits (4,36,256,256), (2,16,512,512)
  float* A = alloc(SC);
  float* Bf = alloc(SC);
  float* rf[3], *uf[3], *offs[3], *feats[3];
  rf[0] = alloc((size_t)4 * 16 * 256 * 256);
  uf[0] = alloc((size_t)4 * 16 * 256 * 256);
  rf[1] = alloc((size_t)4 * 16 * 128 * 128);
  uf[1] = alloc((size_t)4 * 16 * 128 * 128);
  rf[2] = alloc((size_t)4 * 16 * 64 * 64);
  uf[2] = alloc((size_t)4 * 16 * 64 * 64);
  offs[0] = alloc((size_t)4 * 18 * 256 * 256);
  offs[1] = alloc((size_t)4 * 18 * 128 * 128);
  offs[2] = alloc((size_t)4 * 18 * 64 * 64);
  feats[0] = alloc((size_t)4 * 16 * 256 * 256);
  feats[1] = alloc((size_t)4 * 16 * 128 * 128);
  feats[2] = alloc((size_t)4 * 16 * 64 * 64);
  float* wt = alloc(7200);    // reordered deform weights (9,16,O)
  float* cw = alloc(70000);   // reordered conv weights (c,9,o)
  if (p * sizeof(float) > ws_size) return;
  const float* wt_dc[3] = {wt, wt + 2304, wt + 4608};
  const float* wt_ddc = wt + 6912;

  // ---- build conv weight reorder table (dog split into two 18-out halves) ----
  WTable T;
  int nw = 0, woff = 0, maxtot = 0;
  auto addw = [&](const float* src, int cin, int cout) {
    T.e[nw].src = src; T.e[nw].cin = cin; T.e[nw].cout = cout; T.e[nw].dstoff = woff;
    int tot = cin * cout * 9;
    if (tot > maxtot) maxtot = tot;
    int start = woff;
    woff += tot;
    ++nw;
    return start;
  };
  int o_few1[3], o_few2[3], o_ob[3], o_og[3], o_fc[3], o_dob, o_dog0, o_dog1;
  for (int i = 0; i < 3; ++i) o_few1[i] = addw(few1[i], i == 0 ? 1 : 16, 16);
  for (int i = 0; i < 3; ++i) o_few2[i] = addw(few2[i], 16, 16);
  for (int i = 0; i < 3; ++i) o_ob[i] = addw(obw[i], 32, 16);
  o_og[0] = addw(ogw[0], 34, 18);
  o_og[1] = addw(ogw[1], 34, 18);
  o_og[2] = addw(ogw[2], 16, 18);
  for (int i = 0; i < 3; ++i) o_fc[i] = addw(fcw[i], i == 2 ? 16 : 32, 16);
  o_dob = addw(dobw, 32, 16);
  o_dog0 = addw(dogw, 34, 18);
  o_dog1 = addw(dogw + (size_t)18 * 34 * 9, 34, 18);

  wreorder_k<<<29, 256, 0, stream>>>(dcw[0], dcw[1], dcw[2], ddcw, wt);
  wreorder_conv_k<<<dim3((maxtot + 255) / 256, nw), 256, 0, stream>>>(T, cw);

  // ---- feature-extraction pyramids ----
  const float* imgs[2] = {ref, unr};
  float** pyr[2] = {rf, uf};
  for (int im = 0; im < 2; ++im) {
    for (int ch = 0; ch < 2; ++ch) {  // 512^2 level in two N=2 chunks
      const float* src = imgs[im] + (size_t)ch * 2 * 512 * 512;
      LC<1, 0, 16>(stream, src, nullptr, cw + o_few1[0], feb1[0], A, 2, 512, 512, true, 0, 16);
      LC<16, 0, 16>(stream, A, nullptr, cw + o_few2[0], feb2[0], Bf, 2, 512, 512, true, 0, 16);
      L_pool(stream, Bf, pyr[im][0] + (size_t)ch * 2 * 16 * 256 * 256, 2 * 16, 512, 512);
    }
    LC<16, 0, 16>(stream, pyr[im][0], nullptr, cw + o_few1[1], feb1[1], A, 4, 256, 256, true, 0, 16);
    LC<16, 0, 16>(stream, A, nullptr, cw + o_few2[1], feb2[1], Bf, 4, 256, 256, true, 0, 16);
    L_pool(stream, Bf, pyr[im][1], 4 * 16, 256, 256);
    LC<16, 0, 16>(stream, pyr[im][1], nullptr, cw + o_few1[2], feb1[2], A, 4, 128, 128, true, 0, 16);
    LC<16, 0, 16>(stream, A, nullptr, cw + o_few2[2], feb2[2], Bf, 4, 128, 128, true, 0, 16);
    L_pool(stream, Bf, pyr[im][2], 4 * 16, 128, 128);
  }

  // ---- coarse-to-fine alignment ----
  int Hs[3] = {256, 128, 64};
  for (int i = 2; i >= 0; --i) {
    int H = Hs[i];
    int hw = H * H;
    float* oBuf = Bf;                       // 16ch compact
    float* upo = Bf + (size_t)4 * 16 * hw;  // 18ch compact (i<2)
    float* hwcB = A;                        // HWC of uf[i]
    float* fBuf = A + (size_t)4 * 16 * hw;  // 16ch compact
    if (i == 2) {
      LC<16, 16, 16>(stream, rf[2], uf[2], cw + o_ob[2], obb[2], oBuf, 4, H, H, true, 0, 16);
      LC<16, 0, 18>(stream, oBuf, nullptr, cw + o_og[2], ogb[2], offs[2], 4, H, H, true, 0, 18);
      L_hwc(stream, uf[2], hwcB, 4, hw);
      L_deform3(stream, hwcB, offs[2], wt_dc[2], fBuf, 4, H, H, 1, 16, true, 0, 16);
      LC<16, 0, 16>(stream, fBuf, nullptr, cw + o_fc[2], fcb[2], feats[2], 4, H, H, true, 0, 16);
    } else {
      LC<16, 16, 16>(stream, rf[i], uf[i], cw + o_ob[i], obb[i], oBuf, 4, H, H, true, 0, 16);
      L_up2(stream, offs[i + 1], upo, 4, 18, H / 2, H / 2, 0, 18);
      LC<16, 18, 18>(stream, oBuf, upo, cw + o_og[i], ogb[i], offs[i], 4, H, H, true, 0, 18);
      L_hwc(stream, uf[i], hwcB, 4, hw);
      L_deform3(stream, hwcB, offs[i], wt_dc[i], fBuf, 4, H, H, 1, 16, true, 0, 16);
      L_up2(stream, feats[i + 1], uf[i], 4, 16, H / 2, H / 2, 0, 16);  // uf[i] is dead
      LC<16, 16, 16>(stream, fBuf, uf[i], cw + o_fc[i], fcb[i], feats[i], 4, H, H, true, 0, 16);
    }
  }

  // ---- final offset head + deform (dg=2) ----
  const int hw0 = 256 * 256;
  float* doBuf = Bf;  // 16ch
  LC<16, 16, 16>(stream, rf[0], feats[0], cw + o_dob, dobb, doBuf, 4, 256, 256, false, 0, 16);
  // dog 34->36 as two 18-out halves into 36-stride buffer A
  LC<16, 18, 18>(stream, doBuf, offs[0], cw + o_dog0, dogb, A, 4, 256, 256, false, 0, 36);
  LC<16, 18, 18>(stream, doBuf, offs[0], cw + o_dog1, dogb + 18, A, 4, 256, 256, false, 18, 36);
  float* fHwc = Bf + (size_t)4 * 16 * hw0;  // doBuf consumed
  L_hwc(stream, feats[0], fHwc, 4, hw0);
  L_deform3(stream, fHwc, A, wt_ddc, (float*)d_out, 4, 256, 256, 2, 2, false, 0, 2);
}

// Round 9
// 1357.269 us; speedup vs baseline: 1.1778x; 1.1778x over previous
//
#include <hip/hip_runtime.h>
#include <math.h>

#define TB 256

// ---------------- maxpool 3x3 stride2 pad1 (levels 1/2) ----------------
__global__ __launch_bounds__(256) void maxpool3s2_k(
    const float* __restrict__ in, float* __restrict__ out,
    int NC, int H, int W, int Ho, int Wo) {
  int idx = blockIdx.x * TB + threadIdx.x;
  int total = NC * Ho * Wo;
  if (idx >= total) return;
  int wo = idx % Wo;
  int t = idx / Wo;
  int ho = t % Ho;
  int nc = t / Ho;
  const float* src = in + (size_t)nc * H * W;
  int y0 = 2 * ho - 1, x0 = 2 * wo - 1;
  float m = -INFINITY;
  for (int dy = 0; dy < 3; ++dy) {
    int y = y0 + dy;
    if (y < 0 || y >= H) continue;
    for (int dx = 0; dx < 3; ++dx) {
      int x = x0 + dx;
      if (x < 0 || x >= W) continue;
      m = fmaxf(m, src[(size_t)y * W + x]);
    }
  }
  out[idx] = m;
}

// ---------------- bilinear x2 upsample (jax.image.resize, half-pixel) ----------------
__global__ __launch_bounds__(256) void up2_k(
    const float* __restrict__ in, float* __restrict__ out,
    int N, int C, int H, int W, int ocoff, int ocstride) {
  int Ho = 2 * H, Wo = 2 * W;
  int total = N * C * Ho * Wo;
  int idx = blockIdx.x * TB + threadIdx.x;
  if (idx >= total) return;
  int xo = idx % Wo;
  int t = idx / Wo;
  int yo = t % Ho;
  t /= Ho;
  int c = t % C;
  int n = t / C;
  float sy = 0.5f * yo - 0.25f;
  float sx = 0.5f * xo - 0.25f;
  float y0f = floorf(sy), x0f = floorf(sx);
  float wy = sy - y0f, wx = sx - x0f;
  int y0 = (int)y0f, x0 = (int)x0f;
  int y0c = min(max(y0, 0), H - 1), y1c = min(max(y0 + 1, 0), H - 1);
  int x0c = min(max(x0, 0), W - 1), x1c = min(max(x0 + 1, 0), W - 1);
  const float* s = in + ((size_t)n * C + c) * H * W;
  float v = (1.f - wy) * ((1.f - wx) * s[(size_t)y0c * W + x0c] + wx * s[(size_t)y0c * W + x1c]) +
            wy * ((1.f - wx) * s[(size_t)y1c * W + x0c] + wx * s[(size_t)y1c * W + x1c]);
  out[(((size_t)n * ocstride + ocoff + c) * Ho + yo) * Wo + xo] = v;
}

// ---------------- CHW -> HWC transpose (C=16), LDS tiled ----------------
__global__ __launch_bounds__(256) void chw2hwc16_k(
    const float* __restrict__ src, float* __restrict__ dst, int HW) {
  __shared__ float t[16 * 65];
  int n = blockIdx.y;
  int p0 = blockIdx.x * 64;
  int tid = threadIdx.x;
  for (int e = tid; e < 1024; e += 256) {
    int c = e >> 6, j = e & 63;
    t[c * 65 + j] = src[((size_t)n * 16 + c) * HW + p0 + j];
  }
  __syncthreads();
  for (int e = tid; e < 1024; e += 256) {
    int j = e >> 4, c = e & 15;
    dst[((size_t)n * HW + p0 + j) * 16 + c] = t[c * 65 + j];
  }
}

// ---------------- deform weight reorder: (O,16,9) -> (9,16,O) ----------------
__global__ __launch_bounds__(256) void wreorder_k(
    const float* __restrict__ a, const float* __restrict__ b,
    const float* __restrict__ c, const float* __restrict__ d,
    float* __restrict__ out) {
  int t = blockIdx.x * 256 + threadIdx.x;
  if (t < 6912) {
    int which = t / 2304, r = t % 2304;
    int o = r % 16, kc = r / 16;
    int ci = kc % 16, k = kc / 16;
    const float* w = which == 0 ? a : (which == 1 ? b : c);
    out[t] = w[(o * 16 + ci) * 9 + k];
  } else if (t < 7200) {
    int r = t - 6912;
    int o = r % 2, kc = r / 2;
    int ci = kc % 16, k = kc / 16;
    out[t] = d[(o * 16 + ci) * 9 + k];
  }
}

// ---------------- conv weight reorder: (O,C,9) -> (C,9,O) ----------------
struct WEntry { const float* src; int cin; int cout; int dstoff; };
struct WTable { WEntry e[20]; };  // 18 used
__global__ __launch_bounds__(256) void wreorder_conv_k(WTable t, float* __restrict__ out) {
  WEntry en = t.e[blockIdx.y];
  int total = en.cin * en.cout * 9;
  int i = blockIdx.x * 256 + threadIdx.x;
  if (i >= total) return;
  int o = i % en.cout;
  int ck = i / en.cout;
  int k = ck % 9;
  int c = ck / 9;
  out[en.dstoff + i] = en.src[((size_t)o * en.cin + c) * 9 + k];
}

// ---------------- fused FE level-0: conv(1->16)+relu -> conv(16->16)+relu -> pool ----------------
// One block = 8x8 pool-out tile @256^2 (17x17 conv2 region, 19x19 conv1, 21x21 input @512^2).
// conv1 zeroed at image-invalid positions == zero-pad semantics for conv2; pool bounds-checked.
__global__ __launch_bounds__(256) void fe0_fused_k(
    const float* __restrict__ refI, const float* __restrict__ unrI,
    const float* __restrict__ w1, const float* __restrict__ b1,
    const float* __restrict__ w2ro, const float* __restrict__ b2,
    float* __restrict__ outR, float* __restrict__ outU) {
  __shared__ float c1buf[16 * 361];  // conv1 out, plane-major 19x19
  __shared__ float sbuf[16 * 289];   // phase1: inbuf(441); phase3: c2buf(4624)
  const int z = blockIdx.z;          // im*4 + n
  const int im = z >> 2, n = z & 3;
  const float* img = (im ? unrI : refI) + (size_t)n * 512 * 512;
  float* outp = (im ? outU : outR) + (size_t)n * 16 * 256 * 256;
  const int py0 = blockIdx.y * 8, px0 = blockIdx.x * 8;
  const int tid = threadIdx.x;

  // stage input 21x21 (rows 2*py0-3 .. +17)
  float* inbuf = sbuf;
  for (int i = tid; i < 441; i += 256) {
    int yi = i / 21, xi = i - yi * 21;
    int gy = 2 * py0 - 3 + yi, gx = 2 * px0 - 3 + xi;
    float v = 0.f;
    if (gy >= 0 && gy < 512 && gx >= 0 && gx < 512) v = img[gy * 512 + gx];
    inbuf[i] = v;
  }
  __syncthreads();

  // conv1: 19x19 x16 (rows 2*py0-2 .. +16); 0 where globally invalid
  for (int p = tid; p < 361; p += 256) {
    int y1 = p / 19, x1 = p - y1 * 19;
    int gy = 2 * py0 - 2 + y1, gx = 2 * px0 - 2 + x1;
    bool valid = (gy >= 0 && gy < 512 && gx >= 0 && gx < 512);
    float t[9];
#pragma unroll
    for (int k = 0; k < 9; ++k) t[k] = inbuf[(y1 + k / 3) * 21 + x1 + (k % 3)];
#pragma unroll
    for (int c = 0; c < 16; ++c) {
      float a = b1[c];
#pragma unroll
      for (int k = 0; k < 9; ++k) a = fmaf(t[k], w1[c * 9 + k], a);
      c1buf[c * 361 + p] = valid ? fmaxf(a, 0.f) : 0.f;
    }
  }
  __syncthreads();

  // conv2: 17x17 x16 (rows 2*py0-1 .. +15) into c2buf (overlays inbuf)
  float* c2buf = sbuf;
  for (int p = tid; p < 289; p += 256) {
    int y2 = p / 17, x2 = p - y2 * 17;
    float acc[16];
#pragma unroll
    for (int o = 0; o < 16; ++o) acc[o] = b2[o];
    for (int ci = 0; ci < 16; ++ci) {
      const float* ld = c1buf + ci * 361 + y2 * 19 + x2;
      float v[9];
#pragma unroll
      for (int k = 0; k < 9; ++k) v[k] = ld[(k / 3) * 19 + (k % 3)];
      const float* wc = w2ro + ci * 144;
#pragma unroll
      for (int k = 0; k < 9; ++k)
#pragma unroll
        for (int o = 0; o < 16; ++o)
          acc[o] = fmaf(v[k], wc[k * 16 + o], acc[o]);
    }
#pragma unroll
    for (int o = 0; o < 16; ++o) c2buf[o * 289 + p] = fmaxf(acc[o], 0.f);
  }
  __syncthreads();

  // maxpool 3x3 s2 p1 -> 8x8 x16, bounds-checked in 512-space
  for (int i = tid; i < 1024; i += 256) {
    int c = i >> 6, r = i & 63, py = r >> 3, px = r & 7;
    float m = -INFINITY;
#pragma unroll
    for (int dy = 0; dy < 3; ++dy) {
      int gy = 2 * (py0 + py) - 1 + dy;
      if (gy < 0 || gy >= 512) continue;
#pragma unroll
      for (int dx = 0; dx < 3; ++dx) {
        int gx = 2 * (px0 + px) - 1 + dx;
        if (gx < 0 || gx >= 512) continue;
        m = fmaxf(m, c2buf[c * 289 + (2 * py + dy) * 17 + 2 * px + dx]);
      }
    }
    outp[((size_t)c * 256 + py0 + py) * 256 + px0 + px] = m;
  }
}

// ---------------- 3x3 conv v3 (R7-proven): 16x16 tile, chunked staging ----------------
template <int L, int COUT>
__device__ __forceinline__ void conv_inner(const float* __restrict__ lds,
                                           const float* __restrict__ wc0,
                                           float* __restrict__ acc, int ty, int tx) {
#pragma unroll
  for (int c = 0; c < L; ++c) {
    const float* ld = lds + c * (18 * 24) + ty * 24 + tx;
    float v[3][3];
#pragma unroll
    for (int dy = 0; dy < 3; ++dy)
#pragma unroll
      for (int dx = 0; dx < 3; ++dx) v[dy][dx] = ld[dy * 24 + dx];
    const float* wc = wc0 + c * 9 * COUT;
#pragma unroll
    for (int k = 0; k < 9; ++k) {
#pragma unroll
      for (int o = 0; o < COUT; ++o)
        acc[o] = fmaf(v[k / 3][k % 3], wc[k * COUT + o], acc[o]);
    }
  }
}

template <int CIN0, int CIN1, int COUT>
__global__ __launch_bounds__(256) void conv3x3_v3(
    const float* __restrict__ in0, const float* __restrict__ in1,
    const float* __restrict__ wro, const float* __restrict__ bias,
    float* __restrict__ out, int H, int W, int relu, int ocoff, int ocstride) {
  constexpr int CIN = CIN0 + CIN1;
  constexpr int CH = (CIN < 8) ? CIN : 8;
  constexpr int NPASS = (CIN + CH - 1) / CH;
  constexpr int LAST = CIN - (NPASS - 1) * CH;
  __shared__ float lds[CH * 18 * 24];
  const int n = blockIdx.z;
  const int bx = blockIdx.x * 16, by = blockIdx.y * 16;
  const int tx = threadIdx.x, ty = threadIdx.y;
  const int tid = ty * 16 + tx;
  const float* i0 = in0 + (size_t)n * CIN0 * H * W;
  const float* i1 = in1 + (size_t)n * CIN1 * H * W;
  float acc[COUT];
#pragma unroll
  for (int o = 0; o < COUT; ++o) acc[o] = bias ? bias[o] : 0.f;

  for (int pass = 0; pass < NPASS; ++pass) {
    const int c0 = pass * CH;
    const int L = (pass < NPASS - 1) ? CH : LAST;
    if (pass) __syncthreads();
    for (int idx = tid; idx < L * 324; idx += 256) {
      int c = idx / 324;
      int r = idx - c * 324;
      int ly = r / 18, lx = r - ly * 18;
      int gy = by + ly - 1, gx = bx + lx - 1;
      int gc = c0 + c;
      float v = 0.f;
      if (gy >= 0 && gy < H && gx >= 0 && gx < W)
        v = (gc < CIN0) ? i0[((size_t)gc * H + gy) * W + gx]
                        : i1[((size_t)(gc - CIN0) * H + gy) * W + gx];
      lds[c * (18 * 24) + ly * 24 + lx] = v;
    }
    __syncthreads();
    const float* wc0 = wro + (size_t)c0 * 9 * COUT;
    if (pass < NPASS - 1)
      conv_inner<CH, COUT>(lds, wc0, acc, ty, tx);
    else
      conv_inner<LAST, COUT>(lds, wc0, acc, ty, tx);
  }

  const int h = by + ty, x = bx + tx;
#pragma unroll
  for (int o = 0; o < COUT; ++o) {
    float r = acc[o];
    if (relu) r = fmaxf(r, 0.f);
    out[(((size_t)n * ocstride + ocoff + o) * H + h) * W + x] = r;
  }
}

// ---------------- deformable 3x3 conv: HWC input, (k,c,o) weights, XCD swizzle ----------------
template <int COUT, int DG>
__global__ __launch_bounds__(256) void deform_v3(
    const float* __restrict__ inHWC, const float* __restrict__ off,
    const float* __restrict__ wt, float* __restrict__ out,
    int H, int W, int relu, int ocoff, int ocstride) {
  constexpr int CIN = 16;
  constexpr int CG = CIN / DG;
  const int n = blockIdx.y;
  const int HWt = H * W;
  const int nbx = gridDim.x;
  int bxs = blockIdx.x;
  bxs = (bxs & 7) * (nbx >> 3) + (bxs >> 3);  // XCD-contiguous band mapping
  const int hw = bxs * 256 + threadIdx.x;
  const int h = hw / W, w = hw - h * W;
  const float* inN = inHWC + (size_t)n * HWt * CIN;
  const float* offN = off + (size_t)n * (DG * 18) * HWt + hw;
  float acc[COUT];
#pragma unroll
  for (int o = 0; o < COUT; ++o) acc[o] = 0.f;
#pragma unroll
  for (int g = 0; g < DG; ++g) {
#pragma unroll
    for (int k = 0; k < 9; ++k) {
      const int ky = k / 3 - 1, kx = k % 3 - 1;
      float oy = offN[(size_t)((g * 9 + k) * 2 + 0) * HWt];
      float ox = offN[(size_t)((g * 9 + k) * 2 + 1) * HWt];
      float py = (float)(h + ky) + oy;
      float px = (float)(w + kx) + ox;
      float y0f = floorf(py), x0f = floorf(px);
      float fy = py - y0f, fx = px - x0f;
      int y0 = (int)y0f, x0 = (int)x0f;
      bool vy0 = ((unsigned)y0 < (unsigned)H);
      bool vy1 = ((unsigned)(y0 + 1) < (unsigned)H);
      bool vx0 = ((unsigned)x0 < (unsigned)W);
      bool vx1 = ((unsigned)(x0 + 1) < (unsigned)W);
      int y0c = min(max(y0, 0), H - 1), y1c = min(max(y0 + 1, 0), H - 1);
      int x0c = min(max(x0, 0), W - 1), x1c = min(max(x0 + 1, 0), W - 1);
      float w00 = (vy0 && vx0) ? (1.f - fy) * (1.f - fx) : 0.f;
      float w01 = (vy0 && vx1) ? (1.f - fy) * fx : 0.f;
      float w10 = (vy1 && vx0) ? fy * (1.f - fx) : 0.f;
      float w11 = (vy1 && vx1) ? fy * fx : 0.f;
      const float* p00 = inN + ((size_t)y0c * W + x0c) * CIN + g * CG;
      const float* p01 = inN + ((size_t)y0c * W + x1c) * CIN + g * CG;
      const float* p10 = inN + ((size_t)y1c * W + x0c) * CIN + g * CG;
      const float* p11 = inN + ((size_t)y1c * W + x1c) * CIN + g * CG;
      const float* wk = wt + (k * CIN + g * CG) * COUT;
#pragma unroll
      for (int c4 = 0; c4 < CG / 4; ++c4) {
        float4 a00 = *(const float4*)(p00 + c4 * 4);
        float4 a01 = *(const float4*)(p01 + c4 * 4);
        float4 a10 = *(const float4*)(p10 + c4 * 4);
        float4 a11 = *(const float4*)(p11 + c4 * 4);
        float v0 = w00 * a00.x + w01 * a01.x + w10 * a10.x + w11 * a11.x;
        float v1 = w00 * a00.y + w01 * a01.y + w10 * a10.y + w11 * a11.y;
        float v2 = w00 * a00.z + w01 * a01.z + w10 * a10.z + w11 * a11.z;
        float v3 = w00 * a00.w + w01 * a01.w + w10 * a10.w + w11 * a11.w;
#pragma unroll
        for (int o = 0; o < COUT; ++o) {
          float t0 = fmaf(v0, wk[(c4 * 4 + 0) * COUT + o], acc[o]);
          t0 = fmaf(v1, wk[(c4 * 4 + 1) * COUT + o], t0);
          t0 = fmaf(v2, wk[(c4 * 4 + 2) * COUT + o], t0);
          acc[o] = fmaf(v3, wk[(c4 * 4 + 3) * COUT + o], t0);
        }
      }
    }
  }
  float* outN = out + ((size_t)n * ocstride + ocoff) * HWt + hw;
#pragma unroll
  for (int o = 0; o < COUT; ++o) {
    float r = acc[o];
    if (relu) r = fmaxf(r, 0.f);
    outN[(size_t)o * HWt] = r;
  }
}

// ---------------- host-side launch helpers ----------------
template <int C0, int C1, int CO>
static void LC(hipStream_t s, const float* a, const float* b, const float* w,
               const float* bi, float* o, int N, int H, int W, bool relu,
               int ocoff, int ocstride) {
  conv3x3_v3<C0, C1, CO><<<dim3(W / 16, H / 16, N), dim3(16, 16), 0, s>>>(
      a, b, w, bi, o, H, W, relu ? 1 : 0, ocoff, ocstride);
}

static void L_deform3(hipStream_t s, const float* inHWC, const float* off, const float* wt,
                      float* out, int N, int H, int W, int dg, int Cout, bool relu,
                      int ocoff, int ocstride) {
  dim3 grd(H * W / 256, N);
  int r = relu ? 1 : 0;
  if (Cout == 16 && dg == 1)
    deform_v3<16, 1><<<grd, 256, 0, s>>>(inHWC, off, wt, out, H, W, r, ocoff, ocstride);
  else if (Cout == 2 && dg == 2)
    deform_v3<2, 2><<<grd, 256, 0, s>>>(inHWC, off, wt, out, H, W, r, ocoff, ocstride);
}

static void L_hwc(hipStream_t s, const float* src, float* dst, int N, int HW) {
  dim3 grd(HW / 64, N);
  chw2hwc16_k<<<grd, 256, 0, s>>>(src, dst, HW);
}

static void L_pool(hipStream_t s, const float* in, float* out, int NC, int H, int W) {
  int Ho = H / 2, Wo = W / 2;
  int total = NC * Ho * Wo;
  maxpool3s2_k<<<(total + TB - 1) / TB, TB, 0, s>>>(in, out, NC, H, W, Ho, Wo);
}

static void L_up2(hipStream_t s, const float* in, float* out, int N, int C, int H, int W,
                  int ocoff, int ocstride) {
  int total = N * C * 4 * H * W;
  up2_k<<<(total + TB - 1) / TB, TB, 0, s>>>(in, out, N, C, H, W, ocoff, ocstride);
}

extern "C" void kernel_launch(void* const* d_in, const int* in_sizes, int n_in,
                              void* d_out, int out_size, void* d_ws, size_t ws_size,
                              hipStream_t stream) {
  auto F = [&](int i) { return (const float*)d_in[i]; };
  const float* ref = F(0);
  const float* unr = F(1);
  const float* few1[3] = {F(2), F(6), F(10)};
  const float* feb1[3] = {F(3), F(7), F(11)};
  const float* few2[3] = {F(4), F(8), F(12)};
  const float* feb2[3] = {F(5), F(9), F(13)};
  const float* obw[3] = {F(14), F(16), F(18)};
  const float* obb[3] = {F(15), F(17), F(19)};
  const float* ogw[3] = {F(20), F(22), F(24)};
  const float* ogb[3] = {F(21), F(23), F(25)};
  const float* dcw[3] = {F(26), F(27), F(28)};
  const float* fcw[3] = {F(29), F(31), F(33)};
  const float* fcb[3] = {F(30), F(32), F(34)};
  const float* dobw = F(35);
  const float* dobb = F(36);
  const float* dogw = F(37);
  const float* dogb = F(38);
  const float* ddcw = F(39);

  // ---- workspace layout (floats) ----
  float* ws = (float*)d_ws;
  size_t p = 0;
  auto alloc = [&](size_t nf) { float* r = ws + p; p += nf; return r; };
  const size_t SC = 9437184;
  float* A = alloc(SC);
  float* Bf = alloc(SC);
  float* rf[3], *uf[3], *offs[3], *feats[3];
  rf[0] = alloc((size_t)4 * 16 * 256 * 256);
  uf[0] = alloc((size_t)4 * 16 * 256 * 256);
  rf[1] = alloc((size_t)4 * 16 * 128 * 128);
  uf[1] = alloc((size_t)4 * 16 * 128 * 128);
  rf[2] = alloc((size_t)4 * 16 * 64 * 64);
  uf[2] = alloc((size_t)4 * 16 * 64 * 64);
  offs[0] = alloc((size_t)4 * 18 * 256 * 256);
  offs[1] = alloc((size_t)4 * 18 * 128 * 128);
  offs[2] = alloc((size_t)4 * 18 * 64 * 64);
  feats[0] = alloc((size_t)4 * 16 * 256 * 256);
  feats[1] = alloc((size_t)4 * 16 * 128 * 128);
  feats[2] = alloc((size_t)4 * 16 * 64 * 64);
  float* wt = alloc(7200);
  float* cw = alloc(70000);
  if (p * sizeof(float) > ws_size) return;
  const float* wt_dc[3] = {wt, wt + 2304, wt + 4608};
  const float* wt_ddc = wt + 6912;

  // ---- build conv weight reorder table ----
  WTable T;
  int nw = 0, woff = 0, maxtot = 0;
  auto addw = [&](const float* src, int cin, int cout) {
    T.e[nw].src = src; T.e[nw].cin = cin; T.e[nw].cout = cout; T.e[nw].dstoff = woff;
    int tot = cin * cout * 9;
    if (tot > maxtot) maxtot = tot;
    int start = woff;
    woff += tot;
    ++nw;
    return start;
  };
  int o_few1[3], o_few2[3], o_ob[3], o_og[3], o_fc[3], o_dob, o_dog0, o_dog1;
  for (int i = 0; i < 3; ++i) o_few1[i] = addw(few1[i], i == 0 ? 1 : 16, 16);
  for (int i = 0; i < 3; ++i) o_few2[i] = addw(few2[i], 16, 16);
  for (int i = 0; i < 3; ++i) o_ob[i] = addw(obw[i], 32, 16);
  o_og[0] = addw(ogw[0], 34, 18);
  o_og[1] = addw(ogw[1], 34, 18);
  o_og[2] = addw(ogw[2], 16, 18);
  for (int i = 0; i < 3; ++i) o_fc[i] = addw(fcw[i], i == 2 ? 16 : 32, 16);
  o_dob = addw(dobw, 32, 16);
  o_dog0 = addw(dogw, 34, 18);
  o_dog1 = addw(dogw + (size_t)18 * 34 * 9, 34, 18);

  wreorder_k<<<29, 256, 0, stream>>>(dcw[0], dcw[1], dcw[2], ddcw, wt);
  wreorder_conv_k<<<dim3((maxtot + 255) / 256, nw), 256, 0, stream>>>(T, cw);

  // ---- FE level 0: single fused launch (conv1+conv2+pool, both images, N=4) ----
  fe0_fused_k<<<dim3(32, 32, 8), 256, 0, stream>>>(
      ref, unr, few1[0], feb1[0], cw + o_few2[0], feb2[0], rf[0], uf[0]);

  // ---- FE levels 1/2 (v3 convs, N=4) ----
  const float* imgs[2] = {ref, unr};
  float** pyr[2] = {rf, uf};
  for (int im = 0; im < 2; ++im) {
    LC<16, 0, 16>(stream, pyr[im][0], nullptr, cw + o_few1[1], feb1[1], A, 4, 256, 256, true, 0, 16);
    LC<16, 0, 16>(stream, A, nullptr, cw + o_few2[1], feb2[1], Bf, 4, 256, 256, true, 0, 16);
    L_pool(stream, Bf, pyr[im][1], 4 * 16, 256, 256);
    LC<16, 0, 16>(stream, pyr[im][1], nullptr, cw + o_few1[2], feb1[2], A, 4, 128, 128, true, 0, 16);
    LC<16, 0, 16>(stream, A, nullptr, cw + o_few2[2], feb2[2], Bf, 4, 128, 128, true, 0, 16);
    L_pool(stream, Bf, pyr[im][2], 4 * 16, 128, 128);
  }

  // ---- coarse-to-fine alignment ----
  int Hs[3] = {256, 128, 64};
  for (int i = 2; i >= 0; --i) {
    int H = Hs[i];
    int hw = H * H;
    float* oBuf = Bf;                       // 16ch compact
    float* upo = Bf + (size_t)4 * 16 * hw;  // 18ch compact (i<2)
    float* hwcB = A;                        // HWC of uf[i]
    float* fBuf = A + (size_t)4 * 16 * hw;  // 16ch compact
    if (i == 2) {
      LC<16, 16, 16>(stream, rf[2], uf[2], cw + o_ob[2], obb[2], oBuf, 4, H, H, true, 0, 16);
      LC<16, 0, 18>(stream, oBuf, nullptr, cw + o_og[2], ogb[2], offs[2], 4, H, H, true, 0, 18);
      L_hwc(stream, uf[2], hwcB, 4, hw);
      L_deform3(stream, hwcB, offs[2], wt_dc[2], fBuf, 4, H, H, 1, 16, true, 0, 16);
      LC<16, 0, 16>(stream, fBuf, nullptr, cw + o_fc[2], fcb[2], feats[2], 4, H, H, true, 0, 16);
    } else {
      LC<16, 16, 16>(stream, rf[i], uf[i], cw + o_ob[i], obb[i], oBuf, 4, H, H, true, 0, 16);
      L_up2(stream, offs[i + 1], upo, 4, 18, H / 2, H / 2, 0, 18);
      LC<16, 18, 18>(stream, oBuf, upo, cw + o_og[i], ogb[i], offs[i], 4, H, H, true, 0, 18);
      L_hwc(stream, uf[i], hwcB, 4, hw);
      L_deform3(stream, hwcB, offs[i], wt_dc[i], fBuf, 4, H, H, 1, 16, true, 0, 16);
      L_up2(stream, feats[i + 1], uf[i], 4, 16, H / 2, H / 2, 0, 16);  // uf[i] is dead
      LC<16, 16, 16>(stream, fBuf, uf[i], cw + o_fc[i], fcb[i], feats[i], 4, H, H, true, 0, 16);
    }
  }

  // ---- final offset head + deform (dg=2) ----
  const int hw0 = 256 * 256;
  float* doBuf = Bf;  // 16ch
  LC<16, 16, 16>(stream, rf[0], feats[0], cw + o_dob, dobb, doBuf, 4, 256, 256, false, 0, 16);
  LC<16, 18, 18>(stream, doBuf, offs[0], cw + o_dog0, dogb, A, 4, 256, 256, false, 0, 36);
  LC<16, 18, 18>(stream, doBuf, offs[0], cw + o_dog1, dogb + 18, A, 4, 256, 256, false, 18, 36);
  float* fHwc = Bf + (size_t)4 * 16 * hw0;  // doBuf consumed
  L_hwc(stream, feats[0], fHwc, 4, hw0);
  L_deform3(stream, fHwc, A, wt_ddc, (float*)d_out, 4, 256, 256, 2, 2, false, 0, 2);
}

// Round 10
// 1238.573 us; speedup vs baseline: 1.2906x; 1.0958x over previous
//
#include <hip/hip_runtime.h>
#include <math.h>

#define TB 256

// ---------------- maxpool 3x3 stride2 pad1 (levels 1/2) ----------------
__global__ __launch_bounds__(256) void maxpool3s2_k(
    const float* __restrict__ in, float* __restrict__ out,
    int NC, int H, int W, int Ho, int Wo) {
  int idx = blockIdx.x * TB + threadIdx.x;
  int total = NC * Ho * Wo;
  if (idx >= total) return;
  int wo = idx % Wo;
  int t = idx / Wo;
  int ho = t % Ho;
  int nc = t / Ho;
  const float* src = in + (size_t)nc * H * W;
  int y0 = 2 * ho - 1, x0 = 2 * wo - 1;
  float m = -INFINITY;
  for (int dy = 0; dy < 3; ++dy) {
    int y = y0 + dy;
    if (y < 0 || y >= H) continue;
    for (int dx = 0; dx < 3; ++dx) {
      int x = x0 + dx;
      if (x < 0 || x >= W) continue;
      m = fmaxf(m, src[(size_t)y * W + x]);
    }
  }
  out[idx] = m;
}

// ---------------- CHW -> HWC transpose (C=16), LDS tiled ----------------
__global__ __launch_bounds__(256) void chw2hwc16_k(
    const float* __restrict__ src, float* __restrict__ dst, int HW) {
  __shared__ float t[16 * 65];
  int n = blockIdx.y;
  int p0 = blockIdx.x * 64;
  int tid = threadIdx.x;
  for (int e = tid; e < 1024; e += 256) {
    int c = e >> 6, j = e & 63;
    t[c * 65 + j] = src[((size_t)n * 16 + c) * HW + p0 + j];
  }
  __syncthreads();
  for (int e = tid; e < 1024; e += 256) {
    int j = e >> 4, c = e & 15;
    dst[((size_t)n * HW + p0 + j) * 16 + c] = t[c * 65 + j];
  }
}

// ---------------- deform weight reorder: (O,16,9) -> (9,16,O) ----------------
__global__ __launch_bounds__(256) void wreorder_k(
    const float* __restrict__ a, const float* __restrict__ b,
    const float* __restrict__ c, const float* __restrict__ d,
    float* __restrict__ out) {
  int t = blockIdx.x * 256 + threadIdx.x;
  if (t < 6912) {
    int which = t / 2304, r = t % 2304;
    int o = r % 16, kc = r / 16;
    int ci = kc % 16, k = kc / 16;
    const float* w = which == 0 ? a : (which == 1 ? b : c);
    out[t] = w[(o * 16 + ci) * 9 + k];
  } else if (t < 7200) {
    int r = t - 6912;
    int o = r % 2, kc = r / 2;
    int ci = kc % 16, k = kc / 16;
    out[t] = d[(o * 16 + ci) * 9 + k];
  }
}

// ---------------- conv weight reorder: (O,C,9) -> (C,9,O) ----------------
struct WEntry { const float* src; int cin; int cout; int dstoff; };
struct WTable { WEntry e[20]; };  // 18 used
__global__ __launch_bounds__(256) void wreorder_conv_k(WTable t, float* __restrict__ out) {
  WEntry en = t.e[blockIdx.y];
  int total = en.cin * en.cout * 9;
  int i = blockIdx.x * 256 + threadIdx.x;
  if (i >= total) return;
  int o = i % en.cout;
  int ck = i / en.cout;
  int k = ck % 9;
  int c = ck / 9;
  out[en.dstoff + i] = en.src[((size_t)o * en.cin + c) * 9 + k];
}

// ---------------- fused FE level-0 (R9-proven): conv1+relu -> conv2+relu -> pool ----------------
__global__ __launch_bounds__(256) void fe0_fused_k(
    const float* __restrict__ refI, const float* __restrict__ unrI,
    const float* __restrict__ w1, const float* __restrict__ b1,
    const float* __restrict__ w2ro, const float* __restrict__ b2,
    float* __restrict__ outR, float* __restrict__ outU) {
  __shared__ float c1buf[16 * 361];  // conv1 out, plane-major 19x19
  __shared__ float sbuf[16 * 289];   // phase1: inbuf(441); phase3: c2buf(4624)
  const int z = blockIdx.z;          // im*4 + n
  const int im = z >> 2, n = z & 3;
  const float* img = (im ? unrI : refI) + (size_t)n * 512 * 512;
  float* outp = (im ? outU : outR) + (size_t)n * 16 * 256 * 256;
  const int py0 = blockIdx.y * 8, px0 = blockIdx.x * 8;
  const int tid = threadIdx.x;

  float* inbuf = sbuf;
  for (int i = tid; i < 441; i += 256) {
    int yi = i / 21, xi = i - yi * 21;
    int gy = 2 * py0 - 3 + yi, gx = 2 * px0 - 3 + xi;
    float v = 0.f;
    if (gy >= 0 && gy < 512 && gx >= 0 && gx < 512) v = img[gy * 512 + gx];
    inbuf[i] = v;
  }
  __syncthreads();

  for (int p = tid; p < 361; p += 256) {
    int y1 = p / 19, x1 = p - y1 * 19;
    int gy = 2 * py0 - 2 + y1, gx = 2 * px0 - 2 + x1;
    bool valid = (gy >= 0 && gy < 512 && gx >= 0 && gx < 512);
    float t[9];
#pragma unroll
    for (int k = 0; k < 9; ++k) t[k] = inbuf[(y1 + k / 3) * 21 + x1 + (k % 3)];
#pragma unroll
    for (int c = 0; c < 16; ++c) {
      float a = b1[c];
#pragma unroll
      for (int k = 0; k < 9; ++k) a = fmaf(t[k], w1[c * 9 + k], a);
      c1buf[c * 361 + p] = valid ? fmaxf(a, 0.f) : 0.f;
    }
  }
  __syncthreads();

  float* c2buf = sbuf;
  for (int p = tid; p < 289; p += 256) {
    int y2 = p / 17, x2 = p - y2 * 17;
    float acc[16];
#pragma unroll
    for (int o = 0; o < 16; ++o) acc[o] = b2[o];
    for (int ci = 0; ci < 16; ++ci) {
      const float* ld = c1buf + ci * 361 + y2 * 19 + x2;
      float v[9];
#pragma unroll
      for (int k = 0; k < 9; ++k) v[k] = ld[(k / 3) * 19 + (k % 3)];
      const float* wc = w2ro + ci * 144;
#pragma unroll
      for (int k = 0; k < 9; ++k)
#pragma unroll
        for (int o = 0; o < 16; ++o)
          acc[o] = fmaf(v[k], wc[k * 16 + o], acc[o]);
    }
#pragma unroll
    for (int o = 0; o < 16; ++o) c2buf[o * 289 + p] = fmaxf(acc[o], 0.f);
  }
  __syncthreads();

  for (int i = tid; i < 1024; i += 256) {
    int c = i >> 6, r = i & 63, py = r >> 3, px = r & 7;
    float m = -INFINITY;
#pragma unroll
    for (int dy = 0; dy < 3; ++dy) {
      int gy = 2 * (py0 + py) - 1 + dy;
      if (gy < 0 || gy >= 512) continue;
#pragma unroll
      for (int dx = 0; dx < 3; ++dx) {
        int gx = 2 * (px0 + px) - 1 + dx;
        if (gx < 0 || gx >= 512) continue;
        m = fmaxf(m, c2buf[c * 289 + (2 * py + dy) * 17 + 2 * px + dx]);
      }
    }
    outp[((size_t)c * 256 + py0 + py) * 256 + px0 + px] = m;
  }
}

// ---------------- 3x3 conv v6: v3's proven structure + fused-up2 in1 + z-split weights ----------------
// UP1=1: in1 is a compact (N,CIN1,H/2,W/2) buffer, staged through the verified
// jax half-pixel bilinear (clamp-replicate) — removes the standalone up2 pass.
// z-split: blocks with blockIdx.z >= zN use (wroB,biasB,ocoffB) — merges the two
// dog 18-out halves into one launch.
template <int L, int COUT>
__device__ __forceinline__ void conv_inner(const float* __restrict__ lds,
                                           const float* __restrict__ wc0,
                                           float* __restrict__ acc, int ty, int tx) {
#pragma unroll
  for (int c = 0; c < L; ++c) {
    const float* ld = lds + c * (18 * 24) + ty * 24 + tx;
    float v[3][3];
#pragma unroll
    for (int dy = 0; dy < 3; ++dy)
#pragma unroll
      for (int dx = 0; dx < 3; ++dx) v[dy][dx] = ld[dy * 24 + dx];
    const float* wc = wc0 + c * 9 * COUT;
#pragma unroll
    for (int k = 0; k < 9; ++k) {
#pragma unroll
      for (int o = 0; o < COUT; ++o)
        acc[o] = fmaf(v[k / 3][k % 3], wc[k * COUT + o], acc[o]);
    }
  }
}

template <int CIN0, int CIN1, int UP1, int COUT>
__global__ __launch_bounds__(256) void conv3x3_v6(
    const float* __restrict__ in0, const float* __restrict__ in1,
    const float* __restrict__ wro, const float* __restrict__ bias,
    float* __restrict__ out, int H, int W, int relu, int ocoff, int ocstride,
    const float* __restrict__ wroB, const float* __restrict__ biasB,
    int ocoffB, int zN) {
  constexpr int CIN = CIN0 + CIN1;
  constexpr int CH = (CIN < 8) ? CIN : 8;
  constexpr int NPASS = (CIN + CH - 1) / CH;
  constexpr int LAST = CIN - (NPASS - 1) * CH;
  __shared__ float lds[CH * 18 * 24];
  int n = blockIdx.z;
  if (n >= zN) {  // second weight set (dog half 1)
    n -= zN;
    wro = wroB;
    bias = biasB;
    ocoff = ocoffB;
  }
  const int bx = blockIdx.x * 16, by = blockIdx.y * 16;
  const int tx = threadIdx.x, ty = threadIdx.y;
  const int tid = ty * 16 + tx;
  const int H2 = H >> 1, W2 = W >> 1;
  const float* i0 = in0 + (size_t)n * CIN0 * H * W;
  const float* i1 = in1 ? in1 + (size_t)n * CIN1 * (UP1 ? H2 * W2 : H * W) : nullptr;
  float acc[COUT];
#pragma unroll
  for (int o = 0; o < COUT; ++o) acc[o] = bias ? bias[o] : 0.f;

  for (int pass = 0; pass < NPASS; ++pass) {
    const int c0 = pass * CH;
    const int L = (pass < NPASS - 1) ? CH : LAST;
    if (pass) __syncthreads();
    for (int idx = tid; idx < L * 324; idx += 256) {
      int c = idx / 324;
      int r = idx - c * 324;
      int ly = r / 18, lx = r - ly * 18;
      int gy = by + ly - 1, gx = bx + lx - 1;
      int gc = c0 + c;
      float v = 0.f;
      if (gy >= 0 && gy < H && gx >= 0 && gx < W) {
        if (CIN1 == 0 || gc < CIN0) {
          v = i0[((size_t)gc * H + gy) * W + gx];
        } else if (!UP1) {
          v = i1[((size_t)(gc - CIN0) * H + gy) * W + gx];
        } else {  // on-the-fly bilinear x2 (half-pixel, clamp) — matches jax resize
          float sy = 0.5f * gy - 0.25f, sx = 0.5f * gx - 0.25f;
          float y0f = floorf(sy), x0f = floorf(sx);
          float wy = sy - y0f, wx = sx - x0f;
          int y0 = (int)y0f, x0 = (int)x0f;
          int y0c = min(max(y0, 0), H2 - 1), y1c = min(max(y0 + 1, 0), H2 - 1);
          int x0c = min(max(x0, 0), W2 - 1), x1c = min(max(x0 + 1, 0), W2 - 1);
          const float* sp = i1 + (size_t)(gc - CIN0) * H2 * W2;
          v = (1.f - wy) * ((1.f - wx) * sp[y0c * W2 + x0c] + wx * sp[y0c * W2 + x1c]) +
              wy * ((1.f - wx) * sp[y1c * W2 + x0c] + wx * sp[y1c * W2 + x1c]);
        }
      }
      lds[c * (18 * 24) + ly * 24 + lx] = v;
    }
    __syncthreads();
    const float* wc0 = wro + (size_t)c0 * 9 * COUT;
    if (pass < NPASS - 1)
      conv_inner<CH, COUT>(lds, wc0, acc, ty, tx);
    else
      conv_inner<LAST, COUT>(lds, wc0, acc, ty, tx);
  }

  const int h = by + ty, x = bx + tx;
#pragma unroll
  for (int o = 0; o < COUT; ++o) {
    float r = acc[o];
    if (relu) r = fmaxf(r, 0.f);
    out[(((size_t)n * ocstride + ocoff + o) * H + h) * W + x] = r;
  }
}

// ---------------- deformable 3x3 conv (R9-proven): HWC input, XCD swizzle ----------------
template <int COUT, int DG>
__global__ __launch_bounds__(256) void deform_v3(
    const float* __restrict__ inHWC, const float* __restrict__ off,
    const float* __restrict__ wt, float* __restrict__ out,
    int H, int W, int relu, int ocoff, int ocstride) {
  constexpr int CIN = 16;
  constexpr int CG = CIN / DG;
  const int n = blockIdx.y;
  const int HWt = H * W;
  const int nbx = gridDim.x;
  int bxs = blockIdx.x;
  bxs = (bxs & 7) * (nbx >> 3) + (bxs >> 3);  // XCD-contiguous band mapping
  const int hw = bxs * 256 + threadIdx.x;
  const int h = hw / W, w = hw - h * W;
  const float* inN = inHWC + (size_t)n * HWt * CIN;
  const float* offN = off + (size_t)n * (DG * 18) * HWt + hw;
  float acc[COUT];
#pragma unroll
  for (int o = 0; o < COUT; ++o) acc[o] = 0.f;
#pragma unroll
  for (int g = 0; g < DG; ++g) {
#pragma unroll
    for (int k = 0; k < 9; ++k) {
      const int ky = k / 3 - 1, kx = k % 3 - 1;
      float oy = offN[(size_t)((g * 9 + k) * 2 + 0) * HWt];
      float ox = offN[(size_t)((g * 9 + k) * 2 + 1) * HWt];
      float py = (float)(h + ky) + oy;
      float px = (float)(w + kx) + ox;
      float y0f = floorf(py), x0f = floorf(px);
      float fy = py - y0f, fx = px - x0f;
      int y0 = (int)y0f, x0 = (int)x0f;
      bool vy0 = ((unsigned)y0 < (unsigned)H);
      bool vy1 = ((unsigned)(y0 + 1) < (unsigned)H);
      bool vx0 = ((unsigned)x0 < (unsigned)W);
      bool vx1 = ((unsigned)(x0 + 1) < (unsigned)W);
      int y0c = min(max(y0, 0), H - 1), y1c = min(max(y0 + 1, 0), H - 1);
      int x0c = min(max(x0, 0), W - 1), x1c = min(max(x0 + 1, 0), W - 1);
      float w00 = (vy0 && vx0) ? (1.f - fy) * (1.f - fx) : 0.f;
      float w01 = (vy0 && vx1) ? (1.f - fy) * fx : 0.f;
      float w10 = (vy1 && vx0) ? fy * (1.f - fx) : 0.f;
      float w11 = (vy1 && vx1) ? fy * fx : 0.f;
      const float* p00 = inN + ((size_t)y0c * W + x0c) * CIN + g * CG;
      const float* p01 = inN + ((size_t)y0c * W + x1c) * CIN + g * CG;
      const float* p10 = inN + ((size_t)y1c * W + x0c) * CIN + g * CG;
      const float* p11 = inN + ((size_t)y1c * W + x1c) * CIN + g * CG;
      const float* wk = wt + (k * CIN + g * CG) * COUT;
#pragma unroll
      for (int c4 = 0; c4 < CG / 4; ++c4) {
        float4 a00 = *(const float4*)(p00 + c4 * 4);
        float4 a01 = *(const float4*)(p01 + c4 * 4);
        float4 a10 = *(const float4*)(p10 + c4 * 4);
        float4 a11 = *(const float4*)(p11 + c4 * 4);
        float v0 = w00 * a00.x + w01 * a01.x + w10 * a10.x + w11 * a11.x;
        float v1 = w00 * a00.y + w01 * a01.y + w10 * a10.y + w11 * a11.y;
        float v2 = w00 * a00.z + w01 * a01.z + w10 * a10.z + w11 * a11.z;
        float v3 = w00 * a00.w + w01 * a01.w + w10 * a10.w + w11 * a11.w;
#pragma unroll
        for (int o = 0; o < COUT; ++o) {
          float t0 = fmaf(v0, wk[(c4 * 4 + 0) * COUT + o], acc[o]);
          t0 = fmaf(v1, wk[(c4 * 4 + 1) * COUT + o], t0);
          t0 = fmaf(v2, wk[(c4 * 4 + 2) * COUT + o], t0);
          acc[o] = fmaf(v3, wk[(c4 * 4 + 3) * COUT + o], t0);
        }
      }
    }
  }
  float* outN = out + ((size_t)n * ocstride + ocoff) * HWt + hw;
#pragma unroll
  for (int o = 0; o < COUT; ++o) {
    float r = acc[o];
    if (relu) r = fmaxf(r, 0.f);
    outN[(size_t)o * HWt] = r;
  }
}

// ---------------- host-side launch helpers ----------------
template <int C0, int C1, int UP, int CO>
static void LC(hipStream_t s, const float* a, const float* b, const float* w,
               const float* bi, float* o, int N, int H, int W, bool relu,
               int ocoff, int ocstride,
               const float* wB = nullptr, const float* biB = nullptr, int ocoffB = 0) {
  int zn = wB ? 2 * N : N;
  conv3x3_v6<C0, C1, UP, CO><<<dim3(W / 16, H / 16, zn), dim3(16, 16), 0, s>>>(
      a, b, w, bi, o, H, W, relu ? 1 : 0, ocoff, ocstride, wB, biB, ocoffB, N);
}

static void L_deform3(hipStream_t s, const float* inHWC, const float* off, const float* wt,
                      float* out, int N, int H, int W, int dg, int Cout, bool relu,
                      int ocoff, int ocstride) {
  dim3 grd(H * W / 256, N);
  int r = relu ? 1 : 0;
  if (Cout == 16 && dg == 1)
    deform_v3<16, 1><<<grd, 256, 0, s>>>(inHWC, off, wt, out, H, W, r, ocoff, ocstride);
  else if (Cout == 2 && dg == 2)
    deform_v3<2, 2><<<grd, 256, 0, s>>>(inHWC, off, wt, out, H, W, r, ocoff, ocstride);
}

static void L_hwc(hipStream_t s, const float* src, float* dst, int N, int HW) {
  dim3 grd(HW / 64, N);
  chw2hwc16_k<<<grd, 256, 0, s>>>(src, dst, HW);
}

static void L_pool(hipStream_t s, const float* in, float* out, int NC, int H, int W) {
  int Ho = H / 2, Wo = W / 2;
  int total = NC * Ho * Wo;
  maxpool3s2_k<<<(total + TB - 1) / TB, TB, 0, s>>>(in, out, NC, H, W, Ho, Wo);
}

extern "C" void kernel_launch(void* const* d_in, const int* in_sizes, int n_in,
                              void* d_out, int out_size, void* d_ws, size_t ws_size,
                              hipStream_t stream) {
  auto F = [&](int i) { return (const float*)d_in[i]; };
  const float* ref = F(0);
  const float* unr = F(1);
  const float* few1[3] = {F(2), F(6), F(10)};
  const float* feb1[3] = {F(3), F(7), F(11)};
  const float* few2[3] = {F(4), F(8), F(12)};
  const float* feb2[3] = {F(5), F(9), F(13)};
  const float* obw[3] = {F(14), F(16), F(18)};
  const float* obb[3] = {F(15), F(17), F(19)};
  const float* ogw[3] = {F(20), F(22), F(24)};
  const float* ogb[3] = {F(21), F(23), F(25)};
  const float* dcw[3] = {F(26), F(27), F(28)};
  const float* fcw[3] = {F(29), F(31), F(33)};
  const float* fcb[3] = {F(30), F(32), F(34)};
  const float* dobw = F(35);
  const float* dobb = F(36);
  const float* dogw = F(37);
  const float* dogb = F(38);
  const float* ddcw = F(39);

  // ---- workspace layout (floats). rf[i]/uf[i] deliberately contiguous (N=8 batching). ----
  float* ws = (float*)d_ws;
  size_t p = 0;
  auto alloc = [&](size_t nf) { float* r = ws + p; p += nf; return r; };
  const size_t SC = 9437184;  // fits (8,16,256,256)=8.4M fl, (4,36,256,256)
  float* A = alloc(SC);
  float* Bf = alloc(SC);
  float* rf[3], *uf[3], *offs[3], *feats[3];
  rf[0] = alloc((size_t)4 * 16 * 256 * 256);
  uf[0] = alloc((size_t)4 * 16 * 256 * 256);
  rf[1] = alloc((size_t)4 * 16 * 128 * 128);
  uf[1] = alloc((size_t)4 * 16 * 128 * 128);
  rf[2] = alloc((size_t)4 * 16 * 64 * 64);
  uf[2] = alloc((size_t)4 * 16 * 64 * 64);
  offs[0] = alloc((size_t)4 * 18 * 256 * 256);
  offs[1] = alloc((size_t)4 * 18 * 128 * 128);
  offs[2] = alloc((size_t)4 * 18 * 64 * 64);
  feats[0] = alloc((size_t)4 * 16 * 256 * 256);
  feats[1] = alloc((size_t)4 * 16 * 128 * 128);
  feats[2] = alloc((size_t)4 * 16 * 64 * 64);
  float* wt = alloc(7200);
  float* cw = alloc(70000);
  if (p * sizeof(float) > ws_size) return;
  const float* wt_dc[3] = {wt, wt + 2304, wt + 4608};
  const float* wt_ddc = wt + 6912;

  // ---- build conv weight reorder table ----
  WTable T;
  int nw = 0, woff = 0, maxtot = 0;
  auto addw = [&](const float* src, int cin, int cout) {
    T.e[nw].src = src; T.e[nw].cin = cin; T.e[nw].cout = cout; T.e[nw].dstoff = woff;
    int tot = cin * cout * 9;
    if (tot > maxtot) maxtot = tot;
    int start = woff;
    woff += tot;
    ++nw;
    return start;
  };
  int o_few1[3], o_few2[3], o_ob[3], o_og[3], o_fc[3], o_dob, o_dog0, o_dog1;
  for (int i = 0; i < 3; ++i) o_few1[i] = addw(few1[i], i == 0 ? 1 : 16, 16);
  for (int i = 0; i < 3; ++i) o_few2[i] = addw(few2[i], 16, 16);
  for (int i = 0; i < 3; ++i) o_ob[i] = addw(obw[i], 32, 16);
  o_og[0] = addw(ogw[0], 34, 18);
  o_og[1] = addw(ogw[1], 34, 18);
  o_og[2] = addw(ogw[2], 16, 18);
  for (int i = 0; i < 3; ++i) o_fc[i] = addw(fcw[i], i == 2 ? 16 : 32, 16);
  o_dob = addw(dobw, 32, 16);
  o_dog0 = addw(dogw, 34, 18);
  o_dog1 = addw(dogw + (size_t)18 * 34 * 9, 34, 18);

  wreorder_k<<<29, 256, 0, stream>>>(dcw[0], dcw[1], dcw[2], ddcw, wt);
  wreorder_conv_k<<<dim3((maxtot + 255) / 256, nw), 256, 0, stream>>>(T, cw);

  // ---- FE level 0: single fused launch ----
  fe0_fused_k<<<dim3(32, 32, 8), 256, 0, stream>>>(
      ref, unr, few1[0], feb1[0], cw + o_few2[0], feb2[0], rf[0], uf[0]);

  // ---- FE levels 1/2, both images batched as N=8 (rf/uf contiguous) ----
  LC<16, 0, 0, 16>(stream, rf[0], nullptr, cw + o_few1[1], feb1[1], A, 8, 256, 256, true, 0, 16);
  LC<16, 0, 0, 16>(stream, A, nullptr, cw + o_few2[1], feb2[1], Bf, 8, 256, 256, true, 0, 16);
  L_pool(stream, Bf, rf[1], 8 * 16, 256, 256);
  LC<16, 0, 0, 16>(stream, rf[1], nullptr, cw + o_few1[2], feb1[2], A, 8, 128, 128, true, 0, 16);
  LC<16, 0, 0, 16>(stream, A, nullptr, cw + o_few2[2], feb2[2], Bf, 8, 128, 128, true, 0, 16);
  L_pool(stream, Bf, rf[2], 8 * 16, 128, 128);

  // ---- coarse-to-fine alignment (up2 fused into og/fc staging at i<2) ----
  int Hs[3] = {256, 128, 64};
  for (int i = 2; i >= 0; --i) {
    int H = Hs[i];
    int hw = H * H;
    float* oBuf = Bf;                       // 16ch compact
    float* hwcB = A;                        // HWC of uf[i]
    float* fBuf = A + (size_t)4 * 16 * hw;  // 16ch compact
    if (i == 2) {
      LC<16, 16, 0, 16>(stream, rf[2], uf[2], cw + o_ob[2], obb[2], oBuf, 4, H, H, true, 0, 16);
      LC<16, 0, 0, 18>(stream, oBuf, nullptr, cw + o_og[2], ogb[2], offs[2], 4, H, H, true, 0, 18);
      L_hwc(stream, uf[2], hwcB, 4, hw);
      L_deform3(stream, hwcB, offs[2], wt_dc[2], fBuf, 4, H, H, 1, 16, true, 0, 16);
      LC<16, 0, 0, 16>(stream, fBuf, nullptr, cw + o_fc[2], fcb[2], feats[2], 4, H, H, true, 0, 16);
    } else {
      LC<16, 16, 0, 16>(stream, rf[i], uf[i], cw + o_ob[i], obb[i], oBuf, 4, H, H, true, 0, 16);
      LC<16, 18, 1, 18>(stream, oBuf, offs[i + 1], cw + o_og[i], ogb[i], offs[i], 4, H, H, true, 0, 18);
      L_hwc(stream, uf[i], hwcB, 4, hw);
      L_deform3(stream, hwcB, offs[i], wt_dc[i], fBuf, 4, H, H, 1, 16, true, 0, 16);
      LC<16, 16, 1, 16>(stream, fBuf, feats[i + 1], cw + o_fc[i], fcb[i], feats[i], 4, H, H, true, 0, 16);
    }
  }

  // ---- final offset head + deform (dg=2); dog halves merged via z-split ----
  const int hw0 = 256 * 256;
  float* doBuf = Bf;  // 16ch
  LC<16, 16, 0, 16>(stream, rf[0], feats[0], cw + o_dob, dobb, doBuf, 4, 256, 256, false, 0, 16);
  LC<16, 18, 0, 18>(stream, doBuf, offs[0], cw + o_dog0, dogb, A, 4, 256, 256, false, 0, 36,
                    cw + o_dog1, dogb + 18, 18);
  float* fHwc = Bf + (size_t)4 * 16 * hw0;  // doBuf consumed
  L_hwc(stream, feats[0], fHwc, 4, hw0);
  L_deform3(stream, fHwc, A, wt_ddc, (float*)d_out, 4, 256, 256, 2, 2, false, 0, 2);
}

// Round 11
// 1209.761 us; speedup vs baseline: 1.3214x; 1.0238x over previous
//
#include <hip/hip_runtime.h>
#include <math.h>

#define TB 256

__device__ __forceinline__ unsigned short f2bf(float x) {  // RNE f32->bf16
  unsigned u = __float_as_uint(x);
  unsigned r = (u + 0x7FFFu + ((u >> 16) & 1u)) >> 16;
  return (unsigned short)r;
}
__device__ __forceinline__ float bf2f(unsigned short h) {
  return __uint_as_float(((unsigned)h) << 16);
}

// ---------------- maxpool 3x3 stride2 pad1 + optional HWC dual-write for uf half ----------------
__global__ __launch_bounds__(256) void maxpool3s2_k(
    const float* __restrict__ in, float* __restrict__ out,
    int NC, int H, int W, int Ho, int Wo, float* __restrict__ hwcDst) {
  int idx = blockIdx.x * TB + threadIdx.x;
  int total = NC * Ho * Wo;
  if (idx >= total) return;
  int wo = idx % Wo;
  int t = idx / Wo;
  int ho = t % Ho;
  int nc = t / Ho;
  const float* src = in + (size_t)nc * H * W;
  int y0 = 2 * ho - 1, x0 = 2 * wo - 1;
  float m = -INFINITY;
  for (int dy = 0; dy < 3; ++dy) {
    int y = y0 + dy;
    if (y < 0 || y >= H) continue;
    for (int dx = 0; dx < 3; ++dx) {
      int x = x0 + dx;
      if (x < 0 || x >= W) continue;
      m = fmaxf(m, src[(size_t)y * W + x]);
    }
  }
  out[idx] = m;
  if (hwcDst && nc >= (NC >> 1)) {  // uf half of the N=8 batch -> HWC
    int r = nc - (NC >> 1);
    int nn = r >> 4, cc = r & 15;
    hwcDst[(((size_t)nn * Ho + ho) * Wo + wo) * 16 + cc] = m;
  }
}

// ---------------- deform weight reorder: (O,16,9) -> (9,16,O) ----------------
__global__ __launch_bounds__(256) void wreorder_k(
    const float* __restrict__ a, const float* __restrict__ b,
    const float* __restrict__ c, const float* __restrict__ d,
    float* __restrict__ out) {
  int t = blockIdx.x * 256 + threadIdx.x;
  if (t < 6912) {
    int which = t / 2304, r = t % 2304;
    int o = r % 16, kc = r / 16;
    int ci = kc % 16, k = kc / 16;
    const float* w = which == 0 ? a : (which == 1 ? b : c);
    out[t] = w[(o * 16 + ci) * 9 + k];
  } else if (t < 7200) {
    int r = t - 6912;
    int o = r % 2, kc = r / 2;
    int ci = kc % 16, k = kc / 16;
    out[t] = d[(o * 16 + ci) * 9 + k];
  }
}

// ---------------- conv weight reorder: (O,C,9) -> (C,9,O) ----------------
struct WEntry { const float* src; int cin; int cout; int dstoff; };
struct WTable { WEntry e[20]; };  // 18 used
__global__ __launch_bounds__(256) void wreorder_conv_k(WTable t, float* __restrict__ out) {
  WEntry en = t.e[blockIdx.y];
  int total = en.cin * en.cout * 9;
  int i = blockIdx.x * 256 + threadIdx.x;
  if (i >= total) return;
  int o = i % en.cout;
  int ck = i / en.cout;
  int k = ck % 9;
  int c = ck / 9;
  out[en.dstoff + i] = en.src[((size_t)o * en.cin + c) * 9 + k];
}

// ---------------- fused FE level-0: conv1+relu -> conv2+relu -> pool ----------------
// bf16 LDS staging (fp32 accumulate): LDS 42KB -> 22.6KB => 3 -> 7 blocks/CU.
// uf (im==1) additionally written in HWC for the deform consumer.
__global__ __launch_bounds__(256) void fe0_fused_k(
    const float* __restrict__ refI, const float* __restrict__ unrI,
    const float* __restrict__ w1, const float* __restrict__ b1,
    const float* __restrict__ w2ro, const float* __restrict__ b2,
    float* __restrict__ outR, float* __restrict__ outU, float* __restrict__ outUH) {
  __shared__ unsigned short c1buf[16 * 361];  // bf16 conv1 out, plane-major 19x19
  __shared__ unsigned short c2buf[16 * 289];  // bf16 conv2 out, plane-major 17x17
  __shared__ float inbuf[441];                // 21x21 raw input
  const int z = blockIdx.z;                   // im*4 + n
  const int im = z >> 2, n = z & 3;
  const float* img = (im ? unrI : refI) + (size_t)n * 512 * 512;
  float* outp = (im ? outU : outR) + (size_t)n * 16 * 256 * 256;
  const int py0 = blockIdx.y * 8, px0 = blockIdx.x * 8;
  const int tid = threadIdx.x;

  for (int i = tid; i < 441; i += 256) {
    int yi = i / 21, xi = i - yi * 21;
    int gy = 2 * py0 - 3 + yi, gx = 2 * px0 - 3 + xi;
    float v = 0.f;
    if (gy >= 0 && gy < 512 && gx >= 0 && gx < 512) v = img[gy * 512 + gx];
    inbuf[i] = v;
  }
  __syncthreads();

  for (int p = tid; p < 361; p += 256) {
    int y1 = p / 19, x1 = p - y1 * 19;
    int gy = 2 * py0 - 2 + y1, gx = 2 * px0 - 2 + x1;
    bool valid = (gy >= 0 && gy < 512 && gx >= 0 && gx < 512);
    float t[9];
#pragma unroll
    for (int k = 0; k < 9; ++k) t[k] = inbuf[(y1 + k / 3) * 21 + x1 + (k % 3)];
#pragma unroll
    for (int c = 0; c < 16; ++c) {
      float a = b1[c];
#pragma unroll
      for (int k = 0; k < 9; ++k) a = fmaf(t[k], w1[c * 9 + k], a);
      c1buf[c * 361 + p] = f2bf(valid ? fmaxf(a, 0.f) : 0.f);
    }
  }
  __syncthreads();

  for (int p = tid; p < 289; p += 256) {
    int y2 = p / 17, x2 = p - y2 * 17;
    float acc[16];
#pragma unroll
    for (int o = 0; o < 16; ++o) acc[o] = b2[o];
    for (int ci = 0; ci < 16; ++ci) {
      const unsigned short* ld = c1buf + ci * 361 + y2 * 19 + x2;
      float v[9];
#pragma unroll
      for (int k = 0; k < 9; ++k) v[k] = bf2f(ld[(k / 3) * 19 + (k % 3)]);
      const float* wc = w2ro + ci * 144;
#pragma unroll
      for (int k = 0; k < 9; ++k)
#pragma unroll
        for (int o = 0; o < 16; ++o)
          acc[o] = fmaf(v[k], wc[k * 16 + o], acc[o]);
    }
#pragma unroll
    for (int o = 0; o < 16; ++o) c2buf[o * 289 + p] = f2bf(fmaxf(acc[o], 0.f));
  }
  __syncthreads();

  // pool: bf16 bit-pattern max is valid for the non-negative post-relu values
  for (int i = tid; i < 1024; i += 256) {
    int c = i >> 6, r = i & 63, py = r >> 3, px = r & 7;
    unsigned short m = 0;
#pragma unroll
    for (int dy = 0; dy < 3; ++dy) {
      int gy = 2 * (py0 + py) - 1 + dy;
      if (gy < 0 || gy >= 512) continue;
#pragma unroll
      for (int dx = 0; dx < 3; ++dx) {
        int gx = 2 * (px0 + px) - 1 + dx;
        if (gx < 0 || gx >= 512) continue;
        unsigned short v = c2buf[c * 289 + (2 * py + dy) * 17 + 2 * px + dx];
        m = (v > m) ? v : m;
      }
    }
    float mf = bf2f(m);
    outp[((size_t)c * 256 + py0 + py) * 256 + px0 + px] = mf;
    if (im)
      outUH[(((size_t)n * 256 + py0 + py) * 256 + px0 + px) * 16 + c] = mf;
  }
}

// ---------------- 3x3 conv v6 (R10-proven) + optional HWC dual-write ----------------
template <int L, int COUT>
__device__ __forceinline__ void conv_inner(const float* __restrict__ lds,
                                           const float* __restrict__ wc0,
                                           float* __restrict__ acc, int ty, int tx) {
#pragma unroll
  for (int c = 0; c < L; ++c) {
    const float* ld = lds + c * (18 * 24) + ty * 24 + tx;
    float v[3][3];
#pragma unroll
    for (int dy = 0; dy < 3; ++dy)
#pragma unroll
      for (int dx = 0; dx < 3; ++dx) v[dy][dx] = ld[dy * 24 + dx];
    const float* wc = wc0 + c * 9 * COUT;
#pragma unroll
    for (int k = 0; k < 9; ++k) {
#pragma unroll
      for (int o = 0; o < COUT; ++o)
        acc[o] = fmaf(v[k / 3][k % 3], wc[k * COUT + o], acc[o]);
    }
  }
}

template <int CIN0, int CIN1, int UP1, int COUT>
__global__ __launch_bounds__(256) void conv3x3_v6(
    const float* __restrict__ in0, const float* __restrict__ in1,
    const float* __restrict__ wro, const float* __restrict__ bias,
    float* __restrict__ out, int H, int W, int relu, int ocoff, int ocstride,
    const float* __restrict__ wroB, const float* __restrict__ biasB,
    int ocoffB, int zN, float* __restrict__ outH) {
  constexpr int CIN = CIN0 + CIN1;
  constexpr int CH = (CIN < 8) ? CIN : 8;
  constexpr int NPASS = (CIN + CH - 1) / CH;
  constexpr int LAST = CIN - (NPASS - 1) * CH;
  __shared__ float lds[CH * 18 * 24];
  int n = blockIdx.z;
  if (n >= zN) {  // second weight set (dog half 1)
    n -= zN;
    wro = wroB;
    bias = biasB;
    ocoff = ocoffB;
  }
  const int bx = blockIdx.x * 16, by = blockIdx.y * 16;
  const int tx = threadIdx.x, ty = threadIdx.y;
  const int tid = ty * 16 + tx;
  const int H2 = H >> 1, W2 = W >> 1;
  const float* i0 = in0 + (size_t)n * CIN0 * H * W;
  const float* i1 = in1 ? in1 + (size_t)n * CIN1 * (UP1 ? H2 * W2 : H * W) : nullptr;
  float acc[COUT];
#pragma unroll
  for (int o = 0; o < COUT; ++o) acc[o] = bias ? bias[o] : 0.f;

  for (int pass = 0; pass < NPASS; ++pass) {
    const int c0 = pass * CH;
    const int L = (pass < NPASS - 1) ? CH : LAST;
    if (pass) __syncthreads();
    for (int idx = tid; idx < L * 324; idx += 256) {
      int c = idx / 324;
      int r = idx - c * 324;
      int ly = r / 18, lx = r - ly * 18;
      int gy = by + ly - 1, gx = bx + lx - 1;
      int gc = c0 + c;
      float v = 0.f;
      if (gy >= 0 && gy < H && gx >= 0 && gx < W) {
        if (CIN1 == 0 || gc < CIN0) {
          v = i0[((size_t)gc * H + gy) * W + gx];
        } else if (!UP1) {
          v = i1[((size_t)(gc - CIN0) * H + gy) * W + gx];
        } else {  // on-the-fly bilinear x2 (half-pixel, clamp) — matches jax resize
          float sy = 0.5f * gy - 0.25f, sx = 0.5f * gx - 0.25f;
          float y0f = floorf(sy), x0f = floorf(sx);
          float wy = sy - y0f, wx = sx - x0f;
          int y0 = (int)y0f, x0 = (int)x0f;
          int y0c = min(max(y0, 0), H2 - 1), y1c = min(max(y0 + 1, 0), H2 - 1);
          int x0c = min(max(x0, 0), W2 - 1), x1c = min(max(x0 + 1, 0), W2 - 1);
          const float* sp = i1 + (size_t)(gc - CIN0) * H2 * W2;
          v = (1.f - wy) * ((1.f - wx) * sp[y0c * W2 + x0c] + wx * sp[y0c * W2 + x1c]) +
              wy * ((1.f - wx) * sp[y1c * W2 + x0c] + wx * sp[y1c * W2 + x1c]);
        }
      }
      lds[c * (18 * 24) + ly * 24 + lx] = v;
    }
    __syncthreads();
    const float* wc0 = wro + (size_t)c0 * 9 * COUT;
    if (pass < NPASS - 1)
      conv_inner<CH, COUT>(lds, wc0, acc, ty, tx);
    else
      conv_inner<LAST, COUT>(lds, wc0, acc, ty, tx);
  }

  const int h = by + ty, x = bx + tx;
  float* oh = outH ? outH + ((size_t)n * H * W + (size_t)h * W + x) * 16 : nullptr;
#pragma unroll
  for (int o = 0; o < COUT; ++o) {
    float r = acc[o];
    if (relu) r = fmaxf(r, 0.f);
    out[(((size_t)n * ocstride + ocoff + o) * H + h) * W + x] = r;
    if (outH) oh[o] = r;
  }
}

// ---------------- deformable 3x3 conv (R9-proven): HWC input, XCD swizzle ----------------
template <int COUT, int DG>
__global__ __launch_bounds__(256) void deform_v3(
    const float* __restrict__ inHWC, const float* __restrict__ off,
    const float* __restrict__ wt, float* __restrict__ out,
    int H, int W, int relu, int ocoff, int ocstride) {
  constexpr int CIN = 16;
  constexpr int CG = CIN / DG;
  const int n = blockIdx.y;
  const int HWt = H * W;
  const int nbx = gridDim.x;
  int bxs = blockIdx.x;
  bxs = (bxs & 7) * (nbx >> 3) + (bxs >> 3);  // XCD-contiguous band mapping
  const int hw = bxs * 256 + threadIdx.x;
  const int h = hw / W, w = hw - h * W;
  const float* inN = inHWC + (size_t)n * HWt * CIN;
  const float* offN = off + (size_t)n * (DG * 18) * HWt + hw;
  float acc[COUT];
#pragma unroll
  for (int o = 0; o < COUT; ++o) acc[o] = 0.f;
#pragma unroll
  for (int g = 0; g < DG; ++g) {
#pragma unroll
    for (int k = 0; k < 9; ++k) {
      const int ky = k / 3 - 1, kx = k % 3 - 1;
      float oy = offN[(size_t)((g * 9 + k) * 2 + 0) * HWt];
      float ox = offN[(size_t)((g * 9 + k) * 2 + 1) * HWt];
      float py = (float)(h + ky) + oy;
      float px = (float)(w + kx) + ox;
      float y0f = floorf(py), x0f = floorf(px);
      float fy = py - y0f, fx = px - x0f;
      int y0 = (int)y0f, x0 = (int)x0f;
      bool vy0 = ((unsigned)y0 < (unsigned)H);
      bool vy1 = ((unsigned)(y0 + 1) < (unsigned)H);
      bool vx0 = ((unsigned)x0 < (unsigned)W);
      bool vx1 = ((unsigned)(x0 + 1) < (unsigned)W);
      int y0c = min(max(y0, 0), H - 1), y1c = min(max(y0 + 1, 0), H - 1);
      int x0c = min(max(x0, 0), W - 1), x1c = min(max(x0 + 1, 0), W - 1);
      float w00 = (vy0 && vx0) ? (1.f - fy) * (1.f - fx) : 0.f;
      float w01 = (vy0 && vx1) ? (1.f - fy) * fx : 0.f;
      float w10 = (vy1 && vx0) ? fy * (1.f - fx) : 0.f;
      float w11 = (vy1 && vx1) ? fy * fx : 0.f;
      const float* p00 = inN + ((size_t)y0c * W + x0c) * CIN + g * CG;
      const float* p01 = inN + ((size_t)y0c * W + x1c) * CIN + g * CG;
      const float* p10 = inN + ((size_t)y1c * W + x0c) * CIN + g * CG;
      const float* p11 = inN + ((size_t)y1c * W + x1c) * CIN + g * CG;
      const float* wk = wt + (k * CIN + g * CG) * COUT;
#pragma unroll
      for (int c4 = 0; c4 < CG / 4; ++c4) {
        float4 a00 = *(const float4*)(p00 + c4 * 4);
        float4 a01 = *(const float4*)(p01 + c4 * 4);
        float4 a10 = *(const float4*)(p10 + c4 * 4);
        float4 a11 = *(const float4*)(p11 + c4 * 4);
        float v0 = w00 * a00.x + w01 * a01.x + w10 * a10.x + w11 * a11.x;
        float v1 = w00 * a00.y + w01 * a01.y + w10 * a10.y + w11 * a11.y;
        float v2 = w00 * a00.z + w01 * a01.z + w10 * a10.z + w11 * a11.z;
        float v3 = w00 * a00.w + w01 * a01.w + w10 * a10.w + w11 * a11.w;
#pragma unroll
        for (int o = 0; o < COUT; ++o) {
          float t0 = fmaf(v0, wk[(c4 * 4 + 0) * COUT + o], acc[o]);
          t0 = fmaf(v1, wk[(c4 * 4 + 1) * COUT + o], t0);
          t0 = fmaf(v2, wk[(c4 * 4 + 2) * COUT + o], t0);
          acc[o] = fmaf(v3, wk[(c4 * 4 + 3) * COUT + o], t0);
        }
      }
    }
  }
  float* outN = out + ((size_t)n * ocstride + ocoff) * HWt + hw;
#pragma unroll
  for (int o = 0; o < COUT; ++o) {
    float r = acc[o];
    if (relu) r = fmaxf(r, 0.f);
    outN[(size_t)o * HWt] = r;
  }
}

// ---------------- host-side launch helpers ----------------
template <int C0, int C1, int UP, int CO>
static void LC(hipStream_t s, const float* a, const float* b, const float* w,
               const float* bi, float* o, int N, int H, int W, bool relu,
               int ocoff, int ocstride,
               const float* wB = nullptr, const float* biB = nullptr, int ocoffB = 0,
               float* outH = nullptr) {
  int zn = wB ? 2 * N : N;
  conv3x3_v6<C0, C1, UP, CO><<<dim3(W / 16, H / 16, zn), dim3(16, 16), 0, s>>>(
      a, b, w, bi, o, H, W, relu ? 1 : 0, ocoff, ocstride, wB, biB, ocoffB, N, outH);
}

static void L_deform3(hipStream_t s, const float* inHWC, const float* off, const float* wt,
                      float* out, int N, int H, int W, int dg, int Cout, bool relu,
                      int ocoff, int ocstride) {
  dim3 grd(H * W / 256, N);
  int r = relu ? 1 : 0;
  if (Cout == 16 && dg == 1)
    deform_v3<16, 1><<<grd, 256, 0, s>>>(inHWC, off, wt, out, H, W, r, ocoff, ocstride);
  else if (Cout == 2 && dg == 2)
    deform_v3<2, 2><<<grd, 256, 0, s>>>(inHWC, off, wt, out, H, W, r, ocoff, ocstride);
}

static void L_pool(hipStream_t s, const float* in, float* out, int NC, int H, int W,
                   float* hwc) {
  int Ho = H / 2, Wo = W / 2;
  int total = NC * Ho * Wo;
  maxpool3s2_k<<<(total + TB - 1) / TB, TB, 0, s>>>(in, out, NC, H, W, Ho, Wo, hwc);
}

extern "C" void kernel_launch(void* const* d_in, const int* in_sizes, int n_in,
                              void* d_out, int out_size, void* d_ws, size_t ws_size,
                              hipStream_t stream) {
  auto F = [&](int i) { return (const float*)d_in[i]; };
  const float* ref = F(0);
  const float* unr = F(1);
  const float* few1[3] = {F(2), F(6), F(10)};
  const float* feb1[3] = {F(3), F(7), F(11)};
  const float* few2[3] = {F(4), F(8), F(12)};
  const float* feb2[3] = {F(5), F(9), F(13)};
  const float* obw[3] = {F(14), F(16), F(18)};
  const float* obb[3] = {F(15), F(17), F(19)};
  const float* ogw[3] = {F(20), F(22), F(24)};
  const float* ogb[3] = {F(21), F(23), F(25)};
  const float* dcw[3] = {F(26), F(27), F(28)};
  const float* fcw[3] = {F(29), F(31), F(33)};
  const float* fcb[3] = {F(30), F(32), F(34)};
  const float* dobw = F(35);
  const float* dobb = F(36);
  const float* dogw = F(37);
  const float* dogb = F(38);
  const float* ddcw = F(39);

  // ---- workspace layout (floats). rf/uf contiguous for N=8 batching. ----
  // HWC deform inputs are ALIASED into feats[i] (dead until fc[i] writes them,
  // which happens strictly after the deform consumes the HWC copy).
  float* ws = (float*)d_ws;
  size_t p = 0;
  auto alloc = [&](size_t nf) { float* r = ws + p; p += nf; return r; };
  const size_t SC = 9437184;
  float* A = alloc(SC);
  float* Bf = alloc(SC);
  float* rf[3], *uf[3], *offs[3], *feats[3];
  rf[0] = alloc((size_t)4 * 16 * 256 * 256);
  uf[0] = alloc((size_t)4 * 16 * 256 * 256);
  rf[1] = alloc((size_t)4 * 16 * 128 * 128);
  uf[1] = alloc((size_t)4 * 16 * 128 * 128);
  rf[2] = alloc((size_t)4 * 16 * 64 * 64);
  uf[2] = alloc((size_t)4 * 16 * 64 * 64);
  offs[0] = alloc((size_t)4 * 18 * 256 * 256);
  offs[1] = alloc((size_t)4 * 18 * 128 * 128);
  offs[2] = alloc((size_t)4 * 18 * 64 * 64);
  feats[0] = alloc((size_t)4 * 16 * 256 * 256);
  feats[1] = alloc((size_t)4 * 16 * 128 * 128);
  feats[2] = alloc((size_t)4 * 16 * 64 * 64);
  float* wt = alloc(7200);
  float* cw = alloc(70000);
  if (p * sizeof(float) > ws_size) return;
  const float* wt_dc[3] = {wt, wt + 2304, wt + 4608};
  const float* wt_ddc = wt + 6912;
  float* ufH[3] = {feats[0], feats[1], feats[2]};  // HWC aliases (liveness audited)
  float* fHwc = Bf + (size_t)4 * 16 * 256 * 256;   // Bf tail, live only at the end

  // ---- build conv weight reorder table ----
  WTable T;
  int nw = 0, woff = 0, maxtot = 0;
  auto addw = [&](const float* src, int cin, int cout) {
    T.e[nw].src = src; T.e[nw].cin = cin; T.e[nw].cout = cout; T.e[nw].dstoff = woff;
    int tot = cin * cout * 9;
    if (tot > maxtot) maxtot = tot;
    int start = woff;
    woff += tot;
    ++nw;
    return start;
  };
  int o_few1[3], o_few2[3], o_ob[3], o_og[3], o_fc[3], o_dob, o_dog0, o_dog1;
  for (int i = 0; i < 3; ++i) o_few1[i] = addw(few1[i], i == 0 ? 1 : 16, 16);
  for (int i = 0; i < 3; ++i) o_few2[i] = addw(few2[i], 16, 16);
  for (int i = 0; i < 3; ++i) o_ob[i] = addw(obw[i], 32, 16);
  o_og[0] = addw(ogw[0], 34, 18);
  o_og[1] = addw(ogw[1], 34, 18);
  o_og[2] = addw(ogw[2], 16, 18);
  for (int i = 0; i < 3; ++i) o_fc[i] = addw(fcw[i], i == 2 ? 16 : 32, 16);
  o_dob = addw(dobw, 32, 16);
  o_dog0 = addw(dogw, 34, 18);
  o_dog1 = addw(dogw + (size_t)18 * 34 * 9, 34, 18);

  wreorder_k<<<29, 256, 0, stream>>>(dcw[0], dcw[1], dcw[2], ddcw, wt);
  wreorder_conv_k<<<dim3((maxtot + 255) / 256, nw), 256, 0, stream>>>(T, cw);

  // ---- FE level 0: fused conv1+conv2+pool; uf[0] dual-written CHW + HWC ----
  fe0_fused_k<<<dim3(32, 32, 8), 256, 0, stream>>>(
      ref, unr, few1[0], feb1[0], cw + o_few2[0], feb2[0], rf[0], uf[0], ufH[0]);

  // ---- FE levels 1/2, N=8 batched; pools dual-write uf HWC ----
  LC<16, 0, 0, 16>(stream, rf[0], nullptr, cw + o_few1[1], feb1[1], A, 8, 256, 256, true, 0, 16);
  LC<16, 0, 0, 16>(stream, A, nullptr, cw + o_few2[1], feb2[1], Bf, 8, 256, 256, true, 0, 16);
  L_pool(stream, Bf, rf[1], 8 * 16, 256, 256, ufH[1]);
  LC<16, 0, 0, 16>(stream, rf[1], nullptr, cw + o_few1[2], feb1[2], A, 8, 128, 128, true, 0, 16);
  LC<16, 0, 0, 16>(stream, A, nullptr, cw + o_few2[2], feb2[2], Bf, 8, 128, 128, true, 0, 16);
  L_pool(stream, Bf, rf[2], 8 * 16, 128, 128, ufH[2]);

  // ---- coarse-to-fine alignment (up2 fused into og/fc staging at i<2) ----
  int Hs[3] = {256, 128, 64};
  for (int i = 2; i >= 0; --i) {
    int H = Hs[i];
    int hw = H * H;
    float* oBuf = Bf;                       // 16ch compact
    float* fBuf = A;                        // 16ch compact (deform out)
    if (i == 2) {
      LC<16, 16, 0, 16>(stream, rf[2], uf[2], cw + o_ob[2], obb[2], oBuf, 4, H, H, true, 0, 16);
      LC<16, 0, 0, 18>(stream, oBuf, nullptr, cw + o_og[2], ogb[2], offs[2], 4, H, H, true, 0, 18);
      L_deform3(stream, ufH[2], offs[2], wt_dc[2], fBuf, 4, H, H, 1, 16, true, 0, 16);
      LC<16, 0, 0, 16>(stream, fBuf, nullptr, cw + o_fc[2], fcb[2], feats[2], 4, H, H, true, 0, 16);
    } else {
      LC<16, 16, 0, 16>(stream, rf[i], uf[i], cw + o_ob[i], obb[i], oBuf, 4, H, H, true, 0, 16);
      LC<16, 18, 1, 18>(stream, oBuf, offs[i + 1], cw + o_og[i], ogb[i], offs[i], 4, H, H, true, 0, 18);
      L_deform3(stream, ufH[i], offs[i], wt_dc[i], fBuf, 4, H, H, 1, 16, true, 0, 16);
      LC<16, 16, 1, 16>(stream, fBuf, feats[i + 1], cw + o_fc[i], fcb[i], feats[i], 4, H, H, true,
                        0, 16, nullptr, nullptr, 0, i == 0 ? fHwc : nullptr);
    }
  }

  // ---- final offset head + deform (dg=2); dog halves merged via z-split ----
  float* doBuf = Bf;  // 16ch
  LC<16, 16, 0, 16>(stream, rf[0], feats[0], cw + o_dob, dobb, doBuf, 4, 256, 256, false, 0, 16);
  LC<16, 18, 0, 18>(stream, doBuf, offs[0], cw + o_dog0, dogb, A, 4, 256, 256, false, 0, 36,
                    cw + o_dog1, dogb + 18, 18);
  L_deform3(stream, fHwc, A, wt_ddc, (float*)d_out, 4, 256, 256, 2, 2, false, 0, 2);
}

// Round 12
// 1189.291 us; speedup vs baseline: 1.3441x; 1.0172x over previous
//
#include <hip/hip_runtime.h>
#include <math.h>

#define TB 256

__device__ __forceinline__ unsigned short f2bf(float x) {  // RNE f32->bf16
  unsigned u = __float_as_uint(x);
  unsigned r = (u + 0x7FFFu + ((u >> 16) & 1u)) >> 16;
  return (unsigned short)r;
}
__device__ __forceinline__ float bf2f(unsigned short h) {
  return __uint_as_float(((unsigned)h) << 16);
}

// ---------------- deform weight reorder: (O,16,9) -> (9,16,O) ----------------
__global__ __launch_bounds__(256) void wreorder_k(
    const float* __restrict__ a, const float* __restrict__ b,
    const float* __restrict__ c, const float* __restrict__ d,
    float* __restrict__ out) {
  int t = blockIdx.x * 256 + threadIdx.x;
  if (t < 6912) {
    int which = t / 2304, r = t % 2304;
    int o = r % 16, kc = r / 16;
    int ci = kc % 16, k = kc / 16;
    const float* w = which == 0 ? a : (which == 1 ? b : c);
    out[t] = w[(o * 16 + ci) * 9 + k];
  } else if (t < 7200) {
    int r = t - 6912;
    int o = r % 2, kc = r / 2;
    int ci = kc % 16, k = kc / 16;
    out[t] = d[(o * 16 + ci) * 9 + k];
  }
}

// ---------------- conv weight reorder: (O,C,9) -> (C,9,O) ----------------
struct WEntry { const float* src; int cin; int cout; int dstoff; };
struct WTable { WEntry e[20]; };  // 18 used
__global__ __launch_bounds__(256) void wreorder_conv_k(WTable t, float* __restrict__ out) {
  WEntry en = t.e[blockIdx.y];
  int total = en.cin * en.cout * 9;
  int i = blockIdx.x * 256 + threadIdx.x;
  if (i >= total) return;
  int o = i % en.cout;
  int ck = i / en.cout;
  int k = ck % 9;
  int c = ck / 9;
  out[en.dstoff + i] = en.src[((size_t)o * en.cin + c) * 9 + k];
}

// ---------------- fused FE level-0 (R11-proven): conv1+relu -> conv2+relu -> pool ----------------
__global__ __launch_bounds__(256) void fe0_fused_k(
    const float* __restrict__ refI, const float* __restrict__ unrI,
    const float* __restrict__ w1, const float* __restrict__ b1,
    const float* __restrict__ w2ro, const float* __restrict__ b2,
    float* __restrict__ outR, float* __restrict__ outU, float* __restrict__ outUH) {
  __shared__ unsigned short c1buf[16 * 361];  // bf16 conv1 out, plane-major 19x19
  __shared__ unsigned short c2buf[16 * 289];  // bf16 conv2 out, plane-major 17x17
  __shared__ float inbuf[441];                // 21x21 raw input
  const int z = blockIdx.z;                   // im*4 + n
  const int im = z >> 2, n = z & 3;
  const float* img = (im ? unrI : refI) + (size_t)n * 512 * 512;
  float* outp = (im ? outU : outR) + (size_t)n * 16 * 256 * 256;
  const int py0 = blockIdx.y * 8, px0 = blockIdx.x * 8;
  const int tid = threadIdx.x;

  for (int i = tid; i < 441; i += 256) {
    int yi = i / 21, xi = i - yi * 21;
    int gy = 2 * py0 - 3 + yi, gx = 2 * px0 - 3 + xi;
    float v = 0.f;
    if (gy >= 0 && gy < 512 && gx >= 0 && gx < 512) v = img[gy * 512 + gx];
    inbuf[i] = v;
  }
  __syncthreads();

  for (int p = tid; p < 361; p += 256) {
    int y1 = p / 19, x1 = p - y1 * 19;
    int gy = 2 * py0 - 2 + y1, gx = 2 * px0 - 2 + x1;
    bool valid = (gy >= 0 && gy < 512 && gx >= 0 && gx < 512);
    float t[9];
#pragma unroll
    for (int k = 0; k < 9; ++k) t[k] = inbuf[(y1 + k / 3) * 21 + x1 + (k % 3)];
#pragma unroll
    for (int c = 0; c < 16; ++c) {
      float a = b1[c];
#pragma unroll
      for (int k = 0; k < 9; ++k) a = fmaf(t[k], w1[c * 9 + k], a);
      c1buf[c * 361 + p] = f2bf(valid ? fmaxf(a, 0.f) : 0.f);
    }
  }
  __syncthreads();

  for (int p = tid; p < 289; p += 256) {
    int y2 = p / 17, x2 = p - y2 * 17;
    float acc[16];
#pragma unroll
    for (int o = 0; o < 16; ++o) acc[o] = b2[o];
    for (int ci = 0; ci < 16; ++ci) {
      const unsigned short* ld = c1buf + ci * 361 + y2 * 19 + x2;
      float v[9];
#pragma unroll
      for (int k = 0; k < 9; ++k) v[k] = bf2f(ld[(k / 3) * 19 + (k % 3)]);
      const float* wc = w2ro + ci * 144;
#pragma unroll
      for (int k = 0; k < 9; ++k)
#pragma unroll
        for (int o = 0; o < 16; ++o)
          acc[o] = fmaf(v[k], wc[k * 16 + o], acc[o]);
    }
#pragma unroll
    for (int o = 0; o < 16; ++o) c2buf[o * 289 + p] = f2bf(fmaxf(acc[o], 0.f));
  }
  __syncthreads();

  for (int i = tid; i < 1024; i += 256) {
    int c = i >> 6, r = i & 63, py = r >> 3, px = r & 7;
    unsigned short m = 0;
#pragma unroll
    for (int dy = 0; dy < 3; ++dy) {
      int gy = 2 * (py0 + py) - 1 + dy;
      if (gy < 0 || gy >= 512) continue;
#pragma unroll
      for (int dx = 0; dx < 3; ++dx) {
        int gx = 2 * (px0 + px) - 1 + dx;
        if (gx < 0 || gx >= 512) continue;
        unsigned short v = c2buf[c * 289 + (2 * py + dy) * 17 + 2 * px + dx];
        m = (v > m) ? v : m;
      }
    }
    float mf = bf2f(m);
    outp[((size_t)c * 256 + py0 + py) * 256 + px0 + px] = mf;
    if (im)
      outUH[(((size_t)n * 256 + py0 + py) * 256 + px0 + px) * 16 + c] = mf;
  }
}

// ---------------- fused FE level-1/2: conv(16->16)+relu -> conv(16->16)+relu -> pool ----------------
// fe0 pattern generalized to 16-ch input (bf16-staged). LDS 25.7KB -> 6 blocks/CU.
// c2buf overlays inbuf. outHWC written for the uf half (n>=4).
__global__ __launch_bounds__(256) void fe12_fused_k(
    const float* __restrict__ in,  // (8,16,Hin,Hin) CHW
    const float* __restrict__ w1ro, const float* __restrict__ b1,
    const float* __restrict__ w2ro, const float* __restrict__ b2,
    float* __restrict__ outC, float* __restrict__ outHWC, int Hin) {
  __shared__ unsigned short c1buf[16 * 361];  // 19x19 x16 bf16
  __shared__ unsigned short sbuf[16 * 441];   // phase1: inbuf 21x21x16; phase3: c2buf 17x17x16
  const int n = blockIdx.z;
  const int Ho = Hin >> 1;
  const int py0 = blockIdx.y * 8, px0 = blockIdx.x * 8;
  const int tid = threadIdx.x;
  const float* inN = in + (size_t)n * 16 * Hin * Hin;

  unsigned short* inbuf = sbuf;
  for (int i = tid; i < 16 * 441; i += 256) {
    int c = i / 441, r = i - c * 441;
    int yi = r / 21, xi = r - yi * 21;
    int gy = 2 * py0 - 3 + yi, gx = 2 * px0 - 3 + xi;
    float v = 0.f;
    if (gy >= 0 && gy < Hin && gx >= 0 && gx < Hin)
      v = inN[((size_t)c * Hin + gy) * Hin + gx];
    inbuf[i] = f2bf(v);
  }
  __syncthreads();

  // conv1: 19x19 x16; zeroed at image-invalid positions (= zero-pad for conv2)
  for (int p = tid; p < 361; p += 256) {
    int y1 = p / 19, x1 = p - y1 * 19;
    int gy = 2 * py0 - 2 + y1, gx = 2 * px0 - 2 + x1;
    bool valid = (gy >= 0 && gy < Hin && gx >= 0 && gx < Hin);
    float acc[16];
#pragma unroll
    for (int o = 0; o < 16; ++o) acc[o] = b1[o];
    for (int ci = 0; ci < 16; ++ci) {
      const unsigned short* ld = inbuf + ci * 441 + y1 * 21 + x1;
      float v[9];
#pragma unroll
      for (int k = 0; k < 9; ++k) v[k] = bf2f(ld[(k / 3) * 21 + (k % 3)]);
      const float* wc = w1ro + ci * 144;
#pragma unroll
      for (int k = 0; k < 9; ++k)
#pragma unroll
        for (int o = 0; o < 16; ++o)
          acc[o] = fmaf(v[k], wc[k * 16 + o], acc[o]);
    }
#pragma unroll
    for (int o = 0; o < 16; ++o)
      c1buf[o * 361 + p] = f2bf(valid ? fmaxf(acc[o], 0.f) : 0.f);
  }
  __syncthreads();

  // conv2: 17x17 x16 into c2buf (overlays inbuf)
  unsigned short* c2buf = sbuf;
  for (int p = tid; p < 289; p += 256) {
    int y2 = p / 17, x2 = p - y2 * 17;
    float acc[16];
#pragma unroll
    for (int o = 0; o < 16; ++o) acc[o] = b2[o];
    for (int ci = 0; ci < 16; ++ci) {
      const unsigned short* ld = c1buf + ci * 361 + y2 * 19 + x2;
      float v[9];
#pragma unroll
      for (int k = 0; k < 9; ++k) v[k] = bf2f(ld[(k / 3) * 19 + (k % 3)]);
      const float* wc = w2ro + ci * 144;
#pragma unroll
      for (int k = 0; k < 9; ++k)
#pragma unroll
        for (int o = 0; o < 16; ++o)
          acc[o] = fmaf(v[k], wc[k * 16 + o], acc[o]);
    }
#pragma unroll
    for (int o = 0; o < 16; ++o) c2buf[o * 289 + p] = f2bf(fmaxf(acc[o], 0.f));
  }
  __syncthreads();

  // pool (bf16 bit-pattern max valid on non-negative post-relu values)
  float* outp = outC + (size_t)n * 16 * Ho * Ho;
  for (int i = tid; i < 1024; i += 256) {
    int c = i >> 6, r = i & 63, py = r >> 3, px = r & 7;
    unsigned short m = 0;
#pragma unroll
    for (int dy = 0; dy < 3; ++dy) {
      int gy = 2 * (py0 + py) - 1 + dy;
      if (gy < 0 || gy >= Hin) continue;
#pragma unroll
      for (int dx = 0; dx < 3; ++dx) {
        int gx = 2 * (px0 + px) - 1 + dx;
        if (gx < 0 || gx >= Hin) continue;
        unsigned short v = c2buf[c * 289 + (2 * py + dy) * 17 + 2 * px + dx];
        m = (v > m) ? v : m;
      }
    }
    float mf = bf2f(m);
    outp[((size_t)c * Ho + py0 + py) * Ho + px0 + px] = mf;
    if (n >= 4)
      outHWC[(((size_t)(n - 4) * Ho + py0 + py) * Ho + px0 + px) * 16 + c] = mf;
  }
}

// ---------------- 3x3 conv v6 (R10-proven) + optional HWC dual-write ----------------
template <int L, int COUT>
__device__ __forceinline__ void conv_inner(const float* __restrict__ lds,
                                           const float* __restrict__ wc0,
                                           float* __restrict__ acc, int ty, int tx) {
#pragma unroll
  for (int c = 0; c < L; ++c) {
    const float* ld = lds + c * (18 * 24) + ty * 24 + tx;
    float v[3][3];
#pragma unroll
    for (int dy = 0; dy < 3; ++dy)
#pragma unroll
      for (int dx = 0; dx < 3; ++dx) v[dy][dx] = ld[dy * 24 + dx];
    const float* wc = wc0 + c * 9 * COUT;
#pragma unroll
    for (int k = 0; k < 9; ++k) {
#pragma unroll
      for (int o = 0; o < COUT; ++o)
        acc[o] = fmaf(v[k / 3][k % 3], wc[k * COUT + o], acc[o]);
    }
  }
}

template <int CIN0, int CIN1, int UP1, int COUT>
__global__ __launch_bounds__(256) void conv3x3_v6(
    const float* __restrict__ in0, const float* __restrict__ in1,
    const float* __restrict__ wro, const float* __restrict__ bias,
    float* __restrict__ out, int H, int W, int relu, int ocoff, int ocstride,
    const float* __restrict__ wroB, const float* __restrict__ biasB,
    int ocoffB, int zN, float* __restrict__ outH) {
  constexpr int CIN = CIN0 + CIN1;
  constexpr int CH = (CIN < 8) ? CIN : 8;
  constexpr int NPASS = (CIN + CH - 1) / CH;
  constexpr int LAST = CIN - (NPASS - 1) * CH;
  __shared__ float lds[CH * 18 * 24];
  int n = blockIdx.z;
  if (n >= zN) {  // second weight set (dog half 1)
    n -= zN;
    wro = wroB;
    bias = biasB;
    ocoff = ocoffB;
  }
  const int bx = blockIdx.x * 16, by = blockIdx.y * 16;
  const int tx = threadIdx.x, ty = threadIdx.y;
  const int tid = ty * 16 + tx;
  const int H2 = H >> 1, W2 = W >> 1;
  const float* i0 = in0 + (size_t)n * CIN0 * H * W;
  const float* i1 = in1 ? in1 + (size_t)n * CIN1 * (UP1 ? H2 * W2 : H * W) : nullptr;
  float acc[COUT];
#pragma unroll
  for (int o = 0; o < COUT; ++o) acc[o] = bias ? bias[o] : 0.f;

  for (int pass = 0; pass < NPASS; ++pass) {
    const int c0 = pass * CH;
    const int L = (pass < NPASS - 1) ? CH : LAST;
    if (pass) __syncthreads();
    for (int idx = tid; idx < L * 324; idx += 256) {
      int c = idx / 324;
      int r = idx - c * 324;
      int ly = r / 18, lx = r - ly * 18;
      int gy = by + ly - 1, gx = bx + lx - 1;
      int gc = c0 + c;
      float v = 0.f;
      if (gy >= 0 && gy < H && gx >= 0 && gx < W) {
        if (CIN1 == 0 || gc < CIN0) {
          v = i0[((size_t)gc * H + gy) * W + gx];
        } else if (!UP1) {
          v = i1[((size_t)(gc - CIN0) * H + gy) * W + gx];
        } else {  // on-the-fly bilinear x2 (half-pixel, clamp) — matches jax resize
          float sy = 0.5f * gy - 0.25f, sx = 0.5f * gx - 0.25f;
          float y0f = floorf(sy), x0f = floorf(sx);
          float wy = sy - y0f, wx = sx - x0f;
          int y0 = (int)y0f, x0 = (int)x0f;
          int y0c = min(max(y0, 0), H2 - 1), y1c = min(max(y0 + 1, 0), H2 - 1);
          int x0c = min(max(x0, 0), W2 - 1), x1c = min(max(x0 + 1, 0), W2 - 1);
          const float* sp = i1 + (size_t)(gc - CIN0) * H2 * W2;
          v = (1.f - wy) * ((1.f - wx) * sp[y0c * W2 + x0c] + wx * sp[y0c * W2 + x1c]) +
              wy * ((1.f - wx) * sp[y1c * W2 + x0c] + wx * sp[y1c * W2 + x1c]);
        }
      }
      lds[c * (18 * 24) + ly * 24 + lx] = v;
    }
    __syncthreads();
    const float* wc0 = wro + (size_t)c0 * 9 * COUT;
    if (pass < NPASS - 1)
      conv_inner<CH, COUT>(lds, wc0, acc, ty, tx);
    else
      conv_inner<LAST, COUT>(lds, wc0, acc, ty, tx);
  }

  const int h = by + ty, x = bx + tx;
  float* oh = outH ? outH + ((size_t)n * H * W + (size_t)h * W + x) * 16 : nullptr;
#pragma unroll
  for (int o = 0; o < COUT; ++o) {
    float r = acc[o];
    if (relu) r = fmaxf(r, 0.f);
    out[(((size_t)n * ocstride + ocoff + o) * H + h) * W + x] = r;
    if (outH) oh[o] = r;
  }
}

// ---------------- deformable 3x3 conv (R9-proven): HWC input, XCD swizzle ----------------
template <int COUT, int DG>
__global__ __launch_bounds__(256) void deform_v3(
    const float* __restrict__ inHWC, const float* __restrict__ off,
    const float* __restrict__ wt, float* __restrict__ out,
    int H, int W, int relu, int ocoff, int ocstride) {
  constexpr int CIN = 16;
  constexpr int CG = CIN / DG;
  const int n = blockIdx.y;
  const int HWt = H * W;
  const int nbx = gridDim.x;
  int bxs = blockIdx.x;
  bxs = (bxs & 7) * (nbx >> 3) + (bxs >> 3);  // XCD-contiguous band mapping
  const int hw = bxs * 256 + threadIdx.x;
  const int h = hw / W, w = hw - h * W;
  const float* inN = inHWC + (size_t)n * HWt * CIN;
  const float* offN = off + (size_t)n * (DG * 18) * HWt + hw;
  float acc[COUT];
#pragma unroll
  for (int o = 0; o < COUT; ++o) acc[o] = 0.f;
#pragma unroll
  for (int g = 0; g < DG; ++g) {
#pragma unroll
    for (int k = 0; k < 9; ++k) {
      const int ky = k / 3 - 1, kx = k % 3 - 1;
      float oy = offN[(size_t)((g * 9 + k) * 2 + 0) * HWt];
      float ox = offN[(size_t)((g * 9 + k) * 2 + 1) * HWt];
      float py = (float)(h + ky) + oy;
      float px = (float)(w + kx) + ox;
      float y0f = floorf(py), x0f = floorf(px);
      float fy = py - y0f, fx = px - x0f;
      int y0 = (int)y0f, x0 = (int)x0f;
      bool vy0 = ((unsigned)y0 < (unsigned)H);
      bool vy1 = ((unsigned)(y0 + 1) < (unsigned)H);
      bool vx0 = ((unsigned)x0 < (unsigned)W);
      bool vx1 = ((unsigned)(x0 + 1) < (unsigned)W);
      int y0c = min(max(y0, 0), H - 1), y1c = min(max(y0 + 1, 0), H - 1);
      int x0c = min(max(x0, 0), W - 1), x1c = min(max(x0 + 1, 0), W - 1);
      float w00 = (vy0 && vx0) ? (1.f - fy) * (1.f - fx) : 0.f;
      float w01 = (vy0 && vx1) ? (1.f - fy) * fx : 0.f;
      float w10 = (vy1 && vx0) ? fy * (1.f - fx) : 0.f;
      float w11 = (vy1 && vx1) ? fy * fx : 0.f;
      const float* p00 = inN + ((size_t)y0c * W + x0c) * CIN + g * CG;
      const float* p01 = inN + ((size_t)y0c * W + x1c) * CIN + g * CG;
      const float* p10 = inN + ((size_t)y1c * W + x0c) * CIN + g * CG;
      const float* p11 = inN + ((size_t)y1c * W + x1c) * CIN + g * CG;
      const float* wk = wt + (k * CIN + g * CG) * COUT;
#pragma unroll
      for (int c4 = 0; c4 < CG / 4; ++c4) {
        float4 a00 = *(const float4*)(p00 + c4 * 4);
        float4 a01 = *(const float4*)(p01 + c4 * 4);
        float4 a10 = *(const float4*)(p10 + c4 * 4);
        float4 a11 = *(const float4*)(p11 + c4 * 4);
        float v0 = w00 * a00.x + w01 * a01.x + w10 * a10.x + w11 * a11.x;
        float v1 = w00 * a00.y + w01 * a01.y + w10 * a10.y + w11 * a11.y;
        float v2 = w00 * a00.z + w01 * a01.z + w10 * a10.z + w11 * a11.z;
        float v3 = w00 * a00.w + w01 * a01.w + w10 * a10.w + w11 * a11.w;
#pragma unroll
        for (int o = 0; o < COUT; ++o) {
          float t0 = fmaf(v0, wk[(c4 * 4 + 0) * COUT + o], acc[o]);
          t0 = fmaf(v1, wk[(c4 * 4 + 1) * COUT + o], t0);
          t0 = fmaf(v2, wk[(c4 * 4 + 2) * COUT + o], t0);
          acc[o] = fmaf(v3, wk[(c4 * 4 + 3) * COUT + o], t0);
        }
      }
    }
  }
  float* outN = out + ((size_t)n * ocstride + ocoff) * HWt + hw;
#pragma unroll
  for (int o = 0; o < COUT; ++o) {
    float r = acc[o];
    if (relu) r = fmaxf(r, 0.f);
    outN[(size_t)o * HWt] = r;
  }
}

// ---------------- host-side launch helpers ----------------
template <int C0, int C1, int UP, int CO>
static void LC(hipStream_t s, const float* a, const float* b, const float* w,
               const float* bi, float* o, int N, int H, int W, bool relu,
               int ocoff, int ocstride,
               const float* wB = nullptr, const float* biB = nullptr, int ocoffB = 0,
               float* outH = nullptr) {
  int zn = wB ? 2 * N : N;
  conv3x3_v6<C0, C1, UP, CO><<<dim3(W / 16, H / 16, zn), dim3(16, 16), 0, s>>>(
      a, b, w, bi, o, H, W, relu ? 1 : 0, ocoff, ocstride, wB, biB, ocoffB, N, outH);
}

static void L_deform3(hipStream_t s, const float* inHWC, const float* off, const float* wt,
                      float* out, int N, int H, int W, int dg, int Cout, bool relu,
                      int ocoff, int ocstride) {
  dim3 grd(H * W / 256, N);
  int r = relu ? 1 : 0;
  if (Cout == 16 && dg == 1)
    deform_v3<16, 1><<<grd, 256, 0, s>>>(inHWC, off, wt, out, H, W, r, ocoff, ocstride);
  else if (Cout == 2 && dg == 2)
    deform_v3<2, 2><<<grd, 256, 0, s>>>(inHWC, off, wt, out, H, W, r, ocoff, ocstride);
}

extern "C" void kernel_launch(void* const* d_in, const int* in_sizes, int n_in,
                              void* d_out, int out_size, void* d_ws, size_t ws_size,
                              hipStream_t stream) {
  auto F = [&](int i) { return (const float*)d_in[i]; };
  const float* ref = F(0);
  const float* unr = F(1);
  const float* few1[3] = {F(2), F(6), F(10)};
  const float* feb1[3] = {F(3), F(7), F(11)};
  const float* few2[3] = {F(4), F(8), F(12)};
  const float* feb2[3] = {F(5), F(9), F(13)};
  const float* obw[3] = {F(14), F(16), F(18)};
  const float* obb[3] = {F(15), F(17), F(19)};
  const float* ogw[3] = {F(20), F(22), F(24)};
  const float* ogb[3] = {F(21), F(23), F(25)};
  const float* dcw[3] = {F(26), F(27), F(28)};
  const float* fcw[3] = {F(29), F(31), F(33)};
  const float* fcb[3] = {F(30), F(32), F(34)};
  const float* dobw = F(35);
  const float* dobb = F(36);
  const float* dogw = F(37);
  const float* dogb = F(38);
  const float* ddcw = F(39);

  // ---- workspace layout (floats). rf/uf contiguous for N=8 batching. ----
  // HWC deform inputs ALIASED into feats[i] (dead until fc[i] writes them,
  // strictly after the deform consumes the HWC copy).
  float* ws = (float*)d_ws;
  size_t p = 0;
  auto alloc = [&](size_t nf) { float* r = ws + p; p += nf; return r; };
  const size_t SC = 9437184;
  float* A = alloc(SC);
  float* Bf = alloc(SC);
  float* rf[3], *uf[3], *offs[3], *feats[3];
  rf[0] = alloc((size_t)4 * 16 * 256 * 256);
  uf[0] = alloc((size_t)4 * 16 * 256 * 256);
  rf[1] = alloc((size_t)4 * 16 * 128 * 128);
  uf[1] = alloc((size_t)4 * 16 * 128 * 128);
  rf[2] = alloc((size_t)4 * 16 * 64 * 64);
  uf[2] = alloc((size_t)4 * 16 * 64 * 64);
  offs[0] = alloc((size_t)4 * 18 * 256 * 256);
  offs[1] = alloc((size_t)4 * 18 * 128 * 128);
  offs[2] = alloc((size_t)4 * 18 * 64 * 64);
  feats[0] = alloc((size_t)4 * 16 * 256 * 256);
  feats[1] = alloc((size_t)4 * 16 * 128 * 128);
  feats[2] = alloc((size_t)4 * 16 * 64 * 64);
  float* wt = alloc(7200);
  float* cw = alloc(70000);
  if (p * sizeof(float) > ws_size) return;
  const float* wt_dc[3] = {wt, wt + 2304, wt + 4608};
  const float* wt_ddc = wt + 6912;
  float* ufH[3] = {feats[0], feats[1], feats[2]};  // HWC aliases (liveness audited)
  float* fHwc = Bf + (size_t)4 * 16 * 256 * 256;   // Bf tail, live only at the end

  // ---- build conv weight reorder table ----
  WTable T;
  int nw = 0, woff = 0, maxtot = 0;
  auto addw = [&](const float* src, int cin, int cout) {
    T.e[nw].src = src; T.e[nw].cin = cin; T.e[nw].cout = cout; T.e[nw].dstoff = woff;
    int tot = cin * cout * 9;
    if (tot > maxtot) maxtot = tot;
    int start = woff;
    woff += tot;
    ++nw;
    return start;
  };
  int o_few1[3], o_few2[3], o_ob[3], o_og[3], o_fc[3], o_dob, o_dog0, o_dog1;
  for (int i = 0; i < 3; ++i) o_few1[i] = addw(few1[i], i == 0 ? 1 : 16, 16);
  for (int i = 0; i < 3; ++i) o_few2[i] = addw(few2[i], 16, 16);
  for (int i = 0; i < 3; ++i) o_ob[i] = addw(obw[i], 32, 16);
  o_og[0] = addw(ogw[0], 34, 18);
  o_og[1] = addw(ogw[1], 34, 18);
  o_og[2] = addw(ogw[2], 16, 18);
  for (int i = 0; i < 3; ++i) o_fc[i] = addw(fcw[i], i == 2 ? 16 : 32, 16);
  o_dob = addw(dobw, 32, 16);
  o_dog0 = addw(dogw, 34, 18);
  o_dog1 = addw(dogw + (size_t)18 * 34 * 9, 34, 18);

  wreorder_k<<<29, 256, 0, stream>>>(dcw[0], dcw[1], dcw[2], ddcw, wt);
  wreorder_conv_k<<<dim3((maxtot + 255) / 256, nw), 256, 0, stream>>>(T, cw);

  // ---- FE level 0: fused conv1+conv2+pool; uf[0] dual-written CHW + HWC ----
  fe0_fused_k<<<dim3(32, 32, 8), 256, 0, stream>>>(
      ref, unr, few1[0], feb1[0], cw + o_few2[0], feb2[0], rf[0], uf[0], ufH[0]);

  // ---- FE levels 1/2: fused conv+conv+pool, N=8; uf HWC dual-written ----
  fe12_fused_k<<<dim3(16, 16, 8), 256, 0, stream>>>(
      rf[0], cw + o_few1[1], feb1[1], cw + o_few2[1], feb2[1], rf[1], ufH[1], 256);
  fe12_fused_k<<<dim3(8, 8, 8), 256, 0, stream>>>(
      rf[1], cw + o_few1[2], feb1[2], cw + o_few2[2], feb2[2], rf[2], ufH[2], 128);

  // ---- coarse-to-fine alignment (up2 fused into og/fc staging at i<2) ----
  int Hs[3] = {256, 128, 64};
  for (int i = 2; i >= 0; --i) {
    int H = Hs[i];
    float* oBuf = Bf;  // 16ch compact
    float* fBuf = A;   // 16ch compact (deform out)
    if (i == 2) {
      LC<16, 16, 0, 16>(stream, rf[2], uf[2], cw + o_ob[2], obb[2], oBuf, 4, H, H, true, 0, 16);
      LC<16, 0, 0, 18>(stream, oBuf, nullptr, cw + o_og[2], ogb[2], offs[2], 4, H, H, true, 0, 18);
      L_deform3(stream, ufH[2], offs[2], wt_dc[2], fBuf, 4, H, H, 1, 16, true, 0, 16);
      LC<16, 0, 0, 16>(stream, fBuf, nullptr, cw + o_fc[2], fcb[2], feats[2], 4, H, H, true, 0, 16);
    } else {
      LC<16, 16, 0, 16>(stream, rf[i], uf[i], cw + o_ob[i], obb[i], oBuf, 4, H, H, true, 0, 16);
      LC<16, 18, 1, 18>(stream, oBuf, offs[i + 1], cw + o_og[i], ogb[i], offs[i], 4, H, H, true, 0, 18);
      L_deform3(stream, ufH[i], offs[i], wt_dc[i], fBuf, 4, H, H, 1, 16, true, 0, 16);
      LC<16, 16, 1, 16>(stream, fBuf, feats[i + 1], cw + o_fc[i], fcb[i], feats[i], 4, H, H, true,
                        0, 16, nullptr, nullptr, 0, i == 0 ? fHwc : nullptr);
    }
  }

  // ---- final offset head + deform (dg=2); dog halves merged via z-split ----
  float* doBuf = Bf;  // 16ch
  LC<16, 16, 0, 16>(stream, rf[0], feats[0], cw + o_dob, dobb, doBuf, 4, 256, 256, false, 0, 16);
  LC<16, 18, 0, 18>(stream, doBuf, offs[0], cw + o_dog0, dogb, A, 4, 256, 256, false, 0, 36,
                    cw + o_dog1, dogb + 18, 18);
  L_deform3(stream, fHwc, A, wt_ddc, (float*)d_out, 4, 256, 256, 2, 2, false, 0, 2);
}

// Round 13
// 1188.742 us; speedup vs baseline: 1.3447x; 1.0005x over previous
//
#include <hip/hip_runtime.h>
#include <math.h>

#define TB 256

typedef _Float16 half2_t __attribute__((ext_vector_type(2)));

__device__ __forceinline__ unsigned packh2(float a, float b) {
  half2_t h;
  h.x = (_Float16)a;
  h.y = (_Float16)b;
  return __builtin_bit_cast(unsigned, h);
}
__device__ __forceinline__ unsigned short f2h(float a) {
  return __builtin_bit_cast(unsigned short, (_Float16)a);
}
__device__ __forceinline__ float h2f(unsigned short u) {
  return (float)__builtin_bit_cast(_Float16, u);
}

// f16-pair dot with fp32 accumulate: 2 MACs per VALU issue on CDNA (v_dot2_f32_f16).
__device__ __forceinline__ float dot2acc(unsigned a, unsigned b, float c) {
  half2_t ha = __builtin_bit_cast(half2_t, a);
  half2_t hb = __builtin_bit_cast(half2_t, b);
#if __has_builtin(__builtin_amdgcn_fdot2)
  return __builtin_amdgcn_fdot2(ha, hb, c, false);
#else
  c = fmaf((float)ha.x, (float)hb.x, c);
  return fmaf((float)ha.y, (float)hb.y, c);
#endif
}

// ---------------- deform weight reorder: (O,16,9) -> (9,16,O) f32 ----------------
__global__ __launch_bounds__(256) void wreorder_k(
    const float* __restrict__ a, const float* __restrict__ b,
    const float* __restrict__ c, const float* __restrict__ d,
    float* __restrict__ out) {
  int t = blockIdx.x * 256 + threadIdx.x;
  if (t < 6912) {
    int which = t / 2304, r = t % 2304;
    int o = r % 16, kc = r / 16;
    int ci = kc % 16, k = kc / 16;
    const float* w = which == 0 ? a : (which == 1 ? b : c);
    out[t] = w[(o * 16 + ci) * 9 + k];
  } else if (t < 7200) {
    int r = t - 6912;
    int o = r % 2, kc = r / 2;
    int ci = kc % 16, k = kc / 16;
    out[t] = d[(o * 16 + ci) * 9 + k];
  }
}

// ---------------- conv weight pairing: (O,C,9) -> (C/2, 9, O) f16-pairs ----------------
struct WEntry { const float* src; int cin; int cout; int dstoff; };
struct WTable { WEntry e[20]; };  // 17 used
__global__ __launch_bounds__(256) void wpair_conv_k(WTable t, unsigned* __restrict__ out) {
  WEntry en = t.e[blockIdx.y];
  int total = (en.cin >> 1) * 9 * en.cout;
  int i = blockIdx.x * 256 + threadIdx.x;
  if (i >= total) return;
  int o = i % en.cout;
  int k = (i / en.cout) % 9;
  int cp = i / (en.cout * 9);
  float s0 = en.src[((size_t)o * en.cin + 2 * cp) * 9 + k];
  float s1 = en.src[((size_t)o * en.cin + 2 * cp + 1) * 9 + k];
  out[en.dstoff + i] = packh2(s0, s1);
}

// ---------------- fused FE level-0: conv1(f32)+relu -> conv2(dot2)+relu -> pool ----------------
__global__ __launch_bounds__(256) void fe0_fused_k(
    const float* __restrict__ refI, const float* __restrict__ unrI,
    const float* __restrict__ w1, const float* __restrict__ b1,
    const unsigned* __restrict__ w2p, const float* __restrict__ b2,
    float* __restrict__ outR, float* __restrict__ outU, float* __restrict__ outUH) {
  __shared__ unsigned c1buf_u[8 * 361];  // f16 channel-pairs, 19x19 per pair-plane
  __shared__ unsigned sbuf_u[2312];      // phase1: inbuf f32 441; phase3: c2 u16 16*289
  const int z = blockIdx.z;              // im*4 + n
  const int im = z >> 2, n = z & 3;
  const float* img = (im ? unrI : refI) + (size_t)n * 512 * 512;
  float* outp = (im ? outU : outR) + (size_t)n * 16 * 256 * 256;
  const int py0 = blockIdx.y * 8, px0 = blockIdx.x * 8;
  const int tid = threadIdx.x;

  float* inbuf = (float*)sbuf_u;
  for (int i = tid; i < 441; i += 256) {
    int yi = i / 21, xi = i - yi * 21;
    int gy = 2 * py0 - 3 + yi, gx = 2 * px0 - 3 + xi;
    float v = 0.f;
    if (gy >= 0 && gy < 512 && gx >= 0 && gx < 512) v = img[gy * 512 + gx];
    inbuf[i] = v;
  }
  __syncthreads();

  unsigned short* c1w = (unsigned short*)c1buf_u;
  for (int p = tid; p < 361; p += 256) {
    int y1 = p / 19, x1 = p - y1 * 19;
    int gy = 2 * py0 - 2 + y1, gx = 2 * px0 - 2 + x1;
    bool valid = (gy >= 0 && gy < 512 && gx >= 0 && gx < 512);
    float t[9];
#pragma unroll
    for (int k = 0; k < 9; ++k) t[k] = inbuf[(y1 + k / 3) * 21 + x1 + (k % 3)];
#pragma unroll
    for (int c = 0; c < 16; ++c) {
      float a = b1[c];
#pragma unroll
      for (int k = 0; k < 9; ++k) a = fmaf(t[k], w1[c * 9 + k], a);
      c1w[(c >> 1) * 722 + p * 2 + (c & 1)] = f2h(valid ? fmaxf(a, 0.f) : 0.f);
    }
  }
  __syncthreads();

  unsigned short* c2w = (unsigned short*)sbuf_u;
  for (int p = tid; p < 289; p += 256) {
    int y2 = p / 17, x2 = p - y2 * 17;
    float acc[16];
#pragma unroll
    for (int o = 0; o < 16; ++o) acc[o] = b2[o];
#pragma unroll 2
    for (int cp = 0; cp < 8; ++cp) {
      const unsigned* ld = c1buf_u + cp * 361 + y2 * 19 + x2;
      unsigned v[9];
#pragma unroll
      for (int k = 0; k < 9; ++k) v[k] = ld[(k / 3) * 19 + (k % 3)];
      const unsigned* wc = w2p + cp * 144;
#pragma unroll
      for (int k = 0; k < 9; ++k)
#pragma unroll
        for (int o = 0; o < 16; ++o)
          acc[o] = dot2acc(v[k], wc[k * 16 + o], acc[o]);
    }
#pragma unroll
    for (int o = 0; o < 16; ++o) c2w[o * 289 + p] = f2h(fmaxf(acc[o], 0.f));
  }
  __syncthreads();

  // pool: f16 bit-pattern max valid for non-negative post-relu values
  for (int i = tid; i < 1024; i += 256) {
    int c = i >> 6, r = i & 63, py = r >> 3, px = r & 7;
    unsigned short m = 0;
#pragma unroll
    for (int dy = 0; dy < 3; ++dy) {
      int gy = 2 * (py0 + py) - 1 + dy;
      if (gy < 0 || gy >= 512) continue;
#pragma unroll
      for (int dx = 0; dx < 3; ++dx) {
        int gx = 2 * (px0 + px) - 1 + dx;
        if (gx < 0 || gx >= 512) continue;
        unsigned short v = c2w[c * 289 + (2 * py + dy) * 17 + 2 * px + dx];
        m = (v > m) ? v : m;
      }
    }
    float mf = h2f(m);
    outp[((size_t)c * 256 + py0 + py) * 256 + px0 + px] = mf;
    if (im)
      outUH[(((size_t)n * 256 + py0 + py) * 256 + px0 + px) * 16 + c] = mf;
  }
}

// ---------------- fused FE level-1/2: conv(dot2) -> conv(dot2) -> pool ----------------
__global__ __launch_bounds__(256) void fe12_fused_k(
    const float* __restrict__ in,  // (8,16,Hin,Hin) CHW
    const unsigned* __restrict__ w1p, const float* __restrict__ b1,
    const unsigned* __restrict__ w2p, const float* __restrict__ b2,
    float* __restrict__ outC, float* __restrict__ outHWC, int Hin) {
  __shared__ unsigned c1buf_u[8 * 361];  // f16 pairs, 19x19 per pair-plane
  __shared__ unsigned sbuf_u[8 * 441];   // phase1: input pairs 21x21; phase3: c2 u16 16*289
  const int n = blockIdx.z;
  const int Ho = Hin >> 1;
  const int py0 = blockIdx.y * 8, px0 = blockIdx.x * 8;
  const int tid = threadIdx.x;
  const float* inN = in + (size_t)n * 16 * Hin * Hin;
  const size_t HH = (size_t)Hin * Hin;

  for (int i = tid; i < 8 * 441; i += 256) {
    int cp = i / 441, r = i - cp * 441;
    int yi = r / 21, xi = r - yi * 21;
    int gy = 2 * py0 - 3 + yi, gx = 2 * px0 - 3 + xi;
    float v0 = 0.f, v1 = 0.f;
    if (gy >= 0 && gy < Hin && gx >= 0 && gx < Hin) {
      const float* s = inN + (size_t)(2 * cp) * HH + (size_t)gy * Hin + gx;
      v0 = s[0];
      v1 = s[HH];
    }
    sbuf_u[i] = packh2(v0, v1);
  }
  __syncthreads();

  unsigned short* c1w = (unsigned short*)c1buf_u;
  for (int p = tid; p < 361; p += 256) {
    int y1 = p / 19, x1 = p - y1 * 19;
    int gy = 2 * py0 - 2 + y1, gx = 2 * px0 - 2 + x1;
    bool valid = (gy >= 0 && gy < Hin && gx >= 0 && gx < Hin);
    float acc[16];
#pragma unroll
    for (int o = 0; o < 16; ++o) acc[o] = b1[o];
#pragma unroll 2
    for (int cp = 0; cp < 8; ++cp) {
      const unsigned* ld = sbuf_u + cp * 441 + y1 * 21 + x1;
      unsigned v[9];
#pragma unroll
      for (int k = 0; k < 9; ++k) v[k] = ld[(k / 3) * 21 + (k % 3)];
      const unsigned* wc = w1p + cp * 144;
#pragma unroll
      for (int k = 0; k < 9; ++k)
#pragma unroll
        for (int o = 0; o < 16; ++o)
          acc[o] = dot2acc(v[k], wc[k * 16 + o], acc[o]);
    }
#pragma unroll
    for (int o = 0; o < 16; ++o)
      c1w[(o >> 1) * 722 + p * 2 + (o & 1)] = f2h(valid ? fmaxf(acc[o], 0.f) : 0.f);
  }
  __syncthreads();

  unsigned short* c2w = (unsigned short*)sbuf_u;
  for (int p = tid; p < 289; p += 256) {
    int y2 = p / 17, x2 = p - y2 * 17;
    float acc[16];
#pragma unroll
    for (int o = 0; o < 16; ++o) acc[o] = b2[o];
#pragma unroll 2
    for (int cp = 0; cp < 8; ++cp) {
      const unsigned* ld = c1buf_u + cp * 361 + y2 * 19 + x2;
      unsigned v[9];
#pragma unroll
      for (int k = 0; k < 9; ++k) v[k] = ld[(k / 3) * 19 + (k % 3)];
      const unsigned* wc = w2p + cp * 144;
#pragma unroll
      for (int k = 0; k < 9; ++k)
#pragma unroll
        for (int o = 0; o < 16; ++o)
          acc[o] = dot2acc(v[k], wc[k * 16 + o], acc[o]);
    }
#pragma unroll
    for (int o = 0; o < 16; ++o) c2w[o * 289 + p] = f2h(fmaxf(acc[o], 0.f));
  }
  __syncthreads();

  float* outp = outC + (size_t)n * 16 * Ho * Ho;
  for (int i = tid; i < 1024; i += 256) {
    int c = i >> 6, r = i & 63, py = r >> 3, px = r & 7;
    unsigned short m = 0;
#pragma unroll
    for (int dy = 0; dy < 3; ++dy) {
      int gy = 2 * (py0 + py) - 1 + dy;
      if (gy < 0 || gy >= Hin) continue;
#pragma unroll
      for (int dx = 0; dx < 3; ++dx) {
        int gx = 2 * (px0 + px) - 1 + dx;
        if (gx < 0 || gx >= Hin) continue;
        unsigned short v = c2w[c * 289 + (2 * py + dy) * 17 + 2 * px + dx];
        m = (v > m) ? v : m;
      }
    }
    float mf = h2f(m);
    outp[((size_t)c * Ho + py0 + py) * Ho + px0 + px] = mf;
    if (n >= 4)
      outHWC[(((size_t)(n - 4) * Ho + py0 + py) * Ho + px0 + px) * 16 + c] = mf;
  }
}

// ---------------- 3x3 conv v7: v6 structure, f16-pair LDS + dot2 inner loop ----------------
template <int LP, int COUT>
__device__ __forceinline__ void conv_inner2(const unsigned* __restrict__ lds,
                                            const unsigned* __restrict__ wc0,
                                            float* __restrict__ acc, int ty, int tx) {
#pragma unroll
  for (int cp = 0; cp < LP; ++cp) {
    const unsigned* ld = lds + cp * 432 + ty * 24 + tx;
    unsigned v[3][3];
#pragma unroll
    for (int dy = 0; dy < 3; ++dy)
#pragma unroll
      for (int dx = 0; dx < 3; ++dx) v[dy][dx] = ld[dy * 24 + dx];
    const unsigned* wc = wc0 + cp * 9 * COUT;
#pragma unroll
    for (int k = 0; k < 9; ++k) {
#pragma unroll
      for (int o = 0; o < COUT; ++o)
        acc[o] = dot2acc(v[k / 3][k % 3], wc[k * COUT + o], acc[o]);
    }
  }
}

template <int CIN0, int CIN1, int UP1, int COUT>
__global__ __launch_bounds__(256) void conv3x3_v7(
    const float* __restrict__ in0, const float* __restrict__ in1,
    const unsigned* __restrict__ wro, const float* __restrict__ bias,
    float* __restrict__ out, int H, int W, int relu, int ocoff, int ocstride,
    const unsigned* __restrict__ wroB, const float* __restrict__ biasB,
    int ocoffB, int zN, float* __restrict__ outH) {
  constexpr int CIN = CIN0 + CIN1;
  constexpr int CP = CIN / 2;  // all CINs even; pairs never straddle the concat boundary (16)
  constexpr int CHP = (CP < 4) ? CP : 4;
  constexpr int NPASS = (CP + CHP - 1) / CHP;
  constexpr int LASTP = CP - (NPASS - 1) * CHP;
  __shared__ unsigned lds[CHP * 432];
  int n = blockIdx.z;
  if (n >= zN) {  // second weight set (dog half 1)
    n -= zN;
    wro = wroB;
    bias = biasB;
    ocoff = ocoffB;
  }
  const int bx = blockIdx.x * 16, by = blockIdx.y * 16;
  const int tx = threadIdx.x, ty = threadIdx.y;
  const int tid = ty * 16 + tx;
  const int H2 = H >> 1, W2 = W >> 1;
  const float* i0 = in0 + (size_t)n * CIN0 * H * W;
  const float* i1 = in1 ? in1 + (size_t)n * CIN1 * (UP1 ? H2 * W2 : H * W) : nullptr;

  auto fetch = [&](int gc, int gy, int gx) -> float {
    if (CIN1 == 0 || gc < CIN0) return i0[((size_t)gc * H + gy) * W + gx];
    if (!UP1) return i1[((size_t)(gc - CIN0) * H + gy) * W + gx];
    float sy = 0.5f * gy - 0.25f, sx = 0.5f * gx - 0.25f;
    float y0f = floorf(sy), x0f = floorf(sx);
    float wy = sy - y0f, wx = sx - x0f;
    int y0 = (int)y0f, x0 = (int)x0f;
    int y0c = min(max(y0, 0), H2 - 1), y1c = min(max(y0 + 1, 0), H2 - 1);
    int x0c = min(max(x0, 0), W2 - 1), x1c = min(max(x0 + 1, 0), W2 - 1);
    const float* sp = i1 + (size_t)(gc - CIN0) * H2 * W2;
    return (1.f - wy) * ((1.f - wx) * sp[y0c * W2 + x0c] + wx * sp[y0c * W2 + x1c]) +
           wy * ((1.f - wx) * sp[y1c * W2 + x0c] + wx * sp[y1c * W2 + x1c]);
  };

  float acc[COUT];
#pragma unroll
  for (int o = 0; o < COUT; ++o) acc[o] = bias ? bias[o] : 0.f;

  for (int pass = 0; pass < NPASS; ++pass) {
    const int cp0 = pass * CHP;
    const int LP = (pass < NPASS - 1) ? CHP : LASTP;
    if (pass) __syncthreads();
    for (int idx = tid; idx < LP * 324; idx += 256) {
      int cp = idx / 324;
      int r = idx - cp * 324;
      int ly = r / 18, lx = r - ly * 18;
      int gy = by + ly - 1, gx = bx + lx - 1;
      int gc = (cp0 + cp) * 2;
      float v0 = 0.f, v1 = 0.f;
      if (gy >= 0 && gy < H && gx >= 0 && gx < W) {
        v0 = fetch(gc, gy, gx);
        v1 = fetch(gc + 1, gy, gx);
      }
      lds[cp * 432 + ly * 24 + lx] = packh2(v0, v1);
    }
    __syncthreads();
    const unsigned* wc0 = wro + (size_t)cp0 * 9 * COUT;
    if (LP == CHP)
      conv_inner2<CHP, COUT>(lds, wc0, acc, ty, tx);
    else
      conv_inner2<LASTP, COUT>(lds, wc0, acc, ty, tx);
  }

  const int h = by + ty, x = bx + tx;
  float* oh = outH ? outH + ((size_t)n * H * W + (size_t)h * W + x) * 16 : nullptr;
#pragma unroll
  for (int o = 0; o < COUT; ++o) {
    float r = acc[o];
    if (relu) r = fmaxf(r, 0.f);
    out[(((size_t)n * ocstride + ocoff + o) * H + h) * W + x] = r;
    if (outH) oh[o] = r;
  }
}

// ---------------- deformable 3x3 conv (R9-proven): HWC input, XCD swizzle ----------------
template <int COUT, int DG>
__global__ __launch_bounds__(256) void deform_v3(
    const float* __restrict__ inHWC, const float* __restrict__ off,
    const float* __restrict__ wt, float* __restrict__ out,
    int H, int W, int relu, int ocoff, int ocstride) {
  constexpr int CIN = 16;
  constexpr int CG = CIN / DG;
  const int n = blockIdx.y;
  const int HWt = H * W;
  const int nbx = gridDim.x;
  int bxs = blockIdx.x;
  bxs = (bxs & 7) * (nbx >> 3) + (bxs >> 3);
  const int hw = bxs * 256 + threadIdx.x;
  const int h = hw / W, w = hw - h * W;
  const float* inN = inHWC + (size_t)n * HWt * CIN;
  const float* offN = off + (size_t)n * (DG * 18) * HWt + hw;
  float acc[COUT];
#pragma unroll
  for (int o = 0; o < COUT; ++o) acc[o] = 0.f;
#pragma unroll
  for (int g = 0; g < DG; ++g) {
#pragma unroll
    for (int k = 0; k < 9; ++k) {
      const int ky = k / 3 - 1, kx = k % 3 - 1;
      float oy = offN[(size_t)((g * 9 + k) * 2 + 0) * HWt];
      float ox = offN[(size_t)((g * 9 + k) * 2 + 1) * HWt];
      float py = (float)(h + ky) + oy;
      float px = (float)(w + kx) + ox;
      float y0f = floorf(py), x0f = floorf(px);
      float fy = py - y0f, fx = px - x0f;
      int y0 = (int)y0f, x0 = (int)x0f;
      bool vy0 = ((unsigned)y0 < (unsigned)H);
      bool vy1 = ((unsigned)(y0 + 1) < (unsigned)H);
      bool vx0 = ((unsigned)x0 < (unsigned)W);
      bool vx1 = ((unsigned)(x0 + 1) < (unsigned)W);
      int y0c = min(max(y0, 0), H - 1), y1c = min(max(y0 + 1, 0), H - 1);
      int x0c = min(max(x0, 0), W - 1), x1c = min(max(x0 + 1, 0), W - 1);
      float w00 = (vy0 && vx0) ? (1.f - fy) * (1.f - fx) : 0.f;
      float w01 = (vy0 && vx1) ? (1.f - fy) * fx : 0.f;
      float w10 = (vy1 && vx0) ? fy * (1.f - fx) : 0.f;
      float w11 = (vy1 && vx1) ? fy * fx : 0.f;
      const float* p00 = inN + ((size_t)y0c * W + x0c) * CIN + g * CG;
      const float* p01 = inN + ((size_t)y0c * W + x1c) * CIN + g * CG;
      const float* p10 = inN + ((size_t)y1c * W + x0c) * CIN + g * CG;
      const float* p11 = inN + ((size_t)y1c * W + x1c) * CIN + g * CG;
      const float* wk = wt + (k * CIN + g * CG) * COUT;
#pragma unroll
      for (int c4 = 0; c4 < CG / 4; ++c4) {
        float4 a00 = *(const float4*)(p00 + c4 * 4);
        float4 a01 = *(const float4*)(p01 + c4 * 4);
        float4 a10 = *(const float4*)(p10 + c4 * 4);
        float4 a11 = *(const float4*)(p11 + c4 * 4);
        float v0 = w00 * a00.x + w01 * a01.x + w10 * a10.x + w11 * a11.x;
        float v1 = w00 * a00.y + w01 * a01.y + w10 * a10.y + w11 * a11.y;
        float v2 = w00 * a00.z + w01 * a01.z + w10 * a10.z + w11 * a11.z;
        float v3 = w00 * a00.w + w01 * a01.w + w10 * a10.w + w11 * a11.w;
#pragma unroll
        for (int o = 0; o < COUT; ++o) {
          float t0 = fmaf(v0, wk[(c4 * 4 + 0) * COUT + o], acc[o]);
          t0 = fmaf(v1, wk[(c4 * 4 + 1) * COUT + o], t0);
          t0 = fmaf(v2, wk[(c4 * 4 + 2) * COUT + o], t0);
          acc[o] = fmaf(v3, wk[(c4 * 4 + 3) * COUT + o], t0);
        }
      }
    }
  }
  float* outN = out + ((size_t)n * ocstride + ocoff) * HWt + hw;
#pragma unroll
  for (int o = 0; o < COUT; ++o) {
    float r = acc[o];
    if (relu) r = fmaxf(r, 0.f);
    outN[(size_t)o * HWt] = r;
  }
}

// ---------------- host-side launch helpers ----------------
template <int C0, int C1, int UP, int CO>
static void LC(hipStream_t s, const float* a, const float* b, const unsigned* w,
               const float* bi, float* o, int N, int H, int W, bool relu,
               int ocoff, int ocstride,
               const unsigned* wB = nullptr, const float* biB = nullptr, int ocoffB = 0,
               float* outH = nullptr) {
  int zn = wB ? 2 * N : N;
  conv3x3_v7<C0, C1, UP, CO><<<dim3(W / 16, H / 16, zn), dim3(16, 16), 0, s>>>(
      a, b, w, bi, o, H, W, relu ? 1 : 0, ocoff, ocstride, wB, biB, ocoffB, N, outH);
}

static void L_deform3(hipStream_t s, const float* inHWC, const float* off, const float* wt,
                      float* out, int N, int H, int W, int dg, int Cout, bool relu,
                      int ocoff, int ocstride) {
  dim3 grd(H * W / 256, N);
  int r = relu ? 1 : 0;
  if (Cout == 16 && dg == 1)
    deform_v3<16, 1><<<grd, 256, 0, s>>>(inHWC, off, wt, out, H, W, r, ocoff, ocstride);
  else if (Cout == 2 && dg == 2)
    deform_v3<2, 2><<<grd, 256, 0, s>>>(inHWC, off, wt, out, H, W, r, ocoff, ocstride);
}

extern "C" void kernel_launch(void* const* d_in, const int* in_sizes, int n_in,
                              void* d_out, int out_size, void* d_ws, size_t ws_size,
                              hipStream_t stream) {
  auto F = [&](int i) { return (const float*)d_in[i]; };
  const float* ref = F(0);
  const float* unr = F(1);
  const float* few1[3] = {F(2), F(6), F(10)};
  const float* feb1[3] = {F(3), F(7), F(11)};
  const float* few2[3] = {F(4), F(8), F(12)};
  const float* feb2[3] = {F(5), F(9), F(13)};
  const float* obw[3] = {F(14), F(16), F(18)};
  const float* obb[3] = {F(15), F(17), F(19)};
  const float* ogw[3] = {F(20), F(22), F(24)};
  const float* ogb[3] = {F(21), F(23), F(25)};
  const float* dcw[3] = {F(26), F(27), F(28)};
  const float* fcw[3] = {F(29), F(31), F(33)};
  const float* fcb[3] = {F(30), F(32), F(34)};
  const float* dobw = F(35);
  const float* dobb = F(36);
  const float* dogw = F(37);
  const float* dogb = F(38);
  const float* ddcw = F(39);

  // ---- workspace layout (floats). rf/uf contiguous; HWC aliases into feats[i]. ----
  float* ws = (float*)d_ws;
  size_t p = 0;
  auto alloc = [&](size_t nf) { float* r = ws + p; p += nf; return r; };
  const size_t SC = 9437184;
  float* A = alloc(SC);
  float* Bf = alloc(SC);
  float* rf[3], *uf[3], *offs[3], *feats[3];
  rf[0] = alloc((size_t)4 * 16 * 256 * 256);
  uf[0] = alloc((size_t)4 * 16 * 256 * 256);
  rf[1] = alloc((size_t)4 * 16 * 128 * 128);
  uf[1] = alloc((size_t)4 * 16 * 128 * 128);
  rf[2] = alloc((size_t)4 * 16 * 64 * 64);
  uf[2] = alloc((size_t)4 * 16 * 64 * 64);
  offs[0] = alloc((size_t)4 * 18 * 256 * 256);
  offs[1] = alloc((size_t)4 * 18 * 128 * 128);
  offs[2] = alloc((size_t)4 * 18 * 64 * 64);
  feats[0] = alloc((size_t)4 * 16 * 256 * 256);
  feats[1] = alloc((size_t)4 * 16 * 128 * 128);
  feats[2] = alloc((size_t)4 * 16 * 64 * 64);
  float* wt = alloc(7200);
  float* cw = alloc(70000);  // used as u32 f16-pair table (33048 needed)
  if (p * sizeof(float) > ws_size) return;
  const float* wt_dc[3] = {wt, wt + 2304, wt + 4608};
  const float* wt_ddc = wt + 6912;
  unsigned* cwp = (unsigned*)cw;
  float* ufH[3] = {feats[0], feats[1], feats[2]};  // HWC aliases (liveness audited)
  float* fHwc = Bf + (size_t)4 * 16 * 256 * 256;   // Bf tail, live only at the end

  // ---- build paired conv weight table (17 entries) ----
  WTable T;
  int nw = 0, woff = 0, maxtot = 0;
  auto addw = [&](const float* src, int cin, int cout) {
    T.e[nw].src = src; T.e[nw].cin = cin; T.e[nw].cout = cout; T.e[nw].dstoff = woff;
    int tot = (cin >> 1) * cout * 9;
    if (tot > maxtot) maxtot = tot;
    int start = woff;
    woff += tot;
    ++nw;
    return start;
  };
  int o_few2_0 = addw(few2[0], 16, 16);
  int o_few1_1 = addw(few1[1], 16, 16);
  int o_few2_1 = addw(few2[1], 16, 16);
  int o_few1_2 = addw(few1[2], 16, 16);
  int o_few2_2 = addw(few2[2], 16, 16);
  int o_ob[3], o_og[3], o_fc[3];
  for (int i = 0; i < 3; ++i) o_ob[i] = addw(obw[i], 32, 16);
  o_og[0] = addw(ogw[0], 34, 18);
  o_og[1] = addw(ogw[1], 34, 18);
  o_og[2] = addw(ogw[2], 16, 18);
  for (int i = 0; i < 3; ++i) o_fc[i] = addw(fcw[i], i == 2 ? 16 : 32, 16);
  int o_dob = addw(dobw, 32, 16);
  int o_dog0 = addw(dogw, 34, 18);
  int o_dog1 = addw(dogw + (size_t)18 * 34 * 9, 34, 18);

  wreorder_k<<<29, 256, 0, stream>>>(dcw[0], dcw[1], dcw[2], ddcw, wt);
  wpair_conv_k<<<dim3((maxtot + 255) / 256, nw), 256, 0, stream>>>(T, cwp);

  // ---- FE level 0: fused conv1+conv2+pool; uf[0] dual-written CHW + HWC ----
  fe0_fused_k<<<dim3(32, 32, 8), 256, 0, stream>>>(
      ref, unr, few1[0], feb1[0], cwp + o_few2_0, feb2[0], rf[0], uf[0], ufH[0]);

  // ---- FE levels 1/2: fused conv+conv+pool, N=8; uf HWC dual-written ----
  fe12_fused_k<<<dim3(16, 16, 8), 256, 0, stream>>>(
      rf[0], cwp + o_few1_1, feb1[1], cwp + o_few2_1, feb2[1], rf[1], ufH[1], 256);
  fe12_fused_k<<<dim3(8, 8, 8), 256, 0, stream>>>(
      rf[1], cwp + o_few1_2, feb1[2], cwp + o_few2_2, feb2[2], rf[2], ufH[2], 128);

  // ---- coarse-to-fine alignment (up2 fused into og/fc staging at i<2) ----
  int Hs[3] = {256, 128, 64};
  for (int i = 2; i >= 0; --i) {
    int H = Hs[i];
    float* oBuf = Bf;  // 16ch compact
    float* fBuf = A;   // 16ch compact (deform out)
    if (i == 2) {
      LC<16, 16, 0, 16>(stream, rf[2], uf[2], cwp + o_ob[2], obb[2], oBuf, 4, H, H, true, 0, 16);
      LC<16, 0, 0, 18>(stream, oBuf, nullptr, cwp + o_og[2], ogb[2], offs[2], 4, H, H, true, 0, 18);
      L_deform3(stream, ufH[2], offs[2], wt_dc[2], fBuf, 4, H, H, 1, 16, true, 0, 16);
      LC<16, 0, 0, 16>(stream, fBuf, nullptr, cwp + o_fc[2], fcb[2], feats[2], 4, H, H, true, 0, 16);
    } else {
      LC<16, 16, 0, 16>(stream, rf[i], uf[i], cwp + o_ob[i], obb[i], oBuf, 4, H, H, true, 0, 16);
      LC<16, 18, 1, 18>(stream, oBuf, offs[i + 1], cwp + o_og[i], ogb[i], offs[i], 4, H, H, true, 0, 18);
      L_deform3(stream, ufH[i], offs[i], wt_dc[i], fBuf, 4, H, H, 1, 16, true, 0, 16);
      LC<16, 16, 1, 16>(stream, fBuf, feats[i + 1], cwp + o_fc[i], fcb[i], feats[i], 4, H, H, true,
                        0, 16, nullptr, nullptr, 0, i == 0 ? fHwc : nullptr);
    }
  }

  // ---- final offset head + deform (dg=2); dog halves merged via z-split ----
  float* doBuf = Bf;  // 16ch
  LC<16, 16, 0, 16>(stream, rf[0], feats[0], cwp + o_dob, dobb, doBuf, 4, 256, 256, false, 0, 16);
  LC<16, 18, 0, 18>(stream, doBuf, offs[0], cwp + o_dog0, dogb, A, 4, 256, 256, false, 0, 36,
                    cwp + o_dog1, dogb + 18, 18);
  L_deform3(stream, fHwc, A, wt_ddc, (float*)d_out, 4, 256, 256, 2, 2, false, 0, 2);
}

// Round 14
// 998.172 us; speedup vs baseline: 1.6015x; 1.1909x over previous
//
#include <hip/hip_runtime.h>
#include <math.h>

typedef _Float16 half2_t __attribute__((ext_vector_type(2)));

__device__ __forceinline__ unsigned packh2(float a, float b) {
  half2_t h;
  h.x = (_Float16)a;
  h.y = (_Float16)b;
  return __builtin_bit_cast(unsigned, h);
}
__device__ __forceinline__ unsigned short f2h(float a) {
  return __builtin_bit_cast(unsigned short, (_Float16)a);
}
__device__ __forceinline__ float h2f(unsigned short u) {
  return (float)__builtin_bit_cast(_Float16, u);
}
__device__ __forceinline__ float dot2acc(unsigned a, unsigned b, float c) {
  half2_t ha = __builtin_bit_cast(half2_t, a);
  half2_t hb = __builtin_bit_cast(half2_t, b);
#if __has_builtin(__builtin_amdgcn_fdot2)
  return __builtin_amdgcn_fdot2(ha, hb, c, false);
#else
  c = fmaf((float)ha.x, (float)hb.x, c);
  return fmaf((float)ha.y, (float)hb.y, c);
#endif
}

// ---------------- deform weight reorder: (O,16,9) -> (9,16,O) f32 ----------------
__global__ __launch_bounds__(256) void wreorder_k(
    const float* __restrict__ a, const float* __restrict__ b,
    const float* __restrict__ c, const float* __restrict__ d,
    float* __restrict__ out) {
  int t = blockIdx.x * 256 + threadIdx.x;
  if (t < 6912) {
    int which = t / 2304, r = t % 2304;
    int o = r % 16, kc = r / 16;
    int ci = kc % 16, k = kc / 16;
    const float* w = which == 0 ? a : (which == 1 ? b : c);
    out[t] = w[(o * 16 + ci) * 9 + k];
  } else if (t < 7200) {
    int r = t - 6912;
    int o = r % 2, kc = r / 2;
    int ci = kc % 16, k = kc / 16;
    out[t] = d[(o * 16 + ci) * 9 + k];
  }
}

// ---------------- conv weight pairing: (O,C,9) -> (C/2, 9, O) f16-pairs ----------------
struct WEntry { const float* src; int cin; int cout; int dstoff; };
struct WTable { WEntry e[20]; };  // 16 used
__global__ __launch_bounds__(256) void wpair_conv_k(WTable t, unsigned* __restrict__ out) {
  WEntry en = t.e[blockIdx.y];
  int total = (en.cin >> 1) * 9 * en.cout;
  int i = blockIdx.x * 256 + threadIdx.x;
  if (i >= total) return;
  int o = i % en.cout;
  int k = (i / en.cout) % 9;
  int cp = i / (en.cout * 9);
  float s0 = en.src[((size_t)o * en.cin + 2 * cp) * 9 + k];
  float s1 = en.src[((size_t)o * en.cin + 2 * cp + 1) * 9 + k];
  out[en.dstoff + i] = packh2(s0, s1);
}

// ---------------- fused FE level-0 (R13-proven) ----------------
__global__ __launch_bounds__(256) void fe0_fused_k(
    const float* __restrict__ refI, const float* __restrict__ unrI,
    const float* __restrict__ w1, const float* __restrict__ b1,
    const unsigned* __restrict__ w2p, const float* __restrict__ b2,
    float* __restrict__ outR, float* __restrict__ outU, float* __restrict__ outUH) {
  __shared__ unsigned c1buf_u[8 * 361];
  __shared__ unsigned sbuf_u[2312];
  const int z = blockIdx.z;
  const int im = z >> 2, n = z & 3;
  const float* img = (im ? unrI : refI) + (size_t)n * 512 * 512;
  float* outp = (im ? outU : outR) + (size_t)n * 16 * 256 * 256;
  const int py0 = blockIdx.y * 8, px0 = blockIdx.x * 8;
  const int tid = threadIdx.x;

  float* inbuf = (float*)sbuf_u;
  for (int i = tid; i < 441; i += 256) {
    int yi = i / 21, xi = i - yi * 21;
    int gy = 2 * py0 - 3 + yi, gx = 2 * px0 - 3 + xi;
    float v = 0.f;
    if (gy >= 0 && gy < 512 && gx >= 0 && gx < 512) v = img[gy * 512 + gx];
    inbuf[i] = v;
  }
  __syncthreads();

  unsigned short* c1w = (unsigned short*)c1buf_u;
  for (int p = tid; p < 361; p += 256) {
    int y1 = p / 19, x1 = p - y1 * 19;
    int gy = 2 * py0 - 2 + y1, gx = 2 * px0 - 2 + x1;
    bool valid = (gy >= 0 && gy < 512 && gx >= 0 && gx < 512);
    float t[9];
#pragma unroll
    for (int k = 0; k < 9; ++k) t[k] = inbuf[(y1 + k / 3) * 21 + x1 + (k % 3)];
#pragma unroll
    for (int c = 0; c < 16; ++c) {
      float a = b1[c];
#pragma unroll
      for (int k = 0; k < 9; ++k) a = fmaf(t[k], w1[c * 9 + k], a);
      c1w[(c >> 1) * 722 + p * 2 + (c & 1)] = f2h(valid ? fmaxf(a, 0.f) : 0.f);
    }
  }
  __syncthreads();

  unsigned short* c2w = (unsigned short*)sbuf_u;
  for (int p = tid; p < 289; p += 256) {
    int y2 = p / 17, x2 = p - y2 * 17;
    float acc[16];
#pragma unroll
    for (int o = 0; o < 16; ++o) acc[o] = b2[o];
#pragma unroll 2
    for (int cp = 0; cp < 8; ++cp) {
      const unsigned* ld = c1buf_u + cp * 361 + y2 * 19 + x2;
      unsigned v[9];
#pragma unroll
      for (int k = 0; k < 9; ++k) v[k] = ld[(k / 3) * 19 + (k % 3)];
      const unsigned* wc = w2p + cp * 144;
#pragma unroll
      for (int k = 0; k < 9; ++k)
#pragma unroll
        for (int o = 0; o < 16; ++o)
          acc[o] = dot2acc(v[k], wc[k * 16 + o], acc[o]);
    }
#pragma unroll
    for (int o = 0; o < 16; ++o) c2w[o * 289 + p] = f2h(fmaxf(acc[o], 0.f));
  }
  __syncthreads();

  for (int i = tid; i < 1024; i += 256) {
    int c = i >> 6, r = i & 63, py = r >> 3, px = r & 7;
    unsigned short m = 0;
#pragma unroll
    for (int dy = 0; dy < 3; ++dy) {
      int gy = 2 * (py0 + py) - 1 + dy;
      if (gy < 0 || gy >= 512) continue;
#pragma unroll
      for (int dx = 0; dx < 3; ++dx) {
        int gx = 2 * (px0 + px) - 1 + dx;
        if (gx < 0 || gx >= 512) continue;
        unsigned short v = c2w[c * 289 + (2 * py + dy) * 17 + 2 * px + dx];
        m = (v > m) ? v : m;
      }
    }
    float mf = h2f(m);
    outp[((size_t)c * 256 + py0 + py) * 256 + px0 + px] = mf;
    if (im)
      outUH[(((size_t)n * 256 + py0 + py) * 256 + px0 + px) * 16 + c] = mf;
  }
}

// ---------------- fused FE level-1/2 (R13-proven) ----------------
__global__ __launch_bounds__(256) void fe12_fused_k(
    const float* __restrict__ in,
    const unsigned* __restrict__ w1p, const float* __restrict__ b1,
    const unsigned* __restrict__ w2p, const float* __restrict__ b2,
    float* __restrict__ outC, float* __restrict__ outHWC, int Hin) {
  __shared__ unsigned c1buf_u[8 * 361];
  __shared__ unsigned sbuf_u[8 * 441];
  const int n = blockIdx.z;
  const int Ho = Hin >> 1;
  const int py0 = blockIdx.y * 8, px0 = blockIdx.x * 8;
  const int tid = threadIdx.x;
  const float* inN = in + (size_t)n * 16 * Hin * Hin;
  const size_t HH = (size_t)Hin * Hin;

  for (int i = tid; i < 8 * 441; i += 256) {
    int cp = i / 441, r = i - cp * 441;
    int yi = r / 21, xi = r - yi * 21;
    int gy = 2 * py0 - 3 + yi, gx = 2 * px0 - 3 + xi;
    float v0 = 0.f, v1 = 0.f;
    if (gy >= 0 && gy < Hin && gx >= 0 && gx < Hin) {
      const float* s = inN + (size_t)(2 * cp) * HH + (size_t)gy * Hin + gx;
      v0 = s[0];
      v1 = s[HH];
    }
    sbuf_u[i] = packh2(v0, v1);
  }
  __syncthreads();

  unsigned short* c1w = (unsigned short*)c1buf_u;
  for (int p = tid; p < 361; p += 256) {
    int y1 = p / 19, x1 = p - y1 * 19;
    int gy = 2 * py0 - 2 + y1, gx = 2 * px0 - 2 + x1;
    bool valid = (gy >= 0 && gy < Hin && gx >= 0 && gx < Hin);
    float acc[16];
#pragma unroll
    for (int o = 0; o < 16; ++o) acc[o] = b1[o];
#pragma unroll 2
    for (int cp = 0; cp < 8; ++cp) {
      const unsigned* ld = sbuf_u + cp * 441 + y1 * 21 + x1;
      unsigned v[9];
#pragma unroll
      for (int k = 0; k < 9; ++k) v[k] = ld[(k / 3) * 21 + (k % 3)];
      const unsigned* wc = w1p + cp * 144;
#pragma unroll
      for (int k = 0; k < 9; ++k)
#pragma unroll
        for (int o = 0; o < 16; ++o)
          acc[o] = dot2acc(v[k], wc[k * 16 + o], acc[o]);
    }
#pragma unroll
    for (int o = 0; o < 16; ++o)
      c1w[(o >> 1) * 722 + p * 2 + (o & 1)] = f2h(valid ? fmaxf(acc[o], 0.f) : 0.f);
  }
  __syncthreads();

  unsigned short* c2w = (unsigned short*)sbuf_u;
  for (int p = tid; p < 289; p += 256) {
    int y2 = p / 17, x2 = p - y2 * 17;
    float acc[16];
#pragma unroll
    for (int o = 0; o < 16; ++o) acc[o] = b2[o];
#pragma unroll 2
    for (int cp = 0; cp < 8; ++cp) {
      const unsigned* ld = c1buf_u + cp * 361 + y2 * 19 + x2;
      unsigned v[9];
#pragma unroll
      for (int k = 0; k < 9; ++k) v[k] = ld[(k / 3) * 19 + (k % 3)];
      const unsigned* wc = w2p + cp * 144;
#pragma unroll
      for (int k = 0; k < 9; ++k)
#pragma unroll
        for (int o = 0; o < 16; ++o)
          acc[o] = dot2acc(v[k], wc[k * 16 + o], acc[o]);
    }
#pragma unroll
    for (int o = 0; o < 16; ++o) c2w[o * 289 + p] = f2h(fmaxf(acc[o], 0.f));
  }
  __syncthreads();

  float* outp = outC + (size_t)n * 16 * Ho * Ho;
  for (int i = tid; i < 1024; i += 256) {
    int c = i >> 6, r = i & 63, py = r >> 3, px = r & 7;
    unsigned short m = 0;
#pragma unroll
    for (int dy = 0; dy < 3; ++dy) {
      int gy = 2 * (py0 + py) - 1 + dy;
      if (gy < 0 || gy >= Hin) continue;
#pragma unroll
      for (int dx = 0; dx < 3; ++dx) {
        int gx = 2 * (px0 + px) - 1 + dx;
        if (gx < 0 || gx >= Hin) continue;
        unsigned short v = c2w[c * 289 + (2 * py + dy) * 17 + 2 * px + dx];
        m = (v > m) ? v : m;
      }
    }
    float mf = h2f(m);
    outp[((size_t)c * Ho + py0 + py) * Ho + px0 + px] = mf;
    if (n >= 4)
      outHWC[(((size_t)(n - 4) * Ho + py0 + py) * Ho + px0 + px) * 16 + c] = mf;
  }
}

// ---------------- fused offset head: ob(18x18 halo) -> og(16x16) -> offs ----------------
template <int HAS_UP>
__global__ __launch_bounds__(256) void obog_k(
    const float* __restrict__ rf, const float* __restrict__ uf,
    const float* __restrict__ offsUp,
    const unsigned* __restrict__ wob, const float* __restrict__ bob,
    const unsigned* __restrict__ wog, const float* __restrict__ bog,
    float* __restrict__ offsOut, int H) {
  __shared__ unsigned ldsA[16 * 400];  // phase1: cat(rf,uf) 20x20 pairs; phase3 overlay: up2 pairs
  __shared__ unsigned ldsB[8 * 324];   // ob out pairs, 18x18
  const int n = blockIdx.z;
  const int bx = blockIdx.x * 16, by = blockIdx.y * 16;
  const int tid = threadIdx.x;
  const size_t HH = (size_t)H * H;
  const float* r0 = rf + (size_t)n * 16 * HH;
  const float* u0 = uf + (size_t)n * 16 * HH;

  for (int i = tid; i < 16 * 400; i += 256) {
    int cp = i / 400, r = i - cp * 400;
    int ly = r / 20, lx = r - ly * 20;
    int gy = by + ly - 2, gx = bx + lx - 2;
    float v0 = 0.f, v1 = 0.f;
    if (gy >= 0 && gy < H && gx >= 0 && gx < H) {
      const float* s = (cp < 8) ? r0 + (size_t)(2 * cp) * HH : u0 + (size_t)(2 * cp - 16) * HH;
      size_t off = (size_t)gy * H + gx;
      v0 = s[off];
      v1 = s[HH + off];
    }
    ldsA[i] = packh2(v0, v1);
  }
  __syncthreads();

  // ob: 18x18 x16, relu, zeroed at image-OOB (= zero-pad input for og)
  unsigned short* obw16 = (unsigned short*)ldsB;
  for (int p = tid; p < 324; p += 256) {
    int y1 = p / 18, x1 = p - y1 * 18;
    int gy = by + y1 - 1, gx = bx + x1 - 1;
    bool valid = (gy >= 0 && gy < H && gx >= 0 && gx < H);
    float acc[16];
#pragma unroll
    for (int o = 0; o < 16; ++o) acc[o] = bob[o];
#pragma unroll 2
    for (int cp = 0; cp < 16; ++cp) {
      const unsigned* ld = ldsA + cp * 400 + y1 * 20 + x1;
      unsigned v[9];
#pragma unroll
      for (int k = 0; k < 9; ++k) v[k] = ld[(k / 3) * 20 + (k % 3)];
      const unsigned* wc = wob + cp * 144;
#pragma unroll
      for (int k = 0; k < 9; ++k)
#pragma unroll
        for (int o = 0; o < 16; ++o)
          acc[o] = dot2acc(v[k], wc[k * 16 + o], acc[o]);
    }
#pragma unroll
    for (int o = 0; o < 16; ++o)
      obw16[(o >> 1) * 648 + 2 * p + (o & 1)] = f2h(valid ? fmaxf(acc[o], 0.f) : 0.f);
  }
  __syncthreads();

  if (HAS_UP) {  // overlay ldsA with up2(offsUp), 18ch -> 9 pairs x 18x18
    const int H2 = H >> 1;
    const float* os = offsUp + (size_t)n * 18 * H2 * H2;
    for (int i = tid; i < 9 * 324; i += 256) {
      int cp = i / 324, r = i - cp * 324;
      int y1 = r / 18, x1 = r - y1 * 18;
      int gy = by + y1 - 1, gx = bx + x1 - 1;
      float v0 = 0.f, v1 = 0.f;
      if (gy >= 0 && gy < H && gx >= 0 && gx < H) {
        float sy = 0.5f * gy - 0.25f, sx = 0.5f * gx - 0.25f;
        float y0f = floorf(sy), x0f = floorf(sx);
        float wy = sy - y0f, wx = sx - x0f;
        int y0 = (int)y0f, x0 = (int)x0f;
        int y0c = min(max(y0, 0), H2 - 1), y1c = min(max(y0 + 1, 0), H2 - 1);
        int x0c = min(max(x0, 0), H2 - 1), x1c = min(max(x0 + 1, 0), H2 - 1);
        const float* sp = os + (size_t)(2 * cp) * H2 * H2;
        v0 = (1.f - wy) * ((1.f - wx) * sp[y0c * H2 + x0c] + wx * sp[y0c * H2 + x1c]) +
             wy * ((1.f - wx) * sp[y1c * H2 + x0c] + wx * sp[y1c * H2 + x1c]);
        sp += (size_t)H2 * H2;
        v1 = (1.f - wy) * ((1.f - wx) * sp[y0c * H2 + x0c] + wx * sp[y0c * H2 + x1c]) +
             wy * ((1.f - wx) * sp[y1c * H2 + x0c] + wx * sp[y1c * H2 + x1c]);
      }
      ldsA[i] = packh2(v0, v1);
    }
    __syncthreads();
  }

  // og: 16x16 x18 -> offs (relu)
  {
    int ty = tid >> 4, tx = tid & 15;
    float acc[18];
#pragma unroll
    for (int o = 0; o < 18; ++o) acc[o] = bog[o];
#pragma unroll 2
    for (int cp = 0; cp < 8; ++cp) {
      const unsigned* ld = ldsB + cp * 324 + ty * 18 + tx;
      unsigned v[9];
#pragma unroll
      for (int k = 0; k < 9; ++k) v[k] = ld[(k / 3) * 18 + (k % 3)];
      const unsigned* wc = wog + cp * 162;
#pragma unroll
      for (int k = 0; k < 9; ++k)
#pragma unroll
        for (int o = 0; o < 18; ++o)
          acc[o] = dot2acc(v[k], wc[k * 18 + o], acc[o]);
    }
    if (HAS_UP) {
#pragma unroll 2
      for (int cp = 0; cp < 9; ++cp) {
        const unsigned* ld = ldsA + cp * 324 + ty * 18 + tx;
        unsigned v[9];
#pragma unroll
        for (int k = 0; k < 9; ++k) v[k] = ld[(k / 3) * 18 + (k % 3)];
        const unsigned* wc = wog + (8 + cp) * 162;
#pragma unroll
        for (int k = 0; k < 9; ++k)
#pragma unroll
          for (int o = 0; o < 18; ++o)
            acc[o] = dot2acc(v[k], wc[k * 18 + o], acc[o]);
      }
    }
    float* op = offsOut + (size_t)n * 18 * HH + (size_t)(by + ty) * H + (bx + tx);
#pragma unroll
    for (int o = 0; o < 18; ++o) op[(size_t)o * HH] = fmaxf(acc[o], 0.f);
  }
}

// ---------------- fused feature head: deform(18x18 halo) -> fc(16x16) -> feats ----------------
template <int HAS_UP>
__global__ __launch_bounds__(256) void defc_k(
    const float* __restrict__ ufHWC, const float* __restrict__ offs,
    const float* __restrict__ wdef, const float* __restrict__ featsUp,
    const unsigned* __restrict__ wfc, const float* __restrict__ bfc,
    float* __restrict__ featsOut, float* __restrict__ outHwc, int H) {
  __shared__ unsigned ldsF[8 * 324];  // deform out pairs
  __shared__ unsigned ldsU[8 * 324];  // up2(featsUp) pairs
  const int n = blockIdx.z;
  const int bx = blockIdx.x * 16, by = blockIdx.y * 16;
  const int tid = threadIdx.x;
  const size_t HH = (size_t)H * H;
  const float* inN = ufHWC + (size_t)n * HH * 16;
  const float* offN = offs + (size_t)n * 18 * HH;

  unsigned short* fw16 = (unsigned short*)ldsF;
  for (int p = tid; p < 324; p += 256) {
    int y1 = p / 18, x1 = p - y1 * 18;
    int h = by + y1 - 1, w = bx + x1 - 1;
    bool valid = (h >= 0 && h < H && w >= 0 && w < H);
    float acc[16];
#pragma unroll
    for (int o = 0; o < 16; ++o) acc[o] = 0.f;
    if (valid) {
      size_t hw = (size_t)h * H + w;
#pragma unroll
      for (int k = 0; k < 9; ++k) {
        int ky = k / 3 - 1, kx = k % 3 - 1;
        float oy = offN[(size_t)(2 * k) * HH + hw];
        float ox = offN[(size_t)(2 * k + 1) * HH + hw];
        float py = (float)(h + ky) + oy;
        float px = (float)(w + kx) + ox;
        float y0f = floorf(py), x0f = floorf(px);
        float fy = py - y0f, fx = px - x0f;
        int y0 = (int)y0f, x0 = (int)x0f;
        bool vy0 = ((unsigned)y0 < (unsigned)H);
        bool vy1 = ((unsigned)(y0 + 1) < (unsigned)H);
        bool vx0 = ((unsigned)x0 < (unsigned)H);
        bool vx1 = ((unsigned)(x0 + 1) < (unsigned)H);
        int y0c = min(max(y0, 0), H - 1), y1c = min(max(y0 + 1, 0), H - 1);
        int x0c = min(max(x0, 0), H - 1), x1c = min(max(x0 + 1, 0), H - 1);
        float w00 = (vy0 && vx0) ? (1.f - fy) * (1.f - fx) : 0.f;
        float w01 = (vy0 && vx1) ? (1.f - fy) * fx : 0.f;
        float w10 = (vy1 && vx0) ? fy * (1.f - fx) : 0.f;
        float w11 = (vy1 && vx1) ? fy * fx : 0.f;
        const float* p00 = inN + ((size_t)y0c * H + x0c) * 16;
        const float* p01 = inN + ((size_t)y0c * H + x1c) * 16;
        const float* p10 = inN + ((size_t)y1c * H + x0c) * 16;
        const float* p11 = inN + ((size_t)y1c * H + x1c) * 16;
        const float* wk = wdef + (size_t)k * 256;
#pragma unroll
        for (int c4 = 0; c4 < 4; ++c4) {
          float4 a00 = *(const float4*)(p00 + c4 * 4);
          float4 a01 = *(const float4*)(p01 + c4 * 4);
          float4 a10 = *(const float4*)(p10 + c4 * 4);
          float4 a11 = *(const float4*)(p11 + c4 * 4);
          float v0 = w00 * a00.x + w01 * a01.x + w10 * a10.x + w11 * a11.x;
          float v1 = w00 * a00.y + w01 * a01.y + w10 * a10.y + w11 * a11.y;
          float v2 = w00 * a00.z + w01 * a01.z + w10 * a10.z + w11 * a11.z;
          float v3 = w00 * a00.w + w01 * a01.w + w10 * a10.w + w11 * a11.w;
#pragma unroll
          for (int o = 0; o < 16; ++o) {
            float t0 = fmaf(v0, wk[(c4 * 4 + 0) * 16 + o], acc[o]);
            t0 = fmaf(v1, wk[(c4 * 4 + 1) * 16 + o], t0);
            t0 = fmaf(v2, wk[(c4 * 4 + 2) * 16 + o], t0);
            acc[o] = fmaf(v3, wk[(c4 * 4 + 3) * 16 + o], t0);
          }
        }
      }
    }
#pragma unroll
    for (int o = 0; o < 16; ++o)
      fw16[(o >> 1) * 648 + 2 * p + (o & 1)] = f2h(valid ? fmaxf(acc[o], 0.f) : 0.f);
  }

  if (HAS_UP) {  // independent buffer; one barrier covers both phases
    const int H2 = H >> 1;
    const float* fu = featsUp + (size_t)n * 16 * H2 * H2;
    for (int i = tid; i < 8 * 324; i += 256) {
      int cp = i / 324, r = i - cp * 324;
      int y1 = r / 18, x1 = r - y1 * 18;
      int gy = by + y1 - 1, gx = bx + x1 - 1;
      float v0 = 0.f, v1 = 0.f;
      if (gy >= 0 && gy < H && gx >= 0 && gx < H) {
        float sy = 0.5f * gy - 0.25f, sx = 0.5f * gx - 0.25f;
        float y0f = floorf(sy), x0f = floorf(sx);
        float wy = sy - y0f, wx = sx - x0f;
        int y0 = (int)y0f, x0 = (int)x0f;
        int y0c = min(max(y0, 0), H2 - 1), y1c = min(max(y0 + 1, 0), H2 - 1);
        int x0c = min(max(x0, 0), H2 - 1), x1c = min(max(x0 + 1, 0), H2 - 1);
        const float* sp = fu + (size_t)(2 * cp) * H2 * H2;
        v0 = (1.f - wy) * ((1.f - wx) * sp[y0c * H2 + x0c] + wx * sp[y0c * H2 + x1c]) +
             wy * ((1.f - wx) * sp[y1c * H2 + x0c] + wx * sp[y1c * H2 + x1c]);
        sp += (size_t)H2 * H2;
        v1 = (1.f - wy) * ((1.f - wx) * sp[y0c * H2 + x0c] + wx * sp[y0c * H2 + x1c]) +
             wy * ((1.f - wx) * sp[y1c * H2 + x0c] + wx * sp[y1c * H2 + x1c]);
      }
      ldsU[i] = packh2(v0, v1);
    }
  }
  __syncthreads();

  // fc: 16x16 x16 (relu) -> feats CHW (+ optional HWC)
  {
    int ty = tid >> 4, tx = tid & 15;
    float acc[16];
#pragma unroll
    for (int o = 0; o < 16; ++o) acc[o] = bfc[o];
#pragma unroll 2
    for (int cp = 0; cp < 8; ++cp) {
      const unsigned* ld = ldsF + cp * 324 + ty * 18 + tx;
      unsigned v[9];
#pragma unroll
      for (int k = 0; k < 9; ++k) v[k] = ld[(k / 3) * 18 + (k % 3)];
      const unsigned* wc = wfc + cp * 144;
#pragma unroll
      for (int k = 0; k < 9; ++k)
#pragma unroll
        for (int o = 0; o < 16; ++o)
          acc[o] = dot2acc(v[k], wc[k * 16 + o], acc[o]);
    }
    if (HAS_UP) {
#pragma unroll 2
      for (int cp = 0; cp < 8; ++cp) {
        const unsigned* ld = ldsU + cp * 324 + ty * 18 + tx;
        unsigned v[9];
#pragma unroll
        for (int k = 0; k < 9; ++k) v[k] = ld[(k / 3) * 18 + (k % 3)];
        const unsigned* wc = wfc + (8 + cp) * 144;
#pragma unroll
        for (int k = 0; k < 9; ++k)
#pragma unroll
          for (int o = 0; o < 16; ++o)
            acc[o] = dot2acc(v[k], wc[k * 16 + o], acc[o]);
      }
    }
    int h = by + ty, x = bx + tx;
    float* op = featsOut + (size_t)n * 16 * HH + (size_t)h * H + x;
    float* oh = outHwc ? outHwc + ((size_t)n * HH + (size_t)h * H + x) * 16 : nullptr;
#pragma unroll
    for (int o = 0; o < 16; ++o) {
      float rr = fmaxf(acc[o], 0.f);
      op[(size_t)o * HH] = rr;
      if (oh) oh[o] = rr;
    }
  }
}

// ---------------- fused final head: dob(18x18, no relu) -> dog(regs, 36ch) -> deform dg=2 ----------------
__global__ __launch_bounds__(256) void final_k(
    const float* __restrict__ rf0, const float* __restrict__ f0chw,
    const float* __restrict__ f0hwc, const float* __restrict__ offs0,
    const unsigned* __restrict__ wdob, const float* __restrict__ bdob,
    const unsigned* __restrict__ wdog, const float* __restrict__ bdog,
    const float* __restrict__ wddc, float* __restrict__ out) {
  __shared__ unsigned ldsA[16 * 400];  // phase1: cat(rf0,f0) 20x20 pairs; phase3 overlay: offs0 pairs
  __shared__ unsigned ldsB[8 * 324];   // dob out pairs (signed, no relu)
  const int H = 256;
  const size_t HH = 65536;
  const int n = blockIdx.z;
  const int bx = blockIdx.x * 16, by = blockIdx.y * 16;
  const int tid = threadIdx.x;
  const float* r0 = rf0 + (size_t)n * 16 * HH;
  const float* f0 = f0chw + (size_t)n * 16 * HH;

  for (int i = tid; i < 16 * 400; i += 256) {
    int cp = i / 400, r = i - cp * 400;
    int ly = r / 20, lx = r - ly * 20;
    int gy = by + ly - 2, gx = bx + lx - 2;
    float v0 = 0.f, v1 = 0.f;
    if (gy >= 0 && gy < H && gx >= 0 && gx < H) {
      const float* s = (cp < 8) ? r0 + (size_t)(2 * cp) * HH : f0 + (size_t)(2 * cp - 16) * HH;
      size_t off = (size_t)gy * H + gx;
      v0 = s[off];
      v1 = s[HH + off];
    }
    ldsA[i] = packh2(v0, v1);
  }
  __syncthreads();

  // dob: 18x18 x16, NO relu, zeroed at image-OOB
  unsigned short* dow16 = (unsigned short*)ldsB;
  for (int p = tid; p < 324; p += 256) {
    int y1 = p / 18, x1 = p - y1 * 18;
    int gy = by + y1 - 1, gx = bx + x1 - 1;
    bool valid = (gy >= 0 && gy < H && gx >= 0 && gx < H);
    float acc[16];
#pragma unroll
    for (int o = 0; o < 16; ++o) acc[o] = bdob[o];
#pragma unroll 2
    for (int cp = 0; cp < 16; ++cp) {
      const unsigned* ld = ldsA + cp * 400 + y1 * 20 + x1;
      unsigned v[9];
#pragma unroll
      for (int k = 0; k < 9; ++k) v[k] = ld[(k / 3) * 20 + (k % 3)];
      const unsigned* wc = wdob + cp * 144;
#pragma unroll
      for (int k = 0; k < 9; ++k)
#pragma unroll
        for (int o = 0; o < 16; ++o)
          acc[o] = dot2acc(v[k], wc[k * 16 + o], acc[o]);
    }
#pragma unroll
    for (int o = 0; o < 16; ++o)
      dow16[(o >> 1) * 648 + 2 * p + (o & 1)] = f2h(valid ? acc[o] : 0.f);
  }
  __syncthreads();

  // overlay ldsA with offs0 (18ch, direct read), zero at OOB
  {
    const float* os = offs0 + (size_t)n * 18 * HH;
    for (int i = tid; i < 9 * 324; i += 256) {
      int cp = i / 324, r = i - cp * 324;
      int y1 = r / 18, x1 = r - y1 * 18;
      int gy = by + y1 - 1, gx = bx + x1 - 1;
      float v0 = 0.f, v1 = 0.f;
      if (gy >= 0 && gy < H && gx >= 0 && gx < H) {
        const float* s = os + (size_t)(2 * cp) * HH + (size_t)gy * H + gx;
        v0 = s[0];
        v1 = s[HH];
      }
      ldsA[i] = packh2(v0, v1);
    }
    __syncthreads();
  }

  // dog (36ch, no relu) in registers, then final deform dg=2 at own pixel
  {
    int ty = tid >> 4, tx = tid & 15;
    float a36[36];
#pragma unroll
    for (int o = 0; o < 36; ++o) a36[o] = bdog[o];
    for (int cp = 0; cp < 8; ++cp) {
      const unsigned* ld = ldsB + cp * 324 + ty * 18 + tx;
      unsigned v[9];
#pragma unroll
      for (int k = 0; k < 9; ++k) v[k] = ld[(k / 3) * 18 + (k % 3)];
      const unsigned* wc = wdog + cp * 324;  // 9*36
#pragma unroll
      for (int k = 0; k < 9; ++k)
#pragma unroll
        for (int o = 0; o < 36; ++o)
          a36[o] = dot2acc(v[k], wc[k * 36 + o], a36[o]);
    }
    for (int cp = 0; cp < 9; ++cp) {
      const unsigned* ld = ldsA + cp * 324 + ty * 18 + tx;
      unsigned v[9];
#pragma unroll
      for (int k = 0; k < 9; ++k) v[k] = ld[(k / 3) * 18 + (k % 3)];
      const unsigned* wc = wdog + (8 + cp) * 324;
#pragma unroll
      for (int k = 0; k < 9; ++k)
#pragma unroll
        for (int o = 0; o < 36; ++o)
          a36[o] = dot2acc(v[k], wc[k * 36 + o], a36[o]);
    }

    const int h = by + ty, w = bx + tx;
    const float* inN = f0hwc + (size_t)n * HH * 16;
    float rr[2] = {0.f, 0.f};
#pragma unroll
    for (int g = 0; g < 2; ++g) {
#pragma unroll
      for (int k = 0; k < 9; ++k) {
        int ky = k / 3 - 1, kx = k % 3 - 1;
        float oy = a36[(g * 9 + k) * 2 + 0];
        float ox = a36[(g * 9 + k) * 2 + 1];
        float py = (float)(h + ky) + oy;
        float px = (float)(w + kx) + ox;
        float y0f = floorf(py), x0f = floorf(px);
        float fy = py - y0f, fx = px - x0f;
        int y0 = (int)y0f, x0 = (int)x0f;
        bool vy0 = ((unsigned)y0 < (unsigned)H);
        bool vy1 = ((unsigned)(y0 + 1) < (unsigned)H);
        bool vx0 = ((unsigned)x0 < (unsigned)H);
        bool vx1 = ((unsigned)(x0 + 1) < (unsigned)H);
        int y0c = min(max(y0, 0), H - 1), y1c = min(max(y0 + 1, 0), H - 1);
        int x0c = min(max(x0, 0), H - 1), x1c = min(max(x0 + 1, 0), H - 1);
        float w00 = (vy0 && vx0) ? (1.f - fy) * (1.f - fx) : 0.f;
        float w01 = (vy0 && vx1) ? (1.f - fy) * fx : 0.f;
        float w10 = (vy1 && vx0) ? fy * (1.f - fx) : 0.f;
        float w11 = (vy1 && vx1) ? fy * fx : 0.f;
        const float* p00 = inN + ((size_t)y0c * H + x0c) * 16 + g * 8;
        const float* p01 = inN + ((size_t)y0c * H + x1c) * 16 + g * 8;
        const float* p10 = inN + ((size_t)y1c * H + x0c) * 16 + g * 8;
        const float* p11 = inN + ((size_t)y1c * H + x1c) * 16 + g * 8;
        const float* wk = wddc + (size_t)(k * 16 + g * 8) * 2;
#pragma unroll
        for (int c4 = 0; c4 < 2; ++c4) {
          float4 a00 = *(const float4*)(p00 + c4 * 4);
          float4 a01 = *(const float4*)(p01 + c4 * 4);
          float4 a10 = *(const float4*)(p10 + c4 * 4);
          float4 a11 = *(const float4*)(p11 + c4 * 4);
          float v0 = w00 * a00.x + w01 * a01.x + w10 * a10.x + w11 * a11.x;
          float v1 = w00 * a00.y + w01 * a01.y + w10 * a10.y + w11 * a11.y;
          float v2 = w00 * a00.z + w01 * a01.z + w10 * a10.z + w11 * a11.z;
          float v3 = w00 * a00.w + w01 * a01.w + w10 * a10.w + w11 * a11.w;
#pragma unroll
          for (int o = 0; o < 2; ++o) {
            float t0 = fmaf(v0, wk[(c4 * 4 + 0) * 2 + o], rr[o]);
            t0 = fmaf(v1, wk[(c4 * 4 + 1) * 2 + o], t0);
            t0 = fmaf(v2, wk[(c4 * 4 + 2) * 2 + o], t0);
            rr[o] = fmaf(v3, wk[(c4 * 4 + 3) * 2 + o], t0);
          }
        }
      }
    }
    out[((size_t)n * 2 + 0) * HH + (size_t)h * H + w] = rr[0];
    out[((size_t)n * 2 + 1) * HH + (size_t)h * H + w] = rr[1];
  }
}

extern "C" void kernel_launch(void* const* d_in, const int* in_sizes, int n_in,
                              void* d_out, int out_size, void* d_ws, size_t ws_size,
                              hipStream_t stream) {
  auto F = [&](int i) { return (const float*)d_in[i]; };
  const float* ref = F(0);
  const float* unr = F(1);
  const float* few1[3] = {F(2), F(6), F(10)};
  const float* feb1[3] = {F(3), F(7), F(11)};
  const float* few2[3] = {F(4), F(8), F(12)};
  const float* feb2[3] = {F(5), F(9), F(13)};
  const float* obw[3] = {F(14), F(16), F(18)};
  const float* obb[3] = {F(15), F(17), F(19)};
  const float* ogw[3] = {F(20), F(22), F(24)};
  const float* ogb[3] = {F(21), F(23), F(25)};
  const float* dcw[3] = {F(26), F(27), F(28)};
  const float* fcw[3] = {F(29), F(31), F(33)};
  const float* fcb[3] = {F(30), F(32), F(34)};
  const float* dobw = F(35);
  const float* dobb = F(36);
  const float* dogw = F(37);
  const float* dogb = F(38);
  const float* ddcw = F(39);

  // ---- workspace (floats). rf/uf pairs contiguous (N=8 fe12 batching). ----
  float* ws = (float*)d_ws;
  size_t p = 0;
  auto alloc = [&](size_t nf) { float* r = ws + p; p += nf; return r; };
  float* rf0 = alloc((size_t)4 * 16 * 65536);
  float* uf0 = alloc((size_t)4 * 16 * 65536);
  float* rf1 = alloc((size_t)4 * 16 * 16384);
  float* uf1 = alloc((size_t)4 * 16 * 16384);
  float* rf2 = alloc((size_t)4 * 16 * 4096);
  float* uf2 = alloc((size_t)4 * 16 * 4096);
  float* offs0 = alloc((size_t)4 * 18 * 65536);
  float* offs1 = alloc((size_t)4 * 18 * 16384);
  float* offs2 = alloc((size_t)4 * 18 * 4096);
  float* feats0 = alloc((size_t)4 * 16 * 65536);
  float* feats1 = alloc((size_t)4 * 16 * 16384);
  float* feats2 = alloc((size_t)4 * 16 * 4096);
  float* ufH0 = alloc((size_t)4 * 16 * 65536);  // dedicated (no feats alias: defc fuses read+write)
  float* ufH1 = alloc((size_t)4 * 16 * 16384);
  float* ufH2 = alloc((size_t)4 * 16 * 4096);
  float* fHwc = alloc((size_t)4 * 16 * 65536);
  float* wt = alloc(7200);
  float* cwf = alloc(40000);
  if (p * sizeof(float) > ws_size) return;
  const float* wt_dc[3] = {wt, wt + 2304, wt + 4608};
  const float* wt_ddc = wt + 6912;
  unsigned* cwp = (unsigned*)cwf;

  // ---- paired conv weight table (16 entries) ----
  WTable T;
  int nw = 0, woff = 0, maxtot = 0;
  auto addw = [&](const float* src, int cin, int cout) {
    T.e[nw].src = src; T.e[nw].cin = cin; T.e[nw].cout = cout; T.e[nw].dstoff = woff;
    int tot = (cin >> 1) * cout * 9;
    if (tot > maxtot) maxtot = tot;
    int start = woff;
    woff += tot;
    ++nw;
    return start;
  };
  int o_few2_0 = addw(few2[0], 16, 16);
  int o_few1_1 = addw(few1[1], 16, 16);
  int o_few2_1 = addw(few2[1], 16, 16);
  int o_few1_2 = addw(few1[2], 16, 16);
  int o_few2_2 = addw(few2[2], 16, 16);
  int o_ob[3], o_og[3], o_fc[3];
  for (int i = 0; i < 3; ++i) o_ob[i] = addw(obw[i], 32, 16);
  o_og[0] = addw(ogw[0], 34, 18);
  o_og[1] = addw(ogw[1], 34, 18);
  o_og[2] = addw(ogw[2], 16, 18);
  o_fc[0] = addw(fcw[0], 32, 16);
  o_fc[1] = addw(fcw[1], 32, 16);
  o_fc[2] = addw(fcw[2], 16, 16);
  int o_dob = addw(dobw, 32, 16);
  int o_dog = addw(dogw, 34, 36);

  wreorder_k<<<29, 256, 0, stream>>>(dcw[0], dcw[1], dcw[2], ddcw, wt);
  wpair_conv_k<<<dim3((maxtot + 255) / 256, nw), 256, 0, stream>>>(T, cwp);

  // ---- feature pyramids ----
  fe0_fused_k<<<dim3(32, 32, 8), 256, 0, stream>>>(
      ref, unr, few1[0], feb1[0], cwp + o_few2_0, feb2[0], rf0, uf0, ufH0);
  fe12_fused_k<<<dim3(16, 16, 8), 256, 0, stream>>>(
      rf0, cwp + o_few1_1, feb1[1], cwp + o_few2_1, feb2[1], rf1, ufH1, 256);
  fe12_fused_k<<<dim3(8, 8, 8), 256, 0, stream>>>(
      rf1, cwp + o_few1_2, feb1[2], cwp + o_few2_2, feb2[2], rf2, ufH2, 128);

  // ---- coarse-to-fine: fused [ob->og] then [deform->fc] per level ----
  obog_k<0><<<dim3(4, 4, 4), 256, 0, stream>>>(
      rf2, uf2, nullptr, cwp + o_ob[2], obb[2], cwp + o_og[2], ogb[2], offs2, 64);
  defc_k<0><<<dim3(4, 4, 4), 256, 0, stream>>>(
      ufH2, offs2, wt_dc[2], nullptr, cwp + o_fc[2], fcb[2], feats2, nullptr, 64);
  obog_k<1><<<dim3(8, 8, 4), 256, 0, stream>>>(
      rf1, uf1, offs2, cwp + o_ob[1], obb[1], cwp + o_og[1], ogb[1], offs1, 128);
  defc_k<1><<<dim3(8, 8, 4), 256, 0, stream>>>(
      ufH1, offs1, wt_dc[1], feats2, cwp + o_fc[1], fcb[1], feats1, nullptr, 128);
  obog_k<1><<<dim3(16, 16, 4), 256, 0, stream>>>(
      rf0, uf0, offs1, cwp + o_ob[0], obb[0], cwp + o_og[0], ogb[0], offs0, 256);
  defc_k<1><<<dim3(16, 16, 4), 256, 0, stream>>>(
      ufH0, offs0, wt_dc[0], feats1, cwp + o_fc[0], fcb[0], feats0, fHwc, 256);

  // ---- fused final head: dob -> dog(regs) -> deform dg=2 -> d_out ----
  final_k<<<dim3(16, 16, 4), 256, 0, stream>>>(
      rf0, feats0, fHwc, offs0, cwp + o_dob, dobb, cwp + o_dog, dogb, wt_ddc,
      (float*)d_out);
}

// Round 15
// 928.380 us; speedup vs baseline: 1.7219x; 1.0752x over previous
//
#include <hip/hip_runtime.h>
#include <math.h>

typedef _Float16 half2_t __attribute__((ext_vector_type(2)));
typedef _Float16 half8 __attribute__((ext_vector_type(8)));
typedef float floatx4 __attribute__((ext_vector_type(4)));

__device__ __forceinline__ unsigned packh2(float a, float b) {
  half2_t h;
  h.x = (_Float16)a;
  h.y = (_Float16)b;
  return __builtin_bit_cast(unsigned, h);
}
__device__ __forceinline__ unsigned short f2h(float a) {
  return __builtin_bit_cast(unsigned short, (_Float16)a);
}
__device__ __forceinline__ float h2f(unsigned short u) {
  return (float)__builtin_bit_cast(_Float16, u);
}
__device__ __forceinline__ float dot2acc(unsigned a, unsigned b, float c) {
  half2_t ha = __builtin_bit_cast(half2_t, a);
  half2_t hb = __builtin_bit_cast(half2_t, b);
#if __has_builtin(__builtin_amdgcn_fdot2)
  return __builtin_amdgcn_fdot2(ha, hb, c, false);
#else
  c = fmaf((float)ha.x, (float)hb.x, c);
  return fmaf((float)ha.y, (float)hb.y, c);
#endif
}

// ---------------- deform weight reorder: (O,16,9) -> (9,16,O) f32 ----------------
__global__ __launch_bounds__(256) void wreorder_k(
    const float* __restrict__ a, const float* __restrict__ b,
    const float* __restrict__ c, const float* __restrict__ d,
    float* __restrict__ out) {
  int t = blockIdx.x * 256 + threadIdx.x;
  if (t < 6912) {
    int which = t / 2304, r = t % 2304;
    int o = r % 16, kc = r / 16;
    int ci = kc % 16, k = kc / 16;
    const float* w = which == 0 ? a : (which == 1 ? b : c);
    out[t] = w[(o * 16 + ci) * 9 + k];
  } else if (t < 7200) {
    int r = t - 6912;
    int o = r % 2, kc = r / 2;
    int ci = kc % 16, k = kc / 16;
    out[t] = d[(o * 16 + ci) * 9 + k];
  }
}

// ---------------- conv weight pairing for dot2 kernels: (O,C,9) -> (C/2,9,O) f16-pairs ----------------
struct WEntry { const float* src; int cin; int cout; int dstoff; };
struct WTable { WEntry e[16]; };  // 11 used
__global__ __launch_bounds__(256) void wpair_conv_k(WTable t, unsigned* __restrict__ out) {
  WEntry en = t.e[blockIdx.y];
  int total = (en.cin >> 1) * 9 * en.cout;
  int i = blockIdx.x * 256 + threadIdx.x;
  if (i >= total) return;
  int o = i % en.cout;
  int k = (i / en.cout) % 9;
  int cp = i / (en.cout * 9);
  float s0 = en.src[((size_t)o * en.cin + 2 * cp) * 9 + k];
  float s1 = en.src[((size_t)o * en.cin + 2 * cp + 1) * 9 + k];
  out[en.dstoff + i] = packh2(s0, s1);
}

// ---------------- MFMA weight prepack: five (16,16,3,3) convs -> per-lane B-frags ----------------
// k = tap*16 + cin (K padded 144->160, 5 chunks of 32). B-frag: lane holds B[k=quad*8+j][n=lane&15].
// out[conv*2560 + (c*64+lane)*8 + j]
__global__ __launch_bounds__(256) void wmfma_k(
    const float* __restrict__ w0, const float* __restrict__ w1,
    const float* __restrict__ w2, const float* __restrict__ w3,
    const float* __restrict__ w4, unsigned short* __restrict__ out) {
  int t = blockIdx.x * 256 + threadIdx.x;
  if (t >= 12800) return;
  int conv = t / 2560, r = t % 2560;
  int c = r / 512, L = (r / 8) % 64, j = r & 7;
  int quad = L >> 4, o = L & 15;
  int k = 32 * c + quad * 8 + j;
  int tap = k >> 4, cin = k & 15;
  const float* w = conv == 0 ? w0 : conv == 1 ? w1 : conv == 2 ? w2 : conv == 3 ? w3 : w4;
  float v = (tap < 9) ? w[((size_t)o * 16 + cin) * 9 + tap] : 0.f;
  out[t] = f2h(v);
}

// ---------------- MFMA 16->16 3x3 conv over an LDS HWC tile ----------------
// src: (SW x SW? rows) HWC u16, pitch SW per row; out: OWxOW HWC u16. POS=OW*OW.
// A-layout (m120-verified): lane holds A[m=lane&15][k=quad*8+j]; C/D: col=lane&15(outch), row=quad*4+reg(pos).
__device__ __forceinline__ void conv_mfma(
    const unsigned short* __restrict__ src, int SW,
    unsigned short* __restrict__ dst, const half8* __restrict__ bf,
    const float* __restrict__ bias, int POS, int OW, int tid, int relu,
    int domask, int gby, int gbx, int bound) {
  const int lane = tid & 63, wid = tid >> 6;
  const int quad = lane >> 4, m = lane & 15;
  const int tap01 = quad >> 1, cin8 = (quad & 1) * 8;
  const int ntiles = (POS + 15) >> 4;
  float bs = bias[m];
  half8 zero;
#pragma unroll
  for (int j = 0; j < 8; ++j) zero[j] = (_Float16)0;
  for (int T = wid; T < ntiles; T += 4) {
    int pa = T * 16 + m;
    pa = pa < POS ? pa : POS - 1;
    int ya = pa / OW, xa = pa - ya * OW;
    floatx4 acc = {0.f, 0.f, 0.f, 0.f};
#pragma unroll
    for (int c = 0; c < 5; ++c) {
      int tap = 2 * c + tap01;
      half8 a = zero;
      if (tap < 9) {
        int dy = tap / 3, dx = tap - (tap / 3) * 3;
        a = *(const half8*)(src + ((ya + dy) * SW + xa + dx) * 16 + cin8);
      }
      acc = __builtin_amdgcn_mfma_f32_16x16x32_f16(a, bf[c], acc, 0, 0, 0);
    }
#pragma unroll
    for (int r = 0; r < 4; ++r) {
      int pd = T * 16 + quad * 4 + r;
      if (pd < POS) {
        float v = acc[r] + bs;
        if (relu) v = fmaxf(v, 0.f);
        if (domask) {
          int yd = pd / OW, xd = pd - (pd / OW) * OW;
          int gy = gby + yd, gx = gbx + xd;
          if (gy < 0 || gy >= bound || gx < 0 || gx >= bound) v = 0.f;
        }
        dst[pd * 16 + m] = f2h(v);
      }
    }
  }
}

// ---------------- fused FE level-0: conv1(f32 scalar) -> conv2(MFMA) -> pool ----------------
__global__ __launch_bounds__(256) void fe0_fused_k(
    const float* __restrict__ refI, const float* __restrict__ unrI,
    const float* __restrict__ w1, const float* __restrict__ b1,
    const unsigned short* __restrict__ wm2, const float* __restrict__ b2,
    float* __restrict__ outR, float* __restrict__ outU, float* __restrict__ outUH) {
  __shared__ __attribute__((aligned(16))) unsigned short c1h[361 * 16];  // HWC 19x19
  __shared__ __attribute__((aligned(16))) unsigned short sb[289 * 16];   // inbuf f32 441 / c2 HWC 17x17
  const int z = blockIdx.z;
  const int im = z >> 2, n = z & 3;
  const float* img = (im ? unrI : refI) + (size_t)n * 512 * 512;
  float* outp = (im ? outU : outR) + (size_t)n * 16 * 256 * 256;
  const int py0 = blockIdx.y * 8, px0 = blockIdx.x * 8;
  const int tid = threadIdx.x;

  half8 bf[5];
  {
    const int lane = tid & 63;
#pragma unroll
    for (int c = 0; c < 5; ++c) bf[c] = *(const half8*)(wm2 + (c * 64 + lane) * 8);
  }

  float* inbuf = (float*)sb;
  for (int i = tid; i < 441; i += 256) {
    int yi = i / 21, xi = i - yi * 21;
    int gy = 2 * py0 - 3 + yi, gx = 2 * px0 - 3 + xi;
    float v = 0.f;
    if (gy >= 0 && gy < 512 && gx >= 0 && gx < 512) v = img[gy * 512 + gx];
    inbuf[i] = v;
  }
  __syncthreads();

  // conv1 (1->16, fp32) -> c1h HWC, zeroed at image-invalid
  unsigned* c1w32 = (unsigned*)c1h;
  for (int p = tid; p < 361; p += 256) {
    int y1 = p / 19, x1 = p - y1 * 19;
    int gy = 2 * py0 - 2 + y1, gx = 2 * px0 - 2 + x1;
    bool valid = (gy >= 0 && gy < 512 && gx >= 0 && gx < 512);
    float t[9];
#pragma unroll
    for (int k = 0; k < 9; ++k) t[k] = inbuf[(y1 + k / 3) * 21 + x1 + (k % 3)];
    float va[16];
#pragma unroll
    for (int c = 0; c < 16; ++c) {
      float a = b1[c];
#pragma unroll
      for (int k = 0; k < 9; ++k) a = fmaf(t[k], w1[c * 9 + k], a);
      va[c] = valid ? fmaxf(a, 0.f) : 0.f;
    }
#pragma unroll
    for (int cc = 0; cc < 8; ++cc) c1w32[p * 8 + cc] = packh2(va[2 * cc], va[2 * cc + 1]);
  }
  __syncthreads();

  // conv2 (16->16) via MFMA -> sb as c2 HWC
  conv_mfma(c1h, 19, sb, bf, b2, 289, 17, tid, 1, 0, 0, 0, 0);
  __syncthreads();

  // pool 3x3 s2 (u16 bit-max on non-negative values)
  for (int i = tid; i < 1024; i += 256) {
    int c = i >> 6, r = i & 63, py = r >> 3, px = r & 7;
    unsigned short m = 0;
#pragma unroll
    for (int dy = 0; dy < 3; ++dy) {
      int gy = 2 * (py0 + py) - 1 + dy;
      if (gy < 0 || gy >= 512) continue;
#pragma unroll
      for (int dx = 0; dx < 3; ++dx) {
        int gx = 2 * (px0 + px) - 1 + dx;
        if (gx < 0 || gx >= 512) continue;
        unsigned short v = sb[((2 * py + dy) * 17 + 2 * px + dx) * 16 + c];
        m = (v > m) ? v : m;
      }
    }
    float mf = h2f(m);
    outp[((size_t)c * 256 + py0 + py) * 256 + px0 + px] = mf;
    if (im)
      outUH[(((size_t)n * 256 + py0 + py) * 256 + px0 + px) * 16 + c] = mf;
  }
}

// ---------------- fused FE level-1/2: conv1(MFMA) -> conv2(MFMA) -> pool ----------------
__global__ __launch_bounds__(256) void fe12_fused_k(
    const float* __restrict__ in,
    const unsigned short* __restrict__ wm1, const float* __restrict__ b1,
    const unsigned short* __restrict__ wm2, const float* __restrict__ b2,
    float* __restrict__ outC, float* __restrict__ outHWC, int Hin) {
  __shared__ __attribute__((aligned(16))) unsigned short inh[441 * 16];  // 21x21 HWC / c2 overlay
  __shared__ __attribute__((aligned(16))) unsigned short c1h[361 * 16];  // 19x19 HWC
  const int n = blockIdx.z;
  const int Ho = Hin >> 1;
  const int py0 = blockIdx.y * 8, px0 = blockIdx.x * 8;
  const int tid = threadIdx.x;
  const float* inN = in + (size_t)n * 16 * Hin * Hin;
  const size_t HH = (size_t)Hin * Hin;

  half8 bf1[5], bf2[5];
  {
    const int lane = tid & 63;
#pragma unroll
    for (int c = 0; c < 5; ++c) {
      bf1[c] = *(const half8*)(wm1 + (c * 64 + lane) * 8);
      bf2[c] = *(const half8*)(wm2 + (c * 64 + lane) * 8);
    }
  }

  // stage input 21x21 HWC (coalesced reads per channel pair, scattered LDS writes)
  unsigned* inh32 = (unsigned*)inh;
  for (int i = tid; i < 8 * 441; i += 256) {
    int cp = i / 441, r = i - cp * 441;
    int yi = r / 21, xi = r - yi * 21;
    int gy = 2 * py0 - 3 + yi, gx = 2 * px0 - 3 + xi;
    float v0 = 0.f, v1 = 0.f;
    if (gy >= 0 && gy < Hin && gx >= 0 && gx < Hin) {
      const float* s = inN + (size_t)(2 * cp) * HH + (size_t)gy * Hin + gx;
      v0 = s[0];
      v1 = s[HH];
    }
    inh32[r * 8 + cp] = packh2(v0, v1);
  }
  __syncthreads();

  // conv1 (MFMA), zeroed at image-invalid (= zero-pad for conv2)
  conv_mfma(inh, 21, c1h, bf1, b1, 361, 19, tid, 1, 1, 2 * py0 - 2, 2 * px0 - 2, Hin);
  __syncthreads();

  // conv2 (MFMA) -> overlay inh as c2 HWC
  conv_mfma(c1h, 19, inh, bf2, b2, 289, 17, tid, 1, 0, 0, 0, 0);
  __syncthreads();

  float* outp = outC + (size_t)n * 16 * Ho * Ho;
  for (int i = tid; i < 1024; i += 256) {
    int c = i >> 6, r = i & 63, py = r >> 3, px = r & 7;
    unsigned short m = 0;
#pragma unroll
    for (int dy = 0; dy < 3; ++dy) {
      int gy = 2 * (py0 + py) - 1 + dy;
      if (gy < 0 || gy >= Hin) continue;
#pragma unroll
      for (int dx = 0; dx < 3; ++dx) {
        int gx = 2 * (px0 + px) - 1 + dx;
        if (gx < 0 || gx >= Hin) continue;
        unsigned short v = inh[((2 * py + dy) * 17 + 2 * px + dx) * 16 + c];
        m = (v > m) ? v : m;
      }
    }
    float mf = h2f(m);
    outp[((size_t)c * Ho + py0 + py) * Ho + px0 + px] = mf;
    if (n >= 4)
      outHWC[(((size_t)(n - 4) * Ho + py0 + py) * Ho + px0 + px) * 16 + c] = mf;
  }
}

// ---------------- fused offset head (R14-proven): ob -> og -> offs ----------------
template <int HAS_UP>
__global__ __launch_bounds__(256) void obog_k(
    const float* __restrict__ rf, const float* __restrict__ uf,
    const float* __restrict__ offsUp,
    const unsigned* __restrict__ wob, const float* __restrict__ bob,
    const unsigned* __restrict__ wog, const float* __restrict__ bog,
    float* __restrict__ offsOut, int H) {
  __shared__ unsigned ldsA[16 * 400];
  __shared__ unsigned ldsB[8 * 324];
  const int n = blockIdx.z;
  const int bx = blockIdx.x * 16, by = blockIdx.y * 16;
  const int tid = threadIdx.x;
  const size_t HH = (size_t)H * H;
  const float* r0 = rf + (size_t)n * 16 * HH;
  const float* u0 = uf + (size_t)n * 16 * HH;

  for (int i = tid; i < 16 * 400; i += 256) {
    int cp = i / 400, r = i - cp * 400;
    int ly = r / 20, lx = r - ly * 20;
    int gy = by + ly - 2, gx = bx + lx - 2;
    float v0 = 0.f, v1 = 0.f;
    if (gy >= 0 && gy < H && gx >= 0 && gx < H) {
      const float* s = (cp < 8) ? r0 + (size_t)(2 * cp) * HH : u0 + (size_t)(2 * cp - 16) * HH;
      size_t off = (size_t)gy * H + gx;
      v0 = s[off];
      v1 = s[HH + off];
    }
    ldsA[i] = packh2(v0, v1);
  }
  __syncthreads();

  unsigned short* obw16 = (unsigned short*)ldsB;
  for (int p = tid; p < 324; p += 256) {
    int y1 = p / 18, x1 = p - y1 * 18;
    int gy = by + y1 - 1, gx = bx + x1 - 1;
    bool valid = (gy >= 0 && gy < H && gx >= 0 && gx < H);
    float acc[16];
#pragma unroll
    for (int o = 0; o < 16; ++o) acc[o] = bob[o];
#pragma unroll 2
    for (int cp = 0; cp < 16; ++cp) {
      const unsigned* ld = ldsA + cp * 400 + y1 * 20 + x1;
      unsigned v[9];
#pragma unroll
      for (int k = 0; k < 9; ++k) v[k] = ld[(k / 3) * 20 + (k % 3)];
      const unsigned* wc = wob + cp * 144;
#pragma unroll
      for (int k = 0; k < 9; ++k)
#pragma unroll
        for (int o = 0; o < 16; ++o)
          acc[o] = dot2acc(v[k], wc[k * 16 + o], acc[o]);
    }
#pragma unroll
    for (int o = 0; o < 16; ++o)
      obw16[(o >> 1) * 648 + 2 * p + (o & 1)] = f2h(valid ? fmaxf(acc[o], 0.f) : 0.f);
  }
  __syncthreads();

  if (HAS_UP) {
    const int H2 = H >> 1;
    const float* os = offsUp + (size_t)n * 18 * H2 * H2;
    for (int i = tid; i < 9 * 324; i += 256) {
      int cp = i / 324, r = i - cp * 324;
      int y1 = r / 18, x1 = r - y1 * 18;
      int gy = by + y1 - 1, gx = bx + x1 - 1;
      float v0 = 0.f, v1 = 0.f;
      if (gy >= 0 && gy < H && gx >= 0 && gx < H) {
        float sy = 0.5f * gy - 0.25f, sx = 0.5f * gx - 0.25f;
        float y0f = floorf(sy), x0f = floorf(sx);
        float wy = sy - y0f, wx = sx - x0f;
        int y0 = (int)y0f, x0 = (int)x0f;
        int y0c = min(max(y0, 0), H2 - 1), y1c = min(max(y0 + 1, 0), H2 - 1);
        int x0c = min(max(x0, 0), H2 - 1), x1c = min(max(x0 + 1, 0), H2 - 1);
        const float* sp = os + (size_t)(2 * cp) * H2 * H2;
        v0 = (1.f - wy) * ((1.f - wx) * sp[y0c * H2 + x0c] + wx * sp[y0c * H2 + x1c]) +
             wy * ((1.f - wx) * sp[y1c * H2 + x0c] + wx * sp[y1c * H2 + x1c]);
        sp += (size_t)H2 * H2;
        v1 = (1.f - wy) * ((1.f - wx) * sp[y0c * H2 + x0c] + wx * sp[y0c * H2 + x1c]) +
             wy * ((1.f - wx) * sp[y1c * H2 + x0c] + wx * sp[y1c * H2 + x1c]);
      }
      ldsA[i] = packh2(v0, v1);
    }
    __syncthreads();
  }

  {
    int ty = tid >> 4, tx = tid & 15;
    float acc[18];
#pragma unroll
    for (int o = 0; o < 18; ++o) acc[o] = bog[o];
#pragma unroll 2
    for (int cp = 0; cp < 8; ++cp) {
      const unsigned* ld = ldsB + cp * 324 + ty * 18 + tx;
      unsigned v[9];
#pragma unroll
      for (int k = 0; k < 9; ++k) v[k] = ld[(k / 3) * 18 + (k % 3)];
      const unsigned* wc = wog + cp * 162;
#pragma unroll
      for (int k = 0; k < 9; ++k)
#pragma unroll
        for (int o = 0; o < 18; ++o)
          acc[o] = dot2acc(v[k], wc[k * 18 + o], acc[o]);
    }
    if (HAS_UP) {
#pragma unroll 2
      for (int cp = 0; cp < 9; ++cp) {
        const unsigned* ld = ldsA + cp * 324 + ty * 18 + tx;
        unsigned v[9];
#pragma unroll
        for (int k = 0; k < 9; ++k) v[k] = ld[(k / 3) * 18 + (k % 3)];
        const unsigned* wc = wog + (8 + cp) * 162;
#pragma unroll
        for (int k = 0; k < 9; ++k)
#pragma unroll
          for (int o = 0; o < 18; ++o)
            acc[o] = dot2acc(v[k], wc[k * 18 + o], acc[o]);
      }
    }
    float* op = offsOut + (size_t)n * 18 * HH + (size_t)(by + ty) * H + (bx + tx);
#pragma unroll
    for (int o = 0; o < 18; ++o) op[(size_t)o * HH] = fmaxf(acc[o], 0.f);
  }
}

// ---------------- fused feature head (R14-proven): deform -> fc -> feats ----------------
template <int HAS_UP>
__global__ __launch_bounds__(256) void defc_k(
    const float* __restrict__ ufHWC, const float* __restrict__ offs,
    const float* __restrict__ wdef, const float* __restrict__ featsUp,
    const unsigned* __restrict__ wfc, const float* __restrict__ bfc,
    float* __restrict__ featsOut, float* __restrict__ outHwc, int H) {
  __shared__ unsigned ldsF[8 * 324];
  __shared__ unsigned ldsU[8 * 324];
  const int n = blockIdx.z;
  const int bx = blockIdx.x * 16, by = blockIdx.y * 16;
  const int tid = threadIdx.x;
  const size_t HH = (size_t)H * H;
  const float* inN = ufHWC + (size_t)n * HH * 16;
  const float* offN = offs + (size_t)n * 18 * HH;

  unsigned short* fw16 = (unsigned short*)ldsF;
  for (int p = tid; p < 324; p += 256) {
    int y1 = p / 18, x1 = p - y1 * 18;
    int h = by + y1 - 1, w = bx + x1 - 1;
    bool valid = (h >= 0 && h < H && w >= 0 && w < H);
    float acc[16];
#pragma unroll
    for (int o = 0; o < 16; ++o) acc[o] = 0.f;
    if (valid) {
      size_t hw = (size_t)h * H + w;
#pragma unroll
      for (int k = 0; k < 9; ++k) {
        int ky = k / 3 - 1, kx = k % 3 - 1;
        float oy = offN[(size_t)(2 * k) * HH + hw];
        float ox = offN[(size_t)(2 * k + 1) * HH + hw];
        float py = (float)(h + ky) + oy;
        float px = (float)(w + kx) + ox;
        float y0f = floorf(py), x0f = floorf(px);
        float fy = py - y0f, fx = px - x0f;
        int y0 = (int)y0f, x0 = (int)x0f;
        bool vy0 = ((unsigned)y0 < (unsigned)H);
        bool vy1 = ((unsigned)(y0 + 1) < (unsigned)H);
        bool vx0 = ((unsigned)x0 < (unsigned)H);
        bool vx1 = ((unsigned)(x0 + 1) < (unsigned)H);
        int y0c = min(max(y0, 0), H - 1), y1c = min(max(y0 + 1, 0), H - 1);
        int x0c = min(max(x0, 0), H - 1), x1c = min(max(x0 + 1, 0), H - 1);
        float w00 = (vy0 && vx0) ? (1.f - fy) * (1.f - fx) : 0.f;
        float w01 = (vy0 && vx1) ? (1.f - fy) * fx : 0.f;
        float w10 = (vy1 && vx0) ? fy * (1.f - fx) : 0.f;
        float w11 = (vy1 && vx1) ? fy * fx : 0.f;
        const float* p00 = inN + ((size_t)y0c * H + x0c) * 16;
        const float* p01 = inN + ((size_t)y0c * H + x1c) * 16;
        const float* p10 = inN + ((size_t)y1c * H + x0c) * 16;
        const float* p11 = inN + ((size_t)y1c * H + x1c) * 16;
        const float* wk = wdef + (size_t)k * 256;
#pragma unroll
        for (int c4 = 0; c4 < 4; ++c4) {
          float4 a00 = *(const float4*)(p00 + c4 * 4);
          float4 a01 = *(const float4*)(p01 + c4 * 4);
          float4 a10 = *(const float4*)(p10 + c4 * 4);
          float4 a11 = *(const float4*)(p11 + c4 * 4);
          float v0 = w00 * a00.x + w01 * a01.x + w10 * a10.x + w11 * a11.x;
          float v1 = w00 * a00.y + w01 * a01.y + w10 * a10.y + w11 * a11.y;
          float v2 = w00 * a00.z + w01 * a01.z + w10 * a10.z + w11 * a11.z;
          float v3 = w00 * a00.w + w01 * a01.w + w10 * a10.w + w11 * a11.w;
#pragma unroll
          for (int o = 0; o < 16; ++o) {
            float t0 = fmaf(v0, wk[(c4 * 4 + 0) * 16 + o], acc[o]);
            t0 = fmaf(v1, wk[(c4 * 4 + 1) * 16 + o], t0);
            t0 = fmaf(v2, wk[(c4 * 4 + 2) * 16 + o], t0);
            acc[o] = fmaf(v3, wk[(c4 * 4 + 3) * 16 + o], t0);
          }
        }
      }
    }
#pragma unroll
    for (int o = 0; o < 16; ++o)
      fw16[(o >> 1) * 648 + 2 * p + (o & 1)] = f2h(valid ? fmaxf(acc[o], 0.f) : 0.f);
  }

  if (HAS_UP) {
    const int H2 = H >> 1;
    const float* fu = featsUp + (size_t)n * 16 * H2 * H2;
    for (int i = tid; i < 8 * 324; i += 256) {
      int cp = i / 324, r = i - cp * 324;
      int y1 = r / 18, x1 = r - y1 * 18;
      int gy = by + y1 - 1, gx = bx + x1 - 1;
      float v0 = 0.f, v1 = 0.f;
      if (gy >= 0 && gy < H && gx >= 0 && gx < H) {
        float sy = 0.5f * gy - 0.25f, sx = 0.5f * gx - 0.25f;
        float y0f = floorf(sy), x0f = floorf(sx);
        float wy = sy - y0f, wx = sx - x0f;
        int y0 = (int)y0f, x0 = (int)x0f;
        int y0c = min(max(y0, 0), H2 - 1), y1c = min(max(y0 + 1, 0), H2 - 1);
        int x0c = min(max(x0, 0), H2 - 1), x1c = min(max(x0 + 1, 0), H2 - 1);
        const float* sp = fu + (size_t)(2 * cp) * H2 * H2;
        v0 = (1.f - wy) * ((1.f - wx) * sp[y0c * H2 + x0c] + wx * sp[y0c * H2 + x1c]) +
             wy * ((1.f - wx) * sp[y1c * H2 + x0c] + wx * sp[y1c * H2 + x1c]);
        sp += (size_t)H2 * H2;
        v1 = (1.f - wy) * ((1.f - wx) * sp[y0c * H2 + x0c] + wx * sp[y0c * H2 + x1c]) +
             wy * ((1.f - wx) * sp[y1c * H2 + x0c] + wx * sp[y1c * H2 + x1c]);
      }
      ldsU[i] = packh2(v0, v1);
    }
  }
  __syncthreads();

  {
    int ty = tid >> 4, tx = tid & 15;
    float acc[16];
#pragma unroll
    for (int o = 0; o < 16; ++o) acc[o] = bfc[o];
#pragma unroll 2
    for (int cp = 0; cp < 8; ++cp) {
      const unsigned* ld = ldsF + cp * 324 + ty * 18 + tx;
      unsigned v[9];
#pragma unroll
      for (int k = 0; k < 9; ++k) v[k] = ld[(k / 3) * 18 + (k % 3)];
      const unsigned* wc = wfc + cp * 144;
#pragma unroll
      for (int k = 0; k < 9; ++k)
#pragma unroll
        for (int o = 0; o < 16; ++o)
          acc[o] = dot2acc(v[k], wc[k * 16 + o], acc[o]);
    }
    if (HAS_UP) {
#pragma unroll 2
      for (int cp = 0; cp < 8; ++cp) {
        const unsigned* ld = ldsU + cp * 324 + ty * 18 + tx;
        unsigned v[9];
#pragma unroll
        for (int k = 0; k < 9; ++k) v[k] = ld[(k / 3) * 18 + (k % 3)];
        const unsigned* wc = wfc + (8 + cp) * 144;
#pragma unroll
        for (int k = 0; k < 9; ++k)
#pragma unroll
          for (int o = 0; o < 16; ++o)
            acc[o] = dot2acc(v[k], wc[k * 16 + o], acc[o]);
      }
    }
    int h = by + ty, x = bx + tx;
    float* op = featsOut + (size_t)n * 16 * HH + (size_t)h * H + x;
    float* oh = outHwc ? outHwc + ((size_t)n * HH + (size_t)h * H + x) * 16 : nullptr;
#pragma unroll
    for (int o = 0; o < 16; ++o) {
      float rr = fmaxf(acc[o], 0.f);
      op[(size_t)o * HH] = rr;
      if (oh) oh[o] = rr;
    }
  }
}

// ---------------- fused final head (R14-proven): dob -> dog(regs) -> deform dg=2 ----------------
__global__ __launch_bounds__(256) void final_k(
    const float* __restrict__ rf0, const float* __restrict__ f0chw,
    const float* __restrict__ f0hwc, const float* __restrict__ offs0,
    const unsigned* __restrict__ wdob, const float* __restrict__ bdob,
    const unsigned* __restrict__ wdog, const float* __restrict__ bdog,
    const float* __restrict__ wddc, float* __restrict__ out) {
  __shared__ unsigned ldsA[16 * 400];
  __shared__ unsigned ldsB[8 * 324];
  const int H = 256;
  const size_t HH = 65536;
  const int n = blockIdx.z;
  const int bx = blockIdx.x * 16, by = blockIdx.y * 16;
  const int tid = threadIdx.x;
  const float* r0 = rf0 + (size_t)n * 16 * HH;
  const float* f0 = f0chw + (size_t)n * 16 * HH;

  for (int i = tid; i < 16 * 400; i += 256) {
    int cp = i / 400, r = i - cp * 400;
    int ly = r / 20, lx = r - ly * 20;
    int gy = by + ly - 2, gx = bx + lx - 2;
    float v0 = 0.f, v1 = 0.f;
    if (gy >= 0 && gy < H && gx >= 0 && gx < H) {
      const float* s = (cp < 8) ? r0 + (size_t)(2 * cp) * HH : f0 + (size_t)(2 * cp - 16) * HH;
      size_t off = (size_t)gy * H + gx;
      v0 = s[off];
      v1 = s[HH + off];
    }
    ldsA[i] = packh2(v0, v1);
  }
  __syncthreads();

  unsigned short* dow16 = (unsigned short*)ldsB;
  for (int p = tid; p < 324; p += 256) {
    int y1 = p / 18, x1 = p - y1 * 18;
    int gy = by + y1 - 1, gx = bx + x1 - 1;
    bool valid = (gy >= 0 && gy < H && gx >= 0 && gx < H);
    float acc[16];
#pragma unroll
    for (int o = 0; o < 16; ++o) acc[o] = bdob[o];
#pragma unroll 2
    for (int cp = 0; cp < 16; ++cp) {
      const unsigned* ld = ldsA + cp * 400 + y1 * 20 + x1;
      unsigned v[9];
#pragma unroll
      for (int k = 0; k < 9; ++k) v[k] = ld[(k / 3) * 20 + (k % 3)];
      const unsigned* wc = wdob + cp * 144;
#pragma unroll
      for (int k = 0; k < 9; ++k)
#pragma unroll
        for (int o = 0; o < 16; ++o)
          acc[o] = dot2acc(v[k], wc[k * 16 + o], acc[o]);
    }
#pragma unroll
    for (int o = 0; o < 16; ++o)
      dow16[(o >> 1) * 648 + 2 * p + (o & 1)] = f2h(valid ? acc[o] : 0.f);
  }
  __syncthreads();

  {
    const float* os = offs0 + (size_t)n * 18 * HH;
    for (int i = tid; i < 9 * 324; i += 256) {
      int cp = i / 324, r = i - cp * 324;
      int y1 = r / 18, x1 = r - y1 * 18;
      int gy = by + y1 - 1, gx = bx + x1 - 1;
      float v0 = 0.f, v1 = 0.f;
      if (gy >= 0 && gy < H && gx >= 0 && gx < H) {
        const float* s = os + (size_t)(2 * cp) * HH + (size_t)gy * H + gx;
        v0 = s[0];
        v1 = s[HH];
      }
      ldsA[i] = packh2(v0, v1);
    }
    __syncthreads();
  }

  {
    int ty = tid >> 4, tx = tid & 15;
    float a36[36];
#pragma unroll
    for (int o = 0; o < 36; ++o) a36[o] = bdog[o];
    for (int cp = 0; cp < 8; ++cp) {
      const unsigned* ld = ldsB + cp * 324 + ty * 18 + tx;
      unsigned v[9];
#pragma unroll
      for (int k = 0; k < 9; ++k) v[k] = ld[(k / 3) * 18 + (k % 3)];
      const unsigned* wc = wdog + cp * 324;
#pragma unroll
      for (int k = 0; k < 9; ++k)
#pragma unroll
        for (int o = 0; o < 36; ++o)
          a36[o] = dot2acc(v[k], wc[k * 36 + o], a36[o]);
    }
    for (int cp = 0; cp < 9; ++cp) {
      const unsigned* ld = ldsA + cp * 324 + ty * 18 + tx;
      unsigned v[9];
#pragma unroll
      for (int k = 0; k < 9; ++k) v[k] = ld[(k / 3) * 18 + (k % 3)];
      const unsigned* wc = wdog + (8 + cp) * 324;
#pragma unroll
      for (int k = 0; k < 9; ++k)
#pragma unroll
        for (int o = 0; o < 36; ++o)
          a36[o] = dot2acc(v[k], wc[k * 36 + o], a36[o]);
    }

    const int h = by + ty, w = bx + tx;
    const float* inN = f0hwc + (size_t)n * HH * 16;
    float rr[2] = {0.f, 0.f};
#pragma unroll
    for (int g = 0; g < 2; ++g) {
#pragma unroll
      for (int k = 0; k < 9; ++k) {
        int ky = k / 3 - 1, kx = k % 3 - 1;
        float oy = a36[(g * 9 + k) * 2 + 0];
        float ox = a36[(g * 9 + k) * 2 + 1];
        float py = (float)(h + ky) + oy;
        float px = (float)(w + kx) + ox;
        float y0f = floorf(py), x0f = floorf(px);
        float fy = py - y0f, fx = px - x0f;
        int y0 = (int)y0f, x0 = (int)x0f;
        bool vy0 = ((unsigned)y0 < (unsigned)H);
        bool vy1 = ((unsigned)(y0 + 1) < (unsigned)H);
        bool vx0 = ((unsigned)x0 < (unsigned)H);
        bool vx1 = ((unsigned)(x0 + 1) < (unsigned)H);
        int y0c = min(max(y0, 0), H - 1), y1c = min(max(y0 + 1, 0), H - 1);
        int x0c = min(max(x0, 0), H - 1), x1c = min(max(x0 + 1, 0), H - 1);
        float w00 = (vy0 && vx0) ? (1.f - fy) * (1.f - fx) : 0.f;
        float w01 = (vy0 && vx1) ? (1.f - fy) * fx : 0.f;
        float w10 = (vy1 && vx0) ? fy * (1.f - fx) : 0.f;
        float w11 = (vy1 && vx1) ? fy * fx : 0.f;
        const float* p00 = inN + ((size_t)y0c * H + x0c) * 16 + g * 8;
        const float* p01 = inN + ((size_t)y0c * H + x1c) * 16 + g * 8;
        const float* p10 = inN + ((size_t)y1c * H + x0c) * 16 + g * 8;
        const float* p11 = inN + ((size_t)y1c * H + x1c) * 16 + g * 8;
        const float* wk = wddc + (size_t)(k * 16 + g * 8) * 2;
#pragma unroll
        for (int c4 = 0; c4 < 2; ++c4) {
          float4 a00 = *(const float4*)(p00 + c4 * 4);
          float4 a01 = *(const float4*)(p01 + c4 * 4);
          float4 a10 = *(const float4*)(p10 + c4 * 4);
          float4 a11 = *(const float4*)(p11 + c4 * 4);
          float v0 = w00 * a00.x + w01 * a01.x + w10 * a10.x + w11 * a11.x;
          float v1 = w00 * a00.y + w01 * a01.y + w10 * a10.y + w11 * a11.y;
          float v2 = w00 * a00.z + w01 * a01.z + w10 * a10.z + w11 * a11.z;
          float v3 = w00 * a00.w + w01 * a01.w + w10 * a10.w + w11 * a11.w;
#pragma unroll
          for (int o = 0; o < 2; ++o) {
            float t0 = fmaf(v0, wk[(c4 * 4 + 0) * 2 + o], rr[o]);
            t0 = fmaf(v1, wk[(c4 * 4 + 1) * 2 + o], t0);
            t0 = fmaf(v2, wk[(c4 * 4 + 2) * 2 + o], t0);
            rr[o] = fmaf(v3, wk[(c4 * 4 + 3) * 2 + o], t0);
          }
        }
      }
    }
    out[((size_t)n * 2 + 0) * HH + (size_t)h * H + w] = rr[0];
    out[((size_t)n * 2 + 1) * HH + (size_t)h * H + w] = rr[1];
  }
}

extern "C" void kernel_launch(void* const* d_in, const int* in_sizes, int n_in,
                              void* d_out, int out_size, void* d_ws, size_t ws_size,
                              hipStream_t stream) {
  auto F = [&](int i) { return (const float*)d_in[i]; };
  const float* ref = F(0);
  const float* unr = F(1);
  const float* few1[3] = {F(2), F(6), F(10)};
  const float* feb1[3] = {F(3), F(7), F(11)};
  const float* few2[3] = {F(4), F(8), F(12)};
  const float* feb2[3] = {F(5), F(9), F(13)};
  const float* obw[3] = {F(14), F(16), F(18)};
  const float* obb[3] = {F(15), F(17), F(19)};
  const float* ogw[3] = {F(20), F(22), F(24)};
  const float* ogb[3] = {F(21), F(23), F(25)};
  const float* dcw[3] = {F(26), F(27), F(28)};
  const float* fcw[3] = {F(29), F(31), F(33)};
  const float* fcb[3] = {F(30), F(32), F(34)};
  const float* dobw = F(35);
  const float* dobb = F(36);
  const float* dogw = F(37);
  const float* dogb = F(38);
  const float* ddcw = F(39);

  // ---- workspace (floats) ----
  float* ws = (float*)d_ws;
  size_t p = 0;
  auto alloc = [&](size_t nf) { float* r = ws + p; p += nf; return r; };
  float* rf0 = alloc((size_t)4 * 16 * 65536);
  float* uf0 = alloc((size_t)4 * 16 * 65536);
  float* rf1 = alloc((size_t)4 * 16 * 16384);
  float* uf1 = alloc((size_t)4 * 16 * 16384);
  float* rf2 = alloc((size_t)4 * 16 * 4096);
  float* uf2 = alloc((size_t)4 * 16 * 4096);
  float* offs0 = alloc((size_t)4 * 18 * 65536);
  float* offs1 = alloc((size_t)4 * 18 * 16384);
  float* offs2 = alloc((size_t)4 * 18 * 4096);
  float* feats0 = alloc((size_t)4 * 16 * 65536);
  float* feats1 = alloc((size_t)4 * 16 * 16384);
  float* feats2 = alloc((size_t)4 * 16 * 4096);
  float* ufH0 = alloc((size_t)4 * 16 * 65536);
  float* ufH1 = alloc((size_t)4 * 16 * 16384);
  float* ufH2 = alloc((size_t)4 * 16 * 4096);
  float* fHwc = alloc((size_t)4 * 16 * 65536);
  float* wt = alloc(7200);
  float* cwf = alloc(40000);
  float* wmf = alloc(6400);  // 12800 f16 MFMA-packed weights
  if (p * sizeof(float) > ws_size) return;
  const float* wt_dc[3] = {wt, wt + 2304, wt + 4608};
  const float* wt_ddc = wt + 6912;
  unsigned* cwp = (unsigned*)cwf;
  unsigned short* wmh = (unsigned short*)wmf;

  // ---- dot2-paired weight table (11 entries: alignment kernels only) ----
  WTable T;
  int nw = 0, woff = 0, maxtot = 0;
  auto addw = [&](const float* src, int cin, int cout) {
    T.e[nw].src = src; T.e[nw].cin = cin; T.e[nw].cout = cout; T.e[nw].dstoff = woff;
    int tot = (cin >> 1) * cout * 9;
    if (tot > maxtot) maxtot = tot;
    int start = woff;
    woff += tot;
    ++nw;
    return start;
  };
  int o_ob[3], o_og[3], o_fc[3];
  for (int i = 0; i < 3; ++i) o_ob[i] = addw(obw[i], 32, 16);
  o_og[0] = addw(ogw[0], 34, 18);
  o_og[1] = addw(ogw[1], 34, 18);
  o_og[2] = addw(ogw[2], 16, 18);
  o_fc[0] = addw(fcw[0], 32, 16);
  o_fc[1] = addw(fcw[1], 32, 16);
  o_fc[2] = addw(fcw[2], 16, 16);
  int o_dob = addw(dobw, 32, 16);
  int o_dog = addw(dogw, 34, 36);

  wreorder_k<<<29, 256, 0, stream>>>(dcw[0], dcw[1], dcw[2], ddcw, wt);
  wpair_conv_k<<<dim3((maxtot + 255) / 256, nw), 256, 0, stream>>>(T, cwp);
  // MFMA-packed: [0]=fe0 conv2, [1,2]=fe12 L1, [3,4]=fe12 L2
  wmfma_k<<<50, 256, 0, stream>>>(few2[0], few1[1], few2[1], few1[2], few2[2], wmh);

  // ---- feature pyramids ----
  fe0_fused_k<<<dim3(32, 32, 8), 256, 0, stream>>>(
      ref, unr, few1[0], feb1[0], wmh, feb2[0], rf0, uf0, ufH0);
  fe12_fused_k<<<dim3(16, 16, 8), 256, 0, stream>>>(
      rf0, wmh + 2560, feb1[1], wmh + 2 * 2560, feb2[1], rf1, ufH1, 256);
  fe12_fused_k<<<dim3(8, 8, 8), 256, 0, stream>>>(
      rf1, wmh + 3 * 2560, feb1[2], wmh + 4 * 2560, feb2[2], rf2, ufH2, 128);

  // ---- coarse-to-fine: fused [ob->og] then [deform->fc] per level ----
  obog_k<0><<<dim3(4, 4, 4), 256, 0, stream>>>(
      rf2, uf2, nullptr, cwp + o_ob[2], obb[2], cwp + o_og[2], ogb[2], offs2, 64);
  defc_k<0><<<dim3(4, 4, 4), 256, 0, stream>>>(
      ufH2, offs2, wt_dc[2], nullptr, cwp + o_fc[2], fcb[2], feats2, nullptr, 64);
  obog_k<1><<<dim3(8, 8, 4), 256, 0, stream>>>(
      rf1, uf1, offs2, cwp + o_ob[1], obb[1], cwp + o_og[1], ogb[1], offs1, 128);
  defc_k<1><<<dim3(8, 8, 4), 256, 0, stream>>>(
      ufH1, offs1, wt_dc[1], feats2, cwp + o_fc[1], fcb[1], feats1, nullptr, 128);
  obog_k<1><<<dim3(16, 16, 4), 256, 0, stream>>>(
      rf0, uf0, offs1, cwp + o_ob[0], obb[0], cwp + o_og[0], ogb[0], offs0, 256);
  defc_k<1><<<dim3(16, 16, 4), 256, 0, stream>>>(
      ufH0, offs0, wt_dc[0], feats1, cwp + o_fc[0], fcb[0], feats0, fHwc, 256);

  // ---- fused final head ----
  final_k<<<dim3(16, 16, 4), 256, 0, stream>>>(
      rf0, feats0, fHwc, offs0, cwp + o_dob, dobb, cwp + o_dog, dogb, wt_ddc,
      (float*)d_out);
}

// Round 16
// 748.424 us; speedup vs baseline: 2.1359x; 1.2404x over previous
//
#include <hip/hip_runtime.h>
#include <math.h>

typedef _Float16 half2_t __attribute__((ext_vector_type(2)));
typedef _Float16 half8 __attribute__((ext_vector_type(8)));
typedef float floatx4 __attribute__((ext_vector_type(4)));

__device__ __forceinline__ unsigned packh2(float a, float b) {
  half2_t h;
  h.x = (_Float16)a;
  h.y = (_Float16)b;
  return __builtin_bit_cast(unsigned, h);
}
__device__ __forceinline__ unsigned short f2h(float a) {
  return __builtin_bit_cast(unsigned short, (_Float16)a);
}
__device__ __forceinline__ float h2f(unsigned short u) {
  return (float)__builtin_bit_cast(_Float16, u);
}
__device__ __forceinline__ float dot2acc(unsigned a, unsigned b, float c) {
  half2_t ha = __builtin_bit_cast(half2_t, a);
  half2_t hb = __builtin_bit_cast(half2_t, b);
#if __has_builtin(__builtin_amdgcn_fdot2)
  return __builtin_amdgcn_fdot2(ha, hb, c, false);
#else
  c = fmaf((float)ha.x, (float)hb.x, c);
  return fmaf((float)ha.y, (float)hb.y, c);
#endif
}

// ---------------- deform weight reorder: (O,16,9) -> (9,16,O) f32 ----------------
__global__ __launch_bounds__(256) void wreorder_k(
    const float* __restrict__ a, const float* __restrict__ b,
    const float* __restrict__ c, const float* __restrict__ d,
    float* __restrict__ out) {
  int t = blockIdx.x * 256 + threadIdx.x;
  if (t < 6912) {
    int which = t / 2304, r = t % 2304;
    int o = r % 16, kc = r / 16;
    int ci = kc % 16, k = kc / 16;
    const float* w = which == 0 ? a : (which == 1 ? b : c);
    out[t] = w[(o * 16 + ci) * 9 + k];
  } else if (t < 7200) {
    int r = t - 6912;
    int o = r % 2, kc = r / 2;
    int ci = kc % 16, k = kc / 16;
    out[t] = d[(o * 16 + ci) * 9 + k];
  }
}

// ---------------- dot2 weight pairing: (O,C,9) -> (C/2,9,O) f16-pairs (og/dog only) ----------------
struct WEntry { const float* src; int cin; int cout; int dstoff; };
struct WTable { WEntry e[8]; };  // 4 used
__global__ __launch_bounds__(256) void wpair_conv_k(WTable t, unsigned* __restrict__ out) {
  WEntry en = t.e[blockIdx.y];
  int total = (en.cin >> 1) * 9 * en.cout;
  int i = blockIdx.x * 256 + threadIdx.x;
  if (i >= total) return;
  int o = i % en.cout;
  int k = (i / en.cout) % 9;
  int cp = i / (en.cout * 9);
  float s0 = en.src[((size_t)o * en.cin + 2 * cp) * 9 + k];
  float s1 = en.src[((size_t)o * en.cin + 2 * cp + 1) * 9 + k];
  out[en.dstoff + i] = packh2(s0, s1);
}

// ---------------- MFMA prepack, 16-cin convs (K=144 pad 160, 5 chunks, 2 taps/chunk) ----------------
__global__ __launch_bounds__(256) void wmfma_k(
    const float* __restrict__ w0, const float* __restrict__ w1,
    const float* __restrict__ w2, const float* __restrict__ w3,
    const float* __restrict__ w4, unsigned short* __restrict__ out) {
  int t = blockIdx.x * 256 + threadIdx.x;
  if (t >= 12800) return;
  int conv = t / 2560, r = t % 2560;
  int c = r / 512, L = (r / 8) % 64, j = r & 7;
  int quad = L >> 4, o = L & 15;
  int k = 32 * c + quad * 8 + j;
  int tap = k >> 4, cin = k & 15;
  const float* w = conv == 0 ? w0 : conv == 1 ? w1 : conv == 2 ? w2 : conv == 3 ? w3 : w4;
  float v = (tap < 9) ? w[((size_t)o * 16 + cin) * 9 + tap] : 0.f;
  out[t] = f2h(v);
}

// ---------------- MFMA prepack, 32-cin convs (K=tap*32+c, 9 chunks = 1 tap each) ----------------
struct W32Entry { const float* src; int cin; };
struct W32Table { W32Entry e[8]; };  // 7 used
__global__ __launch_bounds__(256) void wmfma32_k(W32Table t, unsigned short* __restrict__ out) {
  int i = blockIdx.x * 256 + threadIdx.x;
  if (i >= 7 * 4608) return;
  int conv = i / 4608, r = i % 4608;
  int tap = r / 512, L = (r / 8) % 64, j = r & 7;
  int quad = L >> 4, o = L & 15;
  int c = quad * 8 + j;
  W32Entry en = t.e[conv];
  float v = (c < en.cin) ? en.src[((size_t)o * en.cin + c) * 9 + tap] : 0.f;
  out[i] = f2h(v);
}

// ---------------- MFMA 16-cin 3x3 conv over LDS HWC-16 tile (R15-verified) ----------------
__device__ __forceinline__ void conv_mfma(
    const unsigned short* __restrict__ src, int SW,
    unsigned short* __restrict__ dst, const half8* __restrict__ bf,
    const float* __restrict__ bias, int POS, int OW, int tid, int relu,
    int domask, int gby, int gbx, int bound) {
  const int lane = tid & 63, wid = tid >> 6;
  const int quad = lane >> 4, m = lane & 15;
  const int tap01 = quad >> 1, cin8 = (quad & 1) * 8;
  const int ntiles = (POS + 15) >> 4;
  float bs = bias[m];
  half8 zero;
#pragma unroll
  for (int j = 0; j < 8; ++j) zero[j] = (_Float16)0;
  for (int T = wid; T < ntiles; T += 4) {
    int pa = T * 16 + m;
    pa = pa < POS ? pa : POS - 1;
    int ya = pa / OW, xa = pa - ya * OW;
    floatx4 acc = {0.f, 0.f, 0.f, 0.f};
#pragma unroll
    for (int c = 0; c < 5; ++c) {
      int tap = 2 * c + tap01;
      half8 a = zero;
      if (tap < 9) {
        int dy = tap / 3, dx = tap - (tap / 3) * 3;
        a = *(const half8*)(src + ((ya + dy) * SW + xa + dx) * 16 + cin8);
      }
      acc = __builtin_amdgcn_mfma_f32_16x16x32_f16(a, bf[c], acc, 0, 0, 0);
    }
#pragma unroll
    for (int r = 0; r < 4; ++r) {
      int pd = T * 16 + quad * 4 + r;
      if (pd < POS) {
        float v = acc[r] + bs;
        if (relu) v = fmaxf(v, 0.f);
        if (domask) {
          int yd = pd / OW, xd = pd - (pd / OW) * OW;
          int gy = gby + yd, gx = gbx + xd;
          if (gy < 0 || gy >= bound || gx < 0 || gx >= bound) v = 0.f;
        }
        dst[pd * 16 + m] = f2h(v);
      }
    }
  }
}

// ---------------- MFMA 32-cin 3x3 conv over LDS HWC-32 tile -> LDS HWC-16 out ----------------
__device__ __forceinline__ void conv_mfma32(
    const unsigned short* __restrict__ src, int SW,
    unsigned short* __restrict__ dst, const half8* __restrict__ bf,
    const float* __restrict__ bias, int POS, int OW, int tid, int relu,
    int domask, int gby, int gbx, int bound) {
  const int lane = tid & 63, wid = tid >> 6;
  const int quad = lane >> 4, m = lane & 15;
  const int ntiles = (POS + 15) >> 4;
  float bs = bias[m];
  for (int T = wid; T < ntiles; T += 4) {
    int pa = T * 16 + m;
    pa = pa < POS ? pa : POS - 1;
    int ya = pa / OW, xa = pa - ya * OW;
    floatx4 acc = {0.f, 0.f, 0.f, 0.f};
#pragma unroll
    for (int tap = 0; tap < 9; ++tap) {
      int dy = tap / 3, dx = tap - (tap / 3) * 3;
      half8 a = *(const half8*)(src + ((ya + dy) * SW + xa + dx) * 32 + quad * 8);
      acc = __builtin_amdgcn_mfma_f32_16x16x32_f16(a, bf[tap], acc, 0, 0, 0);
    }
#pragma unroll
    for (int r = 0; r < 4; ++r) {
      int pd = T * 16 + quad * 4 + r;
      if (pd < POS) {
        float v = acc[r] + bs;
        if (relu) v = fmaxf(v, 0.f);
        if (domask) {
          int yd = pd / OW, xd = pd - (pd / OW) * OW;
          int gy = gby + yd, gx = gbx + xd;
          if (gy < 0 || gy >= bound || gx < 0 || gx >= bound) v = 0.f;
        }
        dst[pd * 16 + m] = f2h(v);
      }
    }
  }
}

// ---------------- fused FE level-0 (R15-proven) ----------------
__global__ __launch_bounds__(256) void fe0_fused_k(
    const float* __restrict__ refI, const float* __restrict__ unrI,
    const float* __restrict__ w1, const float* __restrict__ b1,
    const unsigned short* __restrict__ wm2, const float* __restrict__ b2,
    float* __restrict__ outR, float* __restrict__ outU, float* __restrict__ outUH) {
  __shared__ __attribute__((aligned(16))) unsigned short c1h[361 * 16];
  __shared__ __attribute__((aligned(16))) unsigned short sb[289 * 16];
  const int z = blockIdx.z;
  const int im = z >> 2, n = z & 3;
  const float* img = (im ? unrI : refI) + (size_t)n * 512 * 512;
  float* outp = (im ? outU : outR) + (size_t)n * 16 * 256 * 256;
  const int py0 = blockIdx.y * 8, px0 = blockIdx.x * 8;
  const int tid = threadIdx.x;

  half8 bf[5];
  {
    const int lane = tid & 63;
#pragma unroll
    for (int c = 0; c < 5; ++c) bf[c] = *(const half8*)(wm2 + (c * 64 + lane) * 8);
  }

  float* inbuf = (float*)sb;
  for (int i = tid; i < 441; i += 256) {
    int yi = i / 21, xi = i - yi * 21;
    int gy = 2 * py0 - 3 + yi, gx = 2 * px0 - 3 + xi;
    float v = 0.f;
    if (gy >= 0 && gy < 512 && gx >= 0 && gx < 512) v = img[gy * 512 + gx];
    inbuf[i] = v;
  }
  __syncthreads();

  unsigned* c1w32 = (unsigned*)c1h;
  for (int p = tid; p < 361; p += 256) {
    int y1 = p / 19, x1 = p - y1 * 19;
    int gy = 2 * py0 - 2 + y1, gx = 2 * px0 - 2 + x1;
    bool valid = (gy >= 0 && gy < 512 && gx >= 0 && gx < 512);
    float t[9];
#pragma unroll
    for (int k = 0; k < 9; ++k) t[k] = inbuf[(y1 + k / 3) * 21 + x1 + (k % 3)];
    float va[16];
#pragma unroll
    for (int c = 0; c < 16; ++c) {
      float a = b1[c];
#pragma unroll
      for (int k = 0; k < 9; ++k) a = fmaf(t[k], w1[c * 9 + k], a);
      va[c] = valid ? fmaxf(a, 0.f) : 0.f;
    }
#pragma unroll
    for (int cc = 0; cc < 8; ++cc) c1w32[p * 8 + cc] = packh2(va[2 * cc], va[2 * cc + 1]);
  }
  __syncthreads();

  conv_mfma(c1h, 19, sb, bf, b2, 289, 17, tid, 1, 0, 0, 0, 0);
  __syncthreads();

  for (int i = tid; i < 1024; i += 256) {
    int c = i >> 6, r = i & 63, py = r >> 3, px = r & 7;
    unsigned short m = 0;
#pragma unroll
    for (int dy = 0; dy < 3; ++dy) {
      int gy = 2 * (py0 + py) - 1 + dy;
      if (gy < 0 || gy >= 512) continue;
#pragma unroll
      for (int dx = 0; dx < 3; ++dx) {
        int gx = 2 * (px0 + px) - 1 + dx;
        if (gx < 0 || gx >= 512) continue;
        unsigned short v = sb[((2 * py + dy) * 17 + 2 * px + dx) * 16 + c];
        m = (v > m) ? v : m;
      }
    }
    float mf = h2f(m);
    outp[((size_t)c * 256 + py0 + py) * 256 + px0 + px] = mf;
    if (im)
      outUH[(((size_t)n * 256 + py0 + py) * 256 + px0 + px) * 16 + c] = mf;
  }
}

// ---------------- fused FE level-1/2 (R15-proven) ----------------
__global__ __launch_bounds__(256) void fe12_fused_k(
    const float* __restrict__ in,
    const unsigned short* __restrict__ wm1, const float* __restrict__ b1,
    const unsigned short* __restrict__ wm2, const float* __restrict__ b2,
    float* __restrict__ outC, float* __restrict__ outHWC, int Hin) {
  __shared__ __attribute__((aligned(16))) unsigned short inh[441 * 16];
  __shared__ __attribute__((aligned(16))) unsigned short c1h[361 * 16];
  const int n = blockIdx.z;
  const int Ho = Hin >> 1;
  const int py0 = blockIdx.y * 8, px0 = blockIdx.x * 8;
  const int tid = threadIdx.x;
  const float* inN = in + (size_t)n * 16 * Hin * Hin;
  const size_t HH = (size_t)Hin * Hin;

  half8 bf1[5], bf2[5];
  {
    const int lane = tid & 63;
#pragma unroll
    for (int c = 0; c < 5; ++c) {
      bf1[c] = *(const half8*)(wm1 + (c * 64 + lane) * 8);
      bf2[c] = *(const half8*)(wm2 + (c * 64 + lane) * 8);
    }
  }

  unsigned* inh32 = (unsigned*)inh;
  for (int i = tid; i < 8 * 441; i += 256) {
    int cp = i / 441, r = i - cp * 441;
    int yi = r / 21, xi = r - yi * 21;
    int gy = 2 * py0 - 3 + yi, gx = 2 * px0 - 3 + xi;
    float v0 = 0.f, v1 = 0.f;
    if (gy >= 0 && gy < Hin && gx >= 0 && gx < Hin) {
      const float* s = inN + (size_t)(2 * cp) * HH + (size_t)gy * Hin + gx;
      v0 = s[0];
      v1 = s[HH];
    }
    inh32[r * 8 + cp] = packh2(v0, v1);
  }
  __syncthreads();

  conv_mfma(inh, 21, c1h, bf1, b1, 361, 19, tid, 1, 1, 2 * py0 - 2, 2 * px0 - 2, Hin);
  __syncthreads();
  conv_mfma(c1h, 19, inh, bf2, b2, 289, 17, tid, 1, 0, 0, 0, 0);
  __syncthreads();

  float* outp = outC + (size_t)n * 16 * Ho * Ho;
  for (int i = tid; i < 1024; i += 256) {
    int c = i >> 6, r = i & 63, py = r >> 3, px = r & 7;
    unsigned short m = 0;
#pragma unroll
    for (int dy = 0; dy < 3; ++dy) {
      int gy = 2 * (py0 + py) - 1 + dy;
      if (gy < 0 || gy >= Hin) continue;
#pragma unroll
      for (int dx = 0; dx < 3; ++dx) {
        int gx = 2 * (px0 + px) - 1 + dx;
        if (gx < 0 || gx >= Hin) continue;
        unsigned short v = inh[((2 * py + dy) * 17 + 2 * px + dx) * 16 + c];
        m = (v > m) ? v : m;
      }
    }
    float mf = h2f(m);
    outp[((size_t)c * Ho + py0 + py) * Ho + px0 + px] = mf;
    if (n >= 4)
      outHWC[(((size_t)(n - 4) * Ho + py0 + py) * Ho + px0 + px) * 16 + c] = mf;
  }
}

// ---------------- fused offset head: ob(MFMA) -> og(dot2) -> offs ----------------
template <int HAS_UP>
__global__ __launch_bounds__(256) void obog_k(
    const float* __restrict__ rf, const float* __restrict__ uf,
    const float* __restrict__ offsUp,
    const unsigned short* __restrict__ wmob, const float* __restrict__ bob,
    const unsigned* __restrict__ wog, const float* __restrict__ bog,
    float* __restrict__ offsOut, int H) {
  __shared__ __attribute__((aligned(16))) unsigned ldsA[400 * 16];  // HWC-32 20x20 / overlay pair-plane
  __shared__ __attribute__((aligned(16))) unsigned ldsB[324 * 8];   // ob-out HWC-16 18x18
  const int n = blockIdx.z;
  const int bx = blockIdx.x * 16, by = blockIdx.y * 16;
  const int tid = threadIdx.x;
  const size_t HH = (size_t)H * H;
  const float* r0 = rf + (size_t)n * 16 * HH;
  const float* u0 = uf + (size_t)n * 16 * HH;

  for (int i = tid; i < 6400; i += 256) {
    int cp = i / 400, r = i - cp * 400;
    int ly = r / 20, lx = r - ly * 20;
    int gy = by + ly - 2, gx = bx + lx - 2;
    float v0 = 0.f, v1 = 0.f;
    if (gy >= 0 && gy < H && gx >= 0 && gx < H) {
      const float* s = (cp < 8) ? r0 + (size_t)(2 * cp) * HH : u0 + (size_t)(2 * cp - 16) * HH;
      size_t off = (size_t)gy * H + gx;
      v0 = s[off];
      v1 = s[HH + off];
    }
    ldsA[r * 16 + cp] = packh2(v0, v1);
  }
  __syncthreads();

  {
    half8 bf[9];
    const int lane = tid & 63;
#pragma unroll
    for (int c = 0; c < 9; ++c) bf[c] = *(const half8*)(wmob + (c * 64 + lane) * 8);
    conv_mfma32((const unsigned short*)ldsA, 20, (unsigned short*)ldsB, bf, bob,
                324, 18, tid, 1, 1, by - 1, bx - 1, H);
  }
  __syncthreads();

  if (HAS_UP) {  // overlay ldsA with up2(offsUp) pair-plane (9 pairs x 324)
    const int H2 = H >> 1;
    const float* os = offsUp + (size_t)n * 18 * H2 * H2;
    for (int i = tid; i < 9 * 324; i += 256) {
      int cp = i / 324, r = i - cp * 324;
      int y1 = r / 18, x1 = r - y1 * 18;
      int gy = by + y1 - 1, gx = bx + x1 - 1;
      float v0 = 0.f, v1 = 0.f;
      if (gy >= 0 && gy < H && gx >= 0 && gx < H) {
        float sy = 0.5f * gy - 0.25f, sx = 0.5f * gx - 0.25f;
        float y0f = floorf(sy), x0f = floorf(sx);
        float wy = sy - y0f, wx = sx - x0f;
        int y0 = (int)y0f, x0 = (int)x0f;
        int y0c = min(max(y0, 0), H2 - 1), y1c = min(max(y0 + 1, 0), H2 - 1);
        int x0c = min(max(x0, 0), H2 - 1), x1c = min(max(x0 + 1, 0), H2 - 1);
        const float* sp = os + (size_t)(2 * cp) * H2 * H2;
        v0 = (1.f - wy) * ((1.f - wx) * sp[y0c * H2 + x0c] + wx * sp[y0c * H2 + x1c]) +
             wy * ((1.f - wx) * sp[y1c * H2 + x0c] + wx * sp[y1c * H2 + x1c]);
        sp += (size_t)H2 * H2;
        v1 = (1.f - wy) * ((1.f - wx) * sp[y0c * H2 + x0c] + wx * sp[y0c * H2 + x1c]) +
             wy * ((1.f - wx) * sp[y1c * H2 + x0c] + wx * sp[y1c * H2 + x1c]);
      }
      ldsA[cp * 324 + r] = packh2(v0, v1);
    }
    __syncthreads();
  }

  {
    int ty = tid >> 4, tx = tid & 15;
    float acc[18];
#pragma unroll
    for (int o = 0; o < 18; ++o) acc[o] = bog[o];
#pragma unroll 2
    for (int cp = 0; cp < 8; ++cp) {
      const unsigned* ld = ldsB + (ty * 18 + tx) * 8 + cp;
      unsigned v[9];
#pragma unroll
      for (int k = 0; k < 9; ++k) v[k] = ld[((k / 3) * 18 + (k % 3)) * 8];
      const unsigned* wc = wog + cp * 162;
#pragma unroll
      for (int k = 0; k < 9; ++k)
#pragma unroll
        for (int o = 0; o < 18; ++o)
          acc[o] = dot2acc(v[k], wc[k * 18 + o], acc[o]);
    }
    if (HAS_UP) {
#pragma unroll 2
      for (int cp = 0; cp < 9; ++cp) {
        const unsigned* ld = ldsA + cp * 324 + ty * 18 + tx;
        unsigned v[9];
#pragma unroll
        for (int k = 0; k < 9; ++k) v[k] = ld[(k / 3) * 18 + (k % 3)];
        const unsigned* wc = wog + (8 + cp) * 162;
#pragma unroll
        for (int k = 0; k < 9; ++k)
#pragma unroll
          for (int o = 0; o < 18; ++o)
            acc[o] = dot2acc(v[k], wc[k * 18 + o], acc[o]);
      }
    }
    float* op = offsOut + (size_t)n * 18 * HH + (size_t)(by + ty) * H + (bx + tx);
#pragma unroll
    for (int o = 0; o < 18; ++o) op[(size_t)o * HH] = fmaxf(acc[o], 0.f);
  }
}

// ---------------- fused feature head: deform -> fc(MFMA) -> feats ----------------
template <int HAS_UP>
__global__ __launch_bounds__(256) void defc_k(
    const float* __restrict__ ufHWC, const float* __restrict__ offs,
    const float* __restrict__ wdef, const float* __restrict__ featsUp,
    const unsigned short* __restrict__ wmfc, const float* __restrict__ bfc,
    float* __restrict__ featsOut, float* __restrict__ outHwc, int H) {
  __shared__ __attribute__((aligned(16))) unsigned ldsC[324 * 16];  // HWC-32: deform(0-15)+up(16-31)
  const int n = blockIdx.z;
  const int bx = blockIdx.x * 16, by = blockIdx.y * 16;
  const int tid = threadIdx.x;
  const size_t HH = (size_t)H * H;
  const float* inN = ufHWC + (size_t)n * HH * 16;
  const float* offN = offs + (size_t)n * 18 * HH;

  half8 bf[9];
  {
    const int lane = tid & 63;
#pragma unroll
    for (int c = 0; c < 9; ++c) bf[c] = *(const half8*)(wmfc + (c * 64 + lane) * 8);
  }

  for (int p = tid; p < 324; p += 256) {
    int y1 = p / 18, x1 = p - y1 * 18;
    int h = by + y1 - 1, w = bx + x1 - 1;
    bool valid = (h >= 0 && h < H && w >= 0 && w < H);
    float acc[16];
#pragma unroll
    for (int o = 0; o < 16; ++o) acc[o] = 0.f;
    if (valid) {
      size_t hw = (size_t)h * H + w;
#pragma unroll
      for (int k = 0; k < 9; ++k) {
        int ky = k / 3 - 1, kx = k % 3 - 1;
        float oy = offN[(size_t)(2 * k) * HH + hw];
        float ox = offN[(size_t)(2 * k + 1) * HH + hw];
        float py = (float)(h + ky) + oy;
        float px = (float)(w + kx) + ox;
        float y0f = floorf(py), x0f = floorf(px);
        float fy = py - y0f, fx = px - x0f;
        int y0 = (int)y0f, x0 = (int)x0f;
        bool vy0 = ((unsigned)y0 < (unsigned)H);
        bool vy1 = ((unsigned)(y0 + 1) < (unsigned)H);
        bool vx0 = ((unsigned)x0 < (unsigned)H);
        bool vx1 = ((unsigned)(x0 + 1) < (unsigned)H);
        int y0c = min(max(y0, 0), H - 1), y1c = min(max(y0 + 1, 0), H - 1);
        int x0c = min(max(x0, 0), H - 1), x1c = min(max(x0 + 1, 0), H - 1);
        float w00 = (vy0 && vx0) ? (1.f - fy) * (1.f - fx) : 0.f;
        float w01 = (vy0 && vx1) ? (1.f - fy) * fx : 0.f;
        float w10 = (vy1 && vx0) ? fy * (1.f - fx) : 0.f;
        float w11 = (vy1 && vx1) ? fy * fx : 0.f;
        const float* p00 = inN + ((size_t)y0c * H + x0c) * 16;
        const float* p01 = inN + ((size_t)y0c * H + x1c) * 16;
        const float* p10 = inN + ((size_t)y1c * H + x0c) * 16;
        const float* p11 = inN + ((size_t)y1c * H + x1c) * 16;
        const float* wk = wdef + (size_t)k * 256;
#pragma unroll
        for (int c4 = 0; c4 < 4; ++c4) {
          float4 a00 = *(const float4*)(p00 + c4 * 4);
          float4 a01 = *(const float4*)(p01 + c4 * 4);
          float4 a10 = *(const float4*)(p10 + c4 * 4);
          float4 a11 = *(const float4*)(p11 + c4 * 4);
          float v0 = w00 * a00.x + w01 * a01.x + w10 * a10.x + w11 * a11.x;
          float v1 = w00 * a00.y + w01 * a01.y + w10 * a10.y + w11 * a11.y;
          float v2 = w00 * a00.z + w01 * a01.z + w10 * a10.z + w11 * a11.z;
          float v3 = w00 * a00.w + w01 * a01.w + w10 * a10.w + w11 * a11.w;
#pragma unroll
          for (int o = 0; o < 16; ++o) {
            float t0 = fmaf(v0, wk[(c4 * 4 + 0) * 16 + o], acc[o]);
            t0 = fmaf(v1, wk[(c4 * 4 + 1) * 16 + o], t0);
            t0 = fmaf(v2, wk[(c4 * 4 + 2) * 16 + o], t0);
            acc[o] = fmaf(v3, wk[(c4 * 4 + 3) * 16 + o], t0);
          }
        }
      }
    }
#pragma unroll
    for (int cc = 0; cc < 8; ++cc) {
      float a0 = valid ? fmaxf(acc[2 * cc], 0.f) : 0.f;
      float a1 = valid ? fmaxf(acc[2 * cc + 1], 0.f) : 0.f;
      ldsC[p * 16 + cc] = packh2(a0, a1);
      if (!HAS_UP) ldsC[p * 16 + 8 + cc] = 0u;
    }
  }

  if (HAS_UP) {  // up2(featsUp) -> channels 16..31
    const int H2 = H >> 1;
    const float* fu = featsUp + (size_t)n * 16 * H2 * H2;
    for (int i = tid; i < 8 * 324; i += 256) {
      int cp = i / 324, r = i - cp * 324;
      int y1 = r / 18, x1 = r - y1 * 18;
      int gy = by + y1 - 1, gx = bx + x1 - 1;
      float v0 = 0.f, v1 = 0.f;
      if (gy >= 0 && gy < H && gx >= 0 && gx < H) {
        float sy = 0.5f * gy - 0.25f, sx = 0.5f * gx - 0.25f;
        float y0f = floorf(sy), x0f = floorf(sx);
        float wy = sy - y0f, wx = sx - x0f;
        int y0 = (int)y0f, x0 = (int)x0f;
        int y0c = min(max(y0, 0), H2 - 1), y1c = min(max(y0 + 1, 0), H2 - 1);
        int x0c = min(max(x0, 0), H2 - 1), x1c = min(max(x0 + 1, 0), H2 - 1);
        const float* sp = fu + (size_t)(2 * cp) * H2 * H2;
        v0 = (1.f - wy) * ((1.f - wx) * sp[y0c * H2 + x0c] + wx * sp[y0c * H2 + x1c]) +
             wy * ((1.f - wx) * sp[y1c * H2 + x0c] + wx * sp[y1c * H2 + x1c]);
        sp += (size_t)H2 * H2;
        v1 = (1.f - wy) * ((1.f - wx) * sp[y0c * H2 + x0c] + wx * sp[y0c * H2 + x1c]) +
             wy * ((1.f - wx) * sp[y1c * H2 + x0c] + wx * sp[y1c * H2 + x1c]);
      }
      ldsC[r * 16 + 8 + cp] = packh2(v0, v1);
    }
  }
  __syncthreads();

  // fc via MFMA (POS=256, OW=16, SW=18), global epilogue
  {
    const int lane = tid & 63, wid = tid >> 6;
    const int quad = lane >> 4, m = lane & 15;
    const unsigned short* src = (const unsigned short*)ldsC;
    float bs = bfc[m];
    for (int T = wid; T < 16; T += 4) {
      int pa = T * 16 + m;
      int ya = pa >> 4, xa = pa & 15;
      floatx4 acc = {0.f, 0.f, 0.f, 0.f};
#pragma unroll
      for (int tap = 0; tap < 9; ++tap) {
        int dy = tap / 3, dx = tap - (tap / 3) * 3;
        half8 a = *(const half8*)(src + ((ya + dy) * 18 + xa + dx) * 32 + quad * 8);
        acc = __builtin_amdgcn_mfma_f32_16x16x32_f16(a, bf[tap], acc, 0, 0, 0);
      }
#pragma unroll
      for (int r = 0; r < 4; ++r) {
        int pd = T * 16 + quad * 4 + r;
        int yd = pd >> 4, xd = pd & 15;
        float v = fmaxf(acc[r] + bs, 0.f);
        featsOut[(size_t)n * 16 * HH + (size_t)m * HH + (size_t)(by + yd) * H + bx + xd] = v;
        if (outHwc)
          outHwc[((size_t)n * HH + (size_t)(by + yd) * H + bx + xd) * 16 + m] = v;
      }
    }
  }
}

// ---------------- fused final head: dob(MFMA) -> dog(dot2, regs) -> deform dg=2 ----------------
__global__ __launch_bounds__(256) void final_k(
    const float* __restrict__ rf0, const float* __restrict__ f0chw,
    const float* __restrict__ f0hwc, const float* __restrict__ offs0,
    const unsigned short* __restrict__ wmdob, const float* __restrict__ bdob,
    const unsigned* __restrict__ wdog, const float* __restrict__ bdog,
    const float* __restrict__ wddc, float* __restrict__ out) {
  __shared__ __attribute__((aligned(16))) unsigned ldsA[400 * 16];  // HWC-32 / overlay pair-plane
  __shared__ __attribute__((aligned(16))) unsigned ldsB[324 * 8];   // dob-out HWC-16
  const int H = 256;
  const size_t HH = 65536;
  const int n = blockIdx.z;
  const int bx = blockIdx.x * 16, by = blockIdx.y * 16;
  const int tid = threadIdx.x;
  const float* r0 = rf0 + (size_t)n * 16 * HH;
  const float* f0 = f0chw + (size_t)n * 16 * HH;

  for (int i = tid; i < 6400; i += 256) {
    int cp = i / 400, r = i - cp * 400;
    int ly = r / 20, lx = r - ly * 20;
    int gy = by + ly - 2, gx = bx + lx - 2;
    float v0 = 0.f, v1 = 0.f;
    if (gy >= 0 && gy < H && gx >= 0 && gx < H) {
      const float* s = (cp < 8) ? r0 + (size_t)(2 * cp) * HH : f0 + (size_t)(2 * cp - 16) * HH;
      size_t off = (size_t)gy * H + gx;
      v0 = s[off];
      v1 = s[HH + off];
    }
    ldsA[r * 16 + cp] = packh2(v0, v1);
  }
  __syncthreads();

  {
    half8 bf[9];
    const int lane = tid & 63;
#pragma unroll
    for (int c = 0; c < 9; ++c) bf[c] = *(const half8*)(wmdob + (c * 64 + lane) * 8);
    conv_mfma32((const unsigned short*)ldsA, 20, (unsigned short*)ldsB, bf, bdob,
                324, 18, tid, 0, 1, by - 1, bx - 1, H);
  }
  __syncthreads();

  {  // overlay ldsA with offs0 pair-plane
    const float* os = offs0 + (size_t)n * 18 * HH;
    for (int i = tid; i < 9 * 324; i += 256) {
      int cp = i / 324, r = i - cp * 324;
      int y1 = r / 18, x1 = r - y1 * 18;
      int gy = by + y1 - 1, gx = bx + x1 - 1;
      float v0 = 0.f, v1 = 0.f;
      if (gy >= 0 && gy < H && gx >= 0 && gx < H) {
        const float* s = os + (size_t)(2 * cp) * HH + (size_t)gy * H + gx;
        v0 = s[0];
        v1 = s[HH];
      }
      ldsA[cp * 324 + r] = packh2(v0, v1);
    }
    __syncthreads();
  }

  {
    int ty = tid >> 4, tx = tid & 15;
    float a36[36];
#pragma unroll
    for (int o = 0; o < 36; ++o) a36[o] = bdog[o];
    for (int cp = 0; cp < 8; ++cp) {
      const unsigned* ld = ldsB + (ty * 18 + tx) * 8 + cp;
      unsigned v[9];
#pragma unroll
      for (int k = 0; k < 9; ++k) v[k] = ld[((k / 3) * 18 + (k % 3)) * 8];
      const unsigned* wc = wdog + cp * 324;
#pragma unroll
      for (int k = 0; k < 9; ++k)
#pragma unroll
        for (int o = 0; o < 36; ++o)
          a36[o] = dot2acc(v[k], wc[k * 36 + o], a36[o]);
    }
    for (int cp = 0; cp < 9; ++cp) {
      const unsigned* ld = ldsA + cp * 324 + ty * 18 + tx;
      unsigned v[9];
#pragma unroll
      for (int k = 0; k < 9; ++k) v[k] = ld[(k / 3) * 18 + (k % 3)];
      const unsigned* wc = wdog + (8 + cp) * 324;
#pragma unroll
      for (int k = 0; k < 9; ++k)
#pragma unroll
        for (int o = 0; o < 36; ++o)
          a36[o] = dot2acc(v[k], wc[k * 36 + o], a36[o]);
    }

    const int h = by + ty, w = bx + tx;
    const float* inN = f0hwc + (size_t)n * HH * 16;
    float rr[2] = {0.f, 0.f};
#pragma unroll
    for (int g = 0; g < 2; ++g) {
#pragma unroll
      for (int k = 0; k < 9; ++k) {
        int ky = k / 3 - 1, kx = k % 3 - 1;
        float oy = a36[(g * 9 + k) * 2 + 0];
        float ox = a36[(g * 9 + k) * 2 + 1];
        float py = (float)(h + ky) + oy;
        float px = (float)(w + kx) + ox;
        float y0f = floorf(py), x0f = floorf(px);
        float fy = py - y0f, fx = px - x0f;
        int y0 = (int)y0f, x0 = (int)x0f;
        bool vy0 = ((unsigned)y0 < (unsigned)H);
        bool vy1 = ((unsigned)(y0 + 1) < (unsigned)H);
        bool vx0 = ((unsigned)x0 < (unsigned)H);
        bool vx1 = ((unsigned)(x0 + 1) < (unsigned)H);
        int y0c = min(max(y0, 0), H - 1), y1c = min(max(y0 + 1, 0), H - 1);
        int x0c = min(max(x0, 0), H - 1), x1c = min(max(x0 + 1, 0), H - 1);
        float w00 = (vy0 && vx0) ? (1.f - fy) * (1.f - fx) : 0.f;
        float w01 = (vy0 && vx1) ? (1.f - fy) * fx : 0.f;
        float w10 = (vy1 && vx0) ? fy * (1.f - fx) : 0.f;
        float w11 = (vy1 && vx1) ? fy * fx : 0.f;
        const float* p00 = inN + ((size_t)y0c * H + x0c) * 16 + g * 8;
        const float* p01 = inN + ((size_t)y0c * H + x1c) * 16 + g * 8;
        const float* p10 = inN + ((size_t)y1c * H + x0c) * 16 + g * 8;
        const float* p11 = inN + ((size_t)y1c * H + x1c) * 16 + g * 8;
        const float* wk = wddc + (size_t)(k * 16 + g * 8) * 2;
#pragma unroll
        for (int c4 = 0; c4 < 2; ++c4) {
          float4 a00 = *(const float4*)(p00 + c4 * 4);
          float4 a01 = *(const float4*)(p01 + c4 * 4);
          float4 a10 = *(const float4*)(p10 + c4 * 4);
          float4 a11 = *(const float4*)(p11 + c4 * 4);
          float v0 = w00 * a00.x + w01 * a01.x + w10 * a10.x + w11 * a11.x;
          float v1 = w00 * a00.y + w01 * a01.y + w10 * a10.y + w11 * a11.y;
          float v2 = w00 * a00.z + w01 * a01.z + w10 * a10.z + w11 * a11.z;
          float v3 = w00 * a00.w + w01 * a01.w + w10 * a10.w + w11 * a11.w;
#pragma unroll
          for (int o = 0; o < 2; ++o) {
            float t0 = fmaf(v0, wk[(c4 * 4 + 0) * 2 + o], rr[o]);
            t0 = fmaf(v1, wk[(c4 * 4 + 1) * 2 + o], t0);
            t0 = fmaf(v2, wk[(c4 * 4 + 2) * 2 + o], t0);
            rr[o] = fmaf(v3, wk[(c4 * 4 + 3) * 2 + o], t0);
          }
        }
      }
    }
    out[((size_t)n * 2 + 0) * HH + (size_t)h * H + w] = rr[0];
    out[((size_t)n * 2 + 1) * HH + (size_t)h * H + w] = rr[1];
  }
}

extern "C" void kernel_launch(void* const* d_in, const int* in_sizes, int n_in,
                              void* d_out, int out_size, void* d_ws, size_t ws_size,
                              hipStream_t stream) {
  auto F = [&](int i) { return (const float*)d_in[i]; };
  const float* ref = F(0);
  const float* unr = F(1);
  const float* few1[3] = {F(2), F(6), F(10)};
  const float* feb1[3] = {F(3), F(7), F(11)};
  const float* few2[3] = {F(4), F(8), F(12)};
  const float* feb2[3] = {F(5), F(9), F(13)};
  const float* obw[3] = {F(14), F(16), F(18)};
  const float* obb[3] = {F(15), F(17), F(19)};
  const float* ogw[3] = {F(20), F(22), F(24)};
  const float* ogb[3] = {F(21), F(23), F(25)};
  const float* dcw[3] = {F(26), F(27), F(28)};
  const float* fcw[3] = {F(29), F(31), F(33)};
  const float* fcb[3] = {F(30), F(32), F(34)};
  const float* dobw = F(35);
  const float* dobb = F(36);
  const float* dogw = F(37);
  const float* dogb = F(38);
  const float* ddcw = F(39);

  // ---- workspace (floats) ----
  float* ws = (float*)d_ws;
  size_t p = 0;
  auto alloc = [&](size_t nf) { float* r = ws + p; p += nf; return r; };
  float* rf0 = alloc((size_t)4 * 16 * 65536);
  float* uf0 = alloc((size_t)4 * 16 * 65536);
  float* rf1 = alloc((size_t)4 * 16 * 16384);
  float* uf1 = alloc((size_t)4 * 16 * 16384);
  float* rf2 = alloc((size_t)4 * 16 * 4096);
  float* uf2 = alloc((size_t)4 * 16 * 4096);
  float* offs0 = alloc((size_t)4 * 18 * 65536);
  float* offs1 = alloc((size_t)4 * 18 * 16384);
  float* offs2 = alloc((size_t)4 * 18 * 4096);
  float* feats0 = alloc((size_t)4 * 16 * 65536);
  float* feats1 = alloc((size_t)4 * 16 * 16384);
  float* feats2 = alloc((size_t)4 * 16 * 4096);
  float* ufH0 = alloc((size_t)4 * 16 * 65536);
  float* ufH1 = alloc((size_t)4 * 16 * 16384);
  float* ufH2 = alloc((size_t)4 * 16 * 4096);
  float* fHwc = alloc((size_t)4 * 16 * 65536);
  float* wt = alloc(7200);
  float* cwf = alloc(16000);   // dot2 pairs (og x3 + dog): 13770 u32
  float* wmf = alloc(6400);    // 16-cin MFMA pack: 12800 u16
  float* wm32f = alloc(16200); // 32-cin MFMA pack: 32256 u16
  if (p * sizeof(float) > ws_size) return;
  const float* wt_dc[3] = {wt, wt + 2304, wt + 4608};
  const float* wt_ddc = wt + 6912;
  unsigned* cwp = (unsigned*)cwf;
  unsigned short* wmh = (unsigned short*)wmf;
  unsigned short* wm32 = (unsigned short*)wm32f;

  // ---- dot2 weight table: og0, og1, og2, dog ----
  WTable T;
  int nw = 0, woff = 0, maxtot = 0;
  auto addw = [&](const float* src, int cin, int cout) {
    T.e[nw].src = src; T.e[nw].cin = cin; T.e[nw].cout = cout; T.e[nw].dstoff = woff;
    int tot = (cin >> 1) * cout * 9;
    if (tot > maxtot) maxtot = tot;
    int start = woff;
    woff += tot;
    ++nw;
    return start;
  };
  int o_og[3];
  o_og[0] = addw(ogw[0], 34, 18);
  o_og[1] = addw(ogw[1], 34, 18);
  o_og[2] = addw(ogw[2], 16, 18);
  int o_dog = addw(dogw, 34, 36);

  // ---- 32-cin MFMA table: ob0 ob1 ob2 dob fc0 fc1 fc2(pad) ----
  W32Table T32;
  T32.e[0] = {obw[0], 32}; T32.e[1] = {obw[1], 32}; T32.e[2] = {obw[2], 32};
  T32.e[3] = {dobw, 32};   T32.e[4] = {fcw[0], 32}; T32.e[5] = {fcw[1], 32};
  T32.e[6] = {fcw[2], 16};
  auto o32 = [](int i) { return i * 4608; };

  wreorder_k<<<29, 256, 0, stream>>>(dcw[0], dcw[1], dcw[2], ddcw, wt);
  wpair_conv_k<<<dim3((maxtot + 255) / 256, nw), 256, 0, stream>>>(T, cwp);
  wmfma_k<<<50, 256, 0, stream>>>(few2[0], few1[1], few2[1], few1[2], few2[2], wmh);
  wmfma32_k<<<126, 256, 0, stream>>>(T32, wm32);

  // ---- feature pyramids ----
  fe0_fused_k<<<dim3(32, 32, 8), 256, 0, stream>>>(
      ref, unr, few1[0], feb1[0], wmh, feb2[0], rf0, uf0, ufH0);
  fe12_fused_k<<<dim3(16, 16, 8), 256, 0, stream>>>(
      rf0, wmh + 2560, feb1[1], wmh + 2 * 2560, feb2[1], rf1, ufH1, 256);
  fe12_fused_k<<<dim3(8, 8, 8), 256, 0, stream>>>(
      rf1, wmh + 3 * 2560, feb1[2], wmh + 4 * 2560, feb2[2], rf2, ufH2, 128);

  // ---- coarse-to-fine: fused [ob->og] then [deform->fc] per level ----
  obog_k<0><<<dim3(4, 4, 4), 256, 0, stream>>>(
      rf2, uf2, nullptr, wm32 + o32(2), obb[2], cwp + o_og[2], ogb[2], offs2, 64);
  defc_k<0><<<dim3(4, 4, 4), 256, 0, stream>>>(
      ufH2, offs2, wt_dc[2], nullptr, wm32 + o32(6), fcb[2], feats2, nullptr, 64);
  obog_k<1><<<dim3(8, 8, 4), 256, 0, stream>>>(
      rf1, uf1, offs2, wm32 + o32(1), obb[1], cwp + o_og[1], ogb[1], offs1, 128);
  defc_k<1><<<dim3(8, 8, 4), 256, 0, stream>>>(
      ufH1, offs1, wt_dc[1], feats2, wm32 + o32(5), fcb[1], feats1, nullptr, 128);
  obog_k<1><<<dim3(16, 16, 4), 256, 0, stream>>>(
      rf0, uf0, offs1, wm32 + o32(0), obb[0], cwp + o_og[0], ogb[0], offs0, 256);
  defc_k<1><<<dim3(16, 16, 4), 256, 0, stream>>>(
      ufH0, offs0, wt_dc[0], feats1, wm32 + o32(4), fcb[0], feats0, fHwc, 256);

  // ---- fused final head ----
  final_k<<<dim3(16, 16, 4), 256, 0, stream>>>(
      rf0, feats0, fHwc, offs0, wm32 + o32(3), dobb, cwp + o_dog, dogb, wt_ddc,
      (float*)d_out);
}